// Round 1
// baseline (1042.591 us; speedup 1.0000x reference)
//
#include <hip/hip_runtime.h>

#define N_NODES 50000
#define N_EDGES 400000
#define DIM_IN  128
#define DIM_H   192
#define N_LAYERS 3
#define BN_EPSF 1e-5f

__device__ __forceinline__ float relu_f(float x) { return x > 0.f ? x : 0.f; }

// ---------------- CSR build ----------------
__global__ void k_hist(const int* __restrict__ edge, int* __restrict__ cnt) {
  int e = blockIdx.x * 256 + threadIdx.x;
  if (e < N_EDGES) atomicAdd(&cnt[edge[N_EDGES + e]], 1);
}

__global__ void k_scan(const int* __restrict__ deg, int* __restrict__ rowptr) {
  __shared__ int buf[1024];
  __shared__ int carry;
  int tid = threadIdx.x;
  if (tid == 0) { carry = 0; rowptr[0] = 0; }
  __syncthreads();
  for (int base = 0; base < N_NODES; base += 1024) {
    int v = (base + tid < N_NODES) ? deg[base + tid] : 0;
    buf[tid] = v;
    __syncthreads();
    for (int off = 1; off < 1024; off <<= 1) {
      int t = (tid >= off) ? buf[tid - off] : 0;
      __syncthreads();
      buf[tid] += t;
      __syncthreads();
    }
    if (base + tid < N_NODES) rowptr[base + tid + 1] = carry + buf[tid];
    __syncthreads();
    if (tid == 0) carry += buf[1023];
    __syncthreads();
  }
}

__global__ void k_copy_int(const int* __restrict__ src, int* __restrict__ dst, int n) {
  int i = blockIdx.x * 256 + threadIdx.x;
  if (i < n) dst[i] = src[i];
}

__global__ void k_fill(const int* __restrict__ edge, int* __restrict__ cursor, int* __restrict__ csr) {
  int e = blockIdx.x * 256 + threadIdx.x;
  if (e < N_EDGES) {
    int s = edge[e];
    int d = edge[N_EDGES + e];
    int pos = atomicAdd(&cursor[d], 1);
    csr[pos] = s;
  }
}

// ---------------- aggregation: outA = (1+eps)*h + segment_sum(h[src], dst) ----------------
__global__ void k_aggregate(const float* __restrict__ h, const int* __restrict__ rowptr,
                            const int* __restrict__ csr, const float* __restrict__ eps, int l,
                            float* __restrict__ outA) {
  int wid = threadIdx.x >> 6;
  int lane = threadIdx.x & 63;
  int node = blockIdx.x * 4 + wid;
  if (node >= N_NODES) return;
  int c = lane * 3;
  float a0 = 0.f, a1 = 0.f, a2 = 0.f;
  int beg = rowptr[node], end = rowptr[node + 1];
  for (int j = beg; j < end; ++j) {
    int s = csr[j];
    const float* hp = h + (size_t)s * DIM_H + c;
    a0 += hp[0]; a1 += hp[1]; a2 += hp[2];
  }
  float ep = 1.f + eps[l];
  const float* hn = h + (size_t)node * DIM_H + c;
  float* o = outA + (size_t)node * DIM_H + c;
  o[0] = ep * hn[0] + a0;
  o[1] = ep * hn[1] + a1;
  o[2] = ep * hn[2] + a2;
}

// ---------------- fp32 GEMM: C[M,192] = A[M,K] @ W[K,192] + bias (opt relu). In-place safe (C==A). ----------------
template <int K, bool RELU>
__global__ __launch_bounds__(256) void k_gemm(const float* A, const float* __restrict__ W,
                                              const float* __restrict__ bias, float* C, int M) {
  __shared__ float As[16][132];   // transposed, stride 132 keeps float4 16B-aligned
  __shared__ float Bs[16][192];
  const int tid = threadIdx.x;
  const int block_row = blockIdx.x * 128;
  const int mt = tid >> 4, nt = tid & 15;
  const int r0 = mt * 8, c0 = nt * 12;
  float acc[8][12];
#pragma unroll
  for (int r = 0; r < 8; ++r)
#pragma unroll
    for (int c = 0; c < 12; ++c) acc[r][c] = 0.f;

  for (int kc = 0; kc < K; kc += 16) {
#pragma unroll
    for (int i = 0; i < 2; ++i) {
      int idx = tid + 256 * i;
      int row = idx >> 2;
      int kq = (idx & 3) * 4;
      int gr = block_row + row;
      gr = gr < M ? gr : M - 1;
      const float4 v = *(const float4*)(A + (size_t)gr * K + kc + kq);
      As[kq + 0][row] = v.x; As[kq + 1][row] = v.y;
      As[kq + 2][row] = v.z; As[kq + 3][row] = v.w;
    }
#pragma unroll
    for (int i = 0; i < 3; ++i) {
      int idx = tid + 256 * i;
      int kr = idx / 48;
      int cc = (idx % 48) * 4;
      *(float4*)&Bs[kr][cc] = *(const float4*)(W + (size_t)(kc + kr) * DIM_H + cc);
    }
    __syncthreads();
#pragma unroll
    for (int kk = 0; kk < 16; ++kk) {
      float4 A0 = *(const float4*)&As[kk][r0];
      float4 A1 = *(const float4*)&As[kk][r0 + 4];
      float4 B0 = *(const float4*)&Bs[kk][c0];
      float4 B1 = *(const float4*)&Bs[kk][c0 + 4];
      float4 B2 = *(const float4*)&Bs[kk][c0 + 8];
      float a[8] = {A0.x, A0.y, A0.z, A0.w, A1.x, A1.y, A1.z, A1.w};
      float b[12] = {B0.x, B0.y, B0.z, B0.w, B1.x, B1.y, B1.z, B1.w, B2.x, B2.y, B2.z, B2.w};
#pragma unroll
      for (int r = 0; r < 8; ++r)
#pragma unroll
        for (int c = 0; c < 12; ++c) acc[r][c] = fmaf(a[r], b[c], acc[r][c]);
    }
    __syncthreads();
  }
  float bb[12];
#pragma unroll
  for (int c = 0; c < 12; ++c) bb[c] = bias[c0 + c];
#pragma unroll
  for (int r = 0; r < 8; ++r) {
    int gr = block_row + r0 + r;
    if (gr < M) {
      float* cp = C + (size_t)gr * DIM_H + c0;
#pragma unroll
      for (int cq = 0; cq < 12; cq += 4) {
        float4 v;
        v.x = acc[r][cq + 0] + bb[cq + 0];
        v.y = acc[r][cq + 1] + bb[cq + 1];
        v.z = acc[r][cq + 2] + bb[cq + 2];
        v.w = acc[r][cq + 3] + bb[cq + 3];
        if (RELU) { v.x = relu_f(v.x); v.y = relu_f(v.y); v.z = relu_f(v.z); v.w = relu_f(v.w); }
        *(float4*)(cp + cq) = v;
      }
    }
  }
}

// ---------------- BN ----------------
__global__ void k_bn_stats(const float* __restrict__ v, float* __restrict__ stats) {
  int c = threadIdx.x;  // 192 threads
  float s = 0.f, sq = 0.f;
  for (int r = blockIdx.x; r < N_NODES; r += gridDim.x) {
    float x = v[(size_t)r * DIM_H + c];
    s += x; sq += x * x;
  }
  atomicAdd(&stats[c], s);
  atomicAdd(&stats[DIM_H + c], sq);
}

__global__ void k_bn_final(const float* __restrict__ stats, const float* __restrict__ g,
                           const float* __restrict__ b, float* __restrict__ coef) {
  int c = threadIdx.x;  // 192 threads
  float mu = stats[c] * (1.f / N_NODES);
  float var = stats[DIM_H + c] * (1.f / N_NODES) - mu * mu;
  float rs = rsqrtf(var + BN_EPSF);
  float sc = g[c] * rs;
  coef[c] = sc;
  coef[DIM_H + c] = b[c] - mu * sc;
}

__global__ void k_bn_apply(const float* __restrict__ v, const float* __restrict__ coef,
                           float* __restrict__ h) {
  __shared__ float sc[DIM_H], sh[DIM_H];
  if (threadIdx.x < DIM_H) {
    sc[threadIdx.x] = coef[threadIdx.x];
    sh[threadIdx.x] = coef[DIM_H + threadIdx.x];
  }
  __syncthreads();
  const int total4 = N_NODES * DIM_H / 4;
  for (int j = blockIdx.x * blockDim.x + threadIdx.x; j < total4; j += gridDim.x * blockDim.x) {
    float4 x = ((const float4*)v)[j];
    int c = (j * 4) % DIM_H;
    x.x = relu_f(x.x * sc[c + 0] + sh[c + 0]);
    x.y = relu_f(x.y * sc[c + 1] + sh[c + 1]);
    x.z = relu_f(x.z * sc[c + 2] + sh[c + 2]);
    x.w = relu_f(x.w * sc[c + 3] + sh[c + 3]);
    ((float4*)h)[j] = x;
  }
}

// ---------------- seed row projection: s2[a] = h[seed] @ W2[:,a] ----------------
__global__ void k_seed_s2(const float* __restrict__ h, const int* __restrict__ seedp,
                          const float* __restrict__ W2, float* __restrict__ s2) {
  int a = threadIdx.x;  // 192 threads
  int seed = seedp[0];
  const float* hs = h + (size_t)seed * DIM_H;
  float s = 0.f;
  for (int k = 0; k < DIM_H; ++k) s = fmaf(hs[k], W2[(size_t)k * DIM_H + a], s);
  s2[a] = s;
}

// ---------------- attention: e = leaky_relu( sum_a tanh((h@W1)_a + s2_a) * w_attn_a ) ----------------
__global__ __launch_bounds__(256) void k_attn(const float* __restrict__ h, const float* __restrict__ W1,
                                              const float* __restrict__ s2, const float* __restrict__ wat,
                                              float* __restrict__ e, int M) {
  __shared__ float As[16][132];
  __shared__ float Bs[16][192];
  __shared__ float part[128][17];
  const int tid = threadIdx.x;
  const int block_row = blockIdx.x * 128;
  const int mt = tid >> 4, nt = tid & 15;
  const int r0 = mt * 8, c0 = nt * 12;
  float acc[8][12];
#pragma unroll
  for (int r = 0; r < 8; ++r)
#pragma unroll
    for (int c = 0; c < 12; ++c) acc[r][c] = 0.f;

  for (int kc = 0; kc < DIM_H; kc += 16) {
#pragma unroll
    for (int i = 0; i < 2; ++i) {
      int idx = tid + 256 * i;
      int row = idx >> 2;
      int kq = (idx & 3) * 4;
      int gr = block_row + row;
      gr = gr < M ? gr : M - 1;
      const float4 v = *(const float4*)(h + (size_t)gr * DIM_H + kc + kq);
      As[kq + 0][row] = v.x; As[kq + 1][row] = v.y;
      As[kq + 2][row] = v.z; As[kq + 3][row] = v.w;
    }
#pragma unroll
    for (int i = 0; i < 3; ++i) {
      int idx = tid + 256 * i;
      int kr = idx / 48;
      int cc = (idx % 48) * 4;
      *(float4*)&Bs[kr][cc] = *(const float4*)(W1 + (size_t)(kc + kr) * DIM_H + cc);
    }
    __syncthreads();
#pragma unroll
    for (int kk = 0; kk < 16; ++kk) {
      float4 A0 = *(const float4*)&As[kk][r0];
      float4 A1 = *(const float4*)&As[kk][r0 + 4];
      float4 B0 = *(const float4*)&Bs[kk][c0];
      float4 B1 = *(const float4*)&Bs[kk][c0 + 4];
      float4 B2 = *(const float4*)&Bs[kk][c0 + 8];
      float a[8] = {A0.x, A0.y, A0.z, A0.w, A1.x, A1.y, A1.z, A1.w};
      float b[12] = {B0.x, B0.y, B0.z, B0.w, B1.x, B1.y, B1.z, B1.w, B2.x, B2.y, B2.z, B2.w};
#pragma unroll
      for (int r = 0; r < 8; ++r)
#pragma unroll
        for (int c = 0; c < 12; ++c) acc[r][c] = fmaf(a[r], b[c], acc[r][c]);
    }
    __syncthreads();
  }
  float s2v[12], wv[12];
#pragma unroll
  for (int c = 0; c < 12; ++c) { s2v[c] = s2[c0 + c]; wv[c] = wat[c0 + c]; }
#pragma unroll
  for (int r = 0; r < 8; ++r) {
    float p = 0.f;
#pragma unroll
    for (int c = 0; c < 12; ++c) p = fmaf(tanhf(acc[r][c] + s2v[c]), wv[c], p);
    part[r0 + r][nt] = p;
  }
  __syncthreads();
  if (tid < 128) {
    float s = 0.f;
#pragma unroll
    for (int j = 0; j < 16; ++j) s += part[tid][j];
    s = s > 0.f ? s : 0.2f * s;
    int gr = block_row + tid;
    if (gr < M) e[gr] = s;
  }
}

// ---------------- softmax + readout + logit ----------------
__global__ void k_max(const float* __restrict__ e, float* __restrict__ pmax) {
  __shared__ float buf[256];
  float m = -3.4e38f;
  for (int i = blockIdx.x * 256 + threadIdx.x; i < N_NODES; i += 256 * 256) m = fmaxf(m, e[i]);
  buf[threadIdx.x] = m;
  __syncthreads();
  for (int s = 128; s > 0; s >>= 1) {
    if (threadIdx.x < s) buf[threadIdx.x] = fmaxf(buf[threadIdx.x], buf[threadIdx.x + s]);
    __syncthreads();
  }
  if (threadIdx.x == 0) pmax[blockIdx.x] = buf[0];
}

__global__ void k_max2(const float* __restrict__ pmax, float* __restrict__ sc,
                       float* __restrict__ readout) {
  __shared__ float buf[256];
  buf[threadIdx.x] = pmax[threadIdx.x];
  __syncthreads();
  for (int s = 128; s > 0; s >>= 1) {
    if (threadIdx.x < s) buf[threadIdx.x] = fmaxf(buf[threadIdx.x], buf[threadIdx.x + s]);
    __syncthreads();
  }
  if (threadIdx.x == 0) { sc[0] = buf[0]; sc[1] = 0.f; }
  if (threadIdx.x < DIM_H) readout[threadIdx.x] = 0.f;
}

__global__ void k_sumexp(const float* __restrict__ e, float* __restrict__ sc) {
  __shared__ float buf[256];
  float gmax = sc[0];
  float s = 0.f;
  for (int i = blockIdx.x * 256 + threadIdx.x; i < N_NODES; i += 256 * 256) s += expf(e[i] - gmax);
  buf[threadIdx.x] = s;
  __syncthreads();
  for (int t = 128; t > 0; t >>= 1) {
    if (threadIdx.x < t) buf[threadIdx.x] += buf[threadIdx.x + t];
    __syncthreads();
  }
  if (threadIdx.x == 0) atomicAdd(&sc[1], buf[0]);
}

__global__ void k_alpha(const float* __restrict__ e, const float* __restrict__ sc,
                        float* __restrict__ alpha) {
  int i = blockIdx.x * 256 + threadIdx.x;
  if (i < N_NODES) alpha[i] = expf(e[i] - sc[0]) * (1.f / sc[1]);
}

__global__ void k_readout(const float* __restrict__ alpha, const float* __restrict__ h,
                          float* __restrict__ readout) {
  int c = threadIdx.x;  // 192 threads
  float s = 0.f;
  for (int r = blockIdx.x; r < N_NODES; r += gridDim.x) s = fmaf(alpha[r], h[(size_t)r * DIM_H + c], s);
  atomicAdd(&readout[c], s);
}

__global__ void k_logit(const float* __restrict__ readout, const float* __restrict__ cw,
                        const float* __restrict__ cb, float* __restrict__ out) {
  __shared__ float buf[256];
  int tid = threadIdx.x;
  buf[tid] = (tid < DIM_H) ? readout[tid] * cw[tid] : 0.f;
  __syncthreads();
  for (int s = 128; s > 0; s >>= 1) {
    if (tid < s) buf[tid] += buf[tid + s];
    __syncthreads();
  }
  if (tid == 0) out[0] = buf[0] + cb[0];
}

extern "C" void kernel_launch(void* const* d_in, const int* in_sizes, int n_in,
                              void* d_out, int out_size, void* d_ws, size_t ws_size,
                              hipStream_t stream) {
  const float* x      = (const float*)d_in[0];
  const int*   edge   = (const int*)d_in[1];
  const int*   seedp  = (const int*)d_in[2];
  const float* proj_w = (const float*)d_in[3];
  const float* proj_b = (const float*)d_in[4];
  const float* mlp1_w = (const float*)d_in[5];
  const float* mlp1_b = (const float*)d_in[6];
  const float* mlp2_w = (const float*)d_in[7];
  const float* mlp2_b = (const float*)d_in[8];
  const float* eps    = (const float*)d_in[9];
  const float* bn_g   = (const float*)d_in[10];
  const float* bn_b   = (const float*)d_in[11];
  const float* W1     = (const float*)d_in[12];
  const float* W2     = (const float*)d_in[13];
  const float* w_attn = (const float*)d_in[14];
  const float* cls_w  = (const float*)d_in[15];
  const float* cls_b  = (const float*)d_in[16];
  float* out = (float*)d_out;

  char* ws = (char*)d_ws;
  size_t off = 0;
  auto alloc = [&](size_t bytes) -> void* {
    void* p = ws + off;
    off = (off + bytes + 255) & ~(size_t)255;
    return p;
  };
  float* h      = (float*)alloc((size_t)N_NODES * DIM_H * 4);
  float* Abuf   = (float*)alloc((size_t)N_NODES * DIM_H * 4);
  float* ebuf   = (float*)alloc((size_t)N_NODES * 4);
  int* rowptr   = (int*)alloc((size_t)(N_NODES + 1) * 4);
  int* cursor   = (int*)alloc((size_t)N_NODES * 4);
  int* csr      = (int*)alloc((size_t)N_EDGES * 4);
  float* stats  = (float*)alloc(2 * DIM_H * 4);
  float* coef   = (float*)alloc(2 * DIM_H * 4);
  float* s2     = (float*)alloc(DIM_H * 4);
  float* pmax   = (float*)alloc(256 * 4);
  float* scal   = (float*)alloc(8 * 4);
  float* rdout  = (float*)alloc(DIM_H * 4);

  const int GEMM_GRID = (N_NODES + 127) / 128;  // 391

  // CSR build
  hipMemsetAsync(cursor, 0, (size_t)N_NODES * 4, stream);
  k_hist<<<(N_EDGES + 255) / 256, 256, 0, stream>>>(edge, cursor);
  k_scan<<<1, 1024, 0, stream>>>(cursor, rowptr);
  k_copy_int<<<(N_NODES + 255) / 256, 256, 0, stream>>>(rowptr, cursor, N_NODES);
  k_fill<<<(N_EDGES + 255) / 256, 256, 0, stream>>>(edge, cursor, csr);

  // projection
  k_gemm<DIM_IN, true><<<GEMM_GRID, 256, 0, stream>>>(x, proj_w, proj_b, h, N_NODES);

  // GIN layers
  for (int l = 0; l < N_LAYERS; ++l) {
    k_aggregate<<<N_NODES / 4, 256, 0, stream>>>(h, rowptr, csr, eps, l, Abuf);
    k_gemm<DIM_H, true><<<GEMM_GRID, 256, 0, stream>>>(
        Abuf, mlp1_w + (size_t)l * DIM_H * DIM_H, mlp1_b + (size_t)l * DIM_H, Abuf, N_NODES);
    k_gemm<DIM_H, false><<<GEMM_GRID, 256, 0, stream>>>(
        Abuf, mlp2_w + (size_t)l * DIM_H * DIM_H, mlp2_b + (size_t)l * DIM_H, Abuf, N_NODES);
    hipMemsetAsync(stats, 0, 2 * DIM_H * 4, stream);
    k_bn_stats<<<256, DIM_H, 0, stream>>>(Abuf, stats);
    k_bn_final<<<1, DIM_H, 0, stream>>>(stats, bn_g + (size_t)l * DIM_H, bn_b + (size_t)l * DIM_H, coef);
    k_bn_apply<<<2048, 256, 0, stream>>>(Abuf, coef, h);
  }

  // attention + softmax + readout
  k_seed_s2<<<1, DIM_H, 0, stream>>>(h, seedp, W2, s2);
  k_attn<<<GEMM_GRID, 256, 0, stream>>>(h, W1, s2, w_attn, ebuf, N_NODES);
  k_max<<<256, 256, 0, stream>>>(ebuf, pmax);
  k_max2<<<1, 256, 0, stream>>>(pmax, scal, rdout);
  k_sumexp<<<256, 256, 0, stream>>>(ebuf, scal);
  k_alpha<<<(N_NODES + 255) / 256, 256, 0, stream>>>(ebuf, scal, out + 1);
  k_readout<<<256, DIM_H, 0, stream>>>(out + 1, h, rdout);
  k_logit<<<1, 256, 0, stream>>>(rdout, cls_w, cls_b, out);
}

// Round 2
// 932.253 us; speedup vs baseline: 1.1184x; 1.1184x over previous
//
#include <hip/hip_runtime.h>

#define N_NODES 50000
#define N_EDGES 400000
#define DIM_IN  128
#define DIM_H   192
#define N_LAYERS 3
#define BN_EPSF 1e-5f
#define SCAN_NBLK 49  // ceil(50000/1024)

__device__ __forceinline__ float relu_f(float x) { return x > 0.f ? x : 0.f; }

// ---------------- CSR build ----------------
__global__ void k_hist(const int* __restrict__ edge, int* __restrict__ cnt) {
  int e = blockIdx.x * 256 + threadIdx.x;
  if (e < N_EDGES) atomicAdd(&cnt[edge[N_EDGES + e]], 1);
}

__global__ void k_scanA(const int* __restrict__ deg, int* __restrict__ part, int* __restrict__ bsum) {
  __shared__ int buf[1024];
  int g = blockIdx.x * 1024 + threadIdx.x;
  int v = (g < N_NODES) ? deg[g] : 0;
  buf[threadIdx.x] = v;
  __syncthreads();
  for (int off = 1; off < 1024; off <<= 1) {
    int t = (threadIdx.x >= off) ? buf[threadIdx.x - off] : 0;
    __syncthreads();
    buf[threadIdx.x] += t;
    __syncthreads();
  }
  if (g < N_NODES) part[g] = buf[threadIdx.x];
  if (threadIdx.x == 1023) bsum[blockIdx.x] = buf[1023];
}

__global__ void k_scanB(int* __restrict__ bsum) {
  __shared__ int b[64];
  int t = threadIdx.x;
  b[t] = (t < SCAN_NBLK) ? bsum[t] : 0;
  __syncthreads();
  for (int off = 1; off < 64; off <<= 1) {
    int v = (t >= off) ? b[t - off] : 0;
    __syncthreads();
    b[t] += v;
    __syncthreads();
  }
  if (t < SCAN_NBLK) bsum[t] = t ? b[t - 1] : 0;  // exclusive
}

__global__ void k_scanC(const int* __restrict__ part, const int* __restrict__ bsum,
                        int* __restrict__ rowptr) {
  int g = blockIdx.x * 256 + threadIdx.x;
  if (g == 0) rowptr[0] = 0;
  if (g < N_NODES) rowptr[g + 1] = part[g] + bsum[g >> 10];
}

__global__ void k_copy_int(const int* __restrict__ src, int* __restrict__ dst, int n) {
  int i = blockIdx.x * 256 + threadIdx.x;
  if (i < n) dst[i] = src[i];
}

__global__ void k_fill(const int* __restrict__ edge, int* __restrict__ cursor, int* __restrict__ csr) {
  int e = blockIdx.x * 256 + threadIdx.x;
  if (e < N_EDGES) {
    int s = edge[e];
    int d = edge[N_EDGES + e];
    int pos = atomicAdd(&cursor[d], 1);
    csr[pos] = s;
  }
}

// ---------------- aggregation with optional fused BN+ReLU on the fly ----------------
// outA[i] = (1+eps)*f(z[i]) + sum_{j->i} f(z[j]),  f = BN? relu(z*sc+sh) : identity
template <bool BN>
__global__ void k_agg(const float* __restrict__ z, const int* __restrict__ rowptr,
                      const int* __restrict__ csr, const float* __restrict__ coef,
                      const float* __restrict__ eps, int l, float* __restrict__ outA) {
  int wid = threadIdx.x >> 6;
  int lane = threadIdx.x & 63;
  int node = blockIdx.x * 4 + wid;
  if (node >= N_NODES) return;
  int c = lane * 3;
  float sc0 = 1.f, sc1 = 1.f, sc2 = 1.f, sh0 = 0.f, sh1 = 0.f, sh2 = 0.f;
  if (BN) {
    sc0 = coef[c]; sc1 = coef[c + 1]; sc2 = coef[c + 2];
    sh0 = coef[DIM_H + c]; sh1 = coef[DIM_H + c + 1]; sh2 = coef[DIM_H + c + 2];
  }
  float a0 = 0.f, a1 = 0.f, a2 = 0.f;
  int beg = rowptr[node], end = rowptr[node + 1];
  int j = beg;
#define ACCROW(S)                                                       \
  {                                                                     \
    const float* p = z + (size_t)(S)*DIM_H + c;                         \
    float v0 = p[0], v1 = p[1], v2 = p[2];                              \
    if (BN) {                                                           \
      v0 = relu_f(v0 * sc0 + sh0);                                      \
      v1 = relu_f(v1 * sc1 + sh1);                                      \
      v2 = relu_f(v2 * sc2 + sh2);                                      \
    }                                                                   \
    a0 += v0; a1 += v1; a2 += v2;                                       \
  }
  for (; j + 4 <= end; j += 4) {
    int s0 = csr[j], s1 = csr[j + 1], s2 = csr[j + 2], s3 = csr[j + 3];
    ACCROW(s0) ACCROW(s1) ACCROW(s2) ACCROW(s3)
  }
  for (; j < end; ++j) {
    int s = csr[j];
    ACCROW(s)
  }
#undef ACCROW
  float ep = 1.f + eps[l];
  const float* p = z + (size_t)node * DIM_H + c;
  float v0 = p[0], v1 = p[1], v2 = p[2];
  if (BN) {
    v0 = relu_f(v0 * sc0 + sh0);
    v1 = relu_f(v1 * sc1 + sh1);
    v2 = relu_f(v2 * sc2 + sh2);
  }
  float* o = outA + (size_t)node * DIM_H + c;
  o[0] = ep * v0 + a0;
  o[1] = ep * v1 + a1;
  o[2] = ep * v2 + a2;
}

// ---------------- standalone GEMM (proj): C = relu(A[M,K] @ W[K,192] + b), BM=64 ----------------
template <int K, bool RELU>
__global__ __launch_bounds__(256) void k_gemm64(const float* __restrict__ A, const float* __restrict__ W,
                                                const float* __restrict__ bias, float* __restrict__ C,
                                                int M) {
  __shared__ float As[16][64];
  __shared__ float Ws[16][192];
  const int tid = threadIdx.x;
  const int block_row = blockIdx.x * 64;
  const int mt = tid >> 4, nt = tid & 15;
  const int r0 = mt * 4, c0 = nt * 12;
  float acc[4][12];
#pragma unroll
  for (int r = 0; r < 4; ++r)
#pragma unroll
    for (int c = 0; c < 12; ++c) acc[r][c] = 0.f;

  for (int kc = 0; kc < K; kc += 16) {
    {
      int row = tid >> 2;
      int kq = (tid & 3) * 4;
      int gr = block_row + row;
      gr = gr < M ? gr : M - 1;
      const float4 v = *(const float4*)(A + (size_t)gr * K + kc + kq);
      As[kq + 0][row] = v.x; As[kq + 1][row] = v.y;
      As[kq + 2][row] = v.z; As[kq + 3][row] = v.w;
    }
#pragma unroll
    for (int i = 0; i < 3; ++i) {
      int idx = tid + 256 * i;
      int kr = idx / 48;
      int cc = (idx % 48) * 4;
      *(float4*)&Ws[kr][cc] = *(const float4*)(W + (size_t)(kc + kr) * DIM_H + cc);
    }
    __syncthreads();
#pragma unroll
    for (int kk = 0; kk < 16; ++kk) {
      float4 A0 = *(const float4*)&As[kk][r0];
      float4 B0 = *(const float4*)&Ws[kk][c0];
      float4 B1 = *(const float4*)&Ws[kk][c0 + 4];
      float4 B2 = *(const float4*)&Ws[kk][c0 + 8];
      float a[4] = {A0.x, A0.y, A0.z, A0.w};
      float b[12] = {B0.x, B0.y, B0.z, B0.w, B1.x, B1.y, B1.z, B1.w, B2.x, B2.y, B2.z, B2.w};
#pragma unroll
      for (int r = 0; r < 4; ++r)
#pragma unroll
        for (int c = 0; c < 12; ++c) acc[r][c] = fmaf(a[r], b[c], acc[r][c]);
    }
    __syncthreads();
  }
  float bb[12];
#pragma unroll
  for (int c = 0; c < 12; ++c) bb[c] = bias[c0 + c];
#pragma unroll
  for (int r = 0; r < 4; ++r) {
    int gr = block_row + r0 + r;
    if (gr < M) {
      float* cp = C + (size_t)gr * DIM_H + c0;
#pragma unroll
      for (int cq = 0; cq < 12; cq += 4) {
        float4 v;
        v.x = acc[r][cq + 0] + bb[cq + 0];
        v.y = acc[r][cq + 1] + bb[cq + 1];
        v.z = acc[r][cq + 2] + bb[cq + 2];
        v.w = acc[r][cq + 3] + bb[cq + 3];
        if (RELU) { v.x = relu_f(v.x); v.y = relu_f(v.y); v.z = relu_f(v.z); v.w = relu_f(v.w); }
        *(float4*)(cp + cq) = v;
      }
    }
  }
}

// ---------------- fused MLP: Z = relu(A@W1+b1)@W2+b2, plus BN column-stat partials ----------------
// In-place safe (Z may alias A). LDS exactly 64 KB.
__global__ __launch_bounds__(256) void k_mlp_fused(const float* __restrict__ A,
                                                   const float* __restrict__ W1, const float* __restrict__ b1,
                                                   const float* __restrict__ W2, const float* __restrict__ b2,
                                                   float* __restrict__ Z, float* __restrict__ stats) {
  __shared__ float As[16][64];     // 4 KB
  __shared__ float Ws[16][192];    // 12 KB
  __shared__ float zT[192][64];    // 48 KB, z transposed
  const int tid = threadIdx.x;
  const int block_row = blockIdx.x * 64;
  const int mt = tid >> 4, nt = tid & 15;
  const int r0 = mt * 4, c0 = nt * 12;
  float acc[4][12];
#pragma unroll
  for (int r = 0; r < 4; ++r)
#pragma unroll
    for (int c = 0; c < 12; ++c) acc[r][c] = 0.f;

  // ---- stage 1: z = relu(A @ W1 + b1) ----
  for (int kc = 0; kc < DIM_H; kc += 16) {
    {
      int row = tid >> 2;
      int kq = (tid & 3) * 4;
      int gr = block_row + row;
      gr = gr < N_NODES ? gr : N_NODES - 1;
      const float4 v = *(const float4*)(A + (size_t)gr * DIM_H + kc + kq);
      As[kq + 0][row] = v.x; As[kq + 1][row] = v.y;
      As[kq + 2][row] = v.z; As[kq + 3][row] = v.w;
    }
#pragma unroll
    for (int i = 0; i < 3; ++i) {
      int idx = tid + 256 * i;
      int kr = idx / 48;
      int cc = (idx % 48) * 4;
      *(float4*)&Ws[kr][cc] = *(const float4*)(W1 + (size_t)(kc + kr) * DIM_H + cc);
    }
    __syncthreads();
#pragma unroll
    for (int kk = 0; kk < 16; ++kk) {
      float4 A0 = *(const float4*)&As[kk][r0];
      float4 B0 = *(const float4*)&Ws[kk][c0];
      float4 B1 = *(const float4*)&Ws[kk][c0 + 4];
      float4 B2 = *(const float4*)&Ws[kk][c0 + 8];
      float a[4] = {A0.x, A0.y, A0.z, A0.w};
      float b[12] = {B0.x, B0.y, B0.z, B0.w, B1.x, B1.y, B1.z, B1.w, B2.x, B2.y, B2.z, B2.w};
#pragma unroll
      for (int r = 0; r < 4; ++r)
#pragma unroll
        for (int c = 0; c < 12; ++c) acc[r][c] = fmaf(a[r], b[c], acc[r][c]);
    }
    __syncthreads();
  }
  // epilogue 1: relu + bias -> zT
#pragma unroll
  for (int c = 0; c < 12; ++c) {
    float bb = b1[c0 + c];
    float4 v;
    v.x = relu_f(acc[0][c] + bb);
    v.y = relu_f(acc[1][c] + bb);
    v.z = relu_f(acc[2][c] + bb);
    v.w = relu_f(acc[3][c] + bb);
    *(float4*)&zT[c0 + c][r0] = v;
  }
  __syncthreads();

  // ---- stage 2: out = z @ W2 + b2 ----
#pragma unroll
  for (int r = 0; r < 4; ++r)
#pragma unroll
    for (int c = 0; c < 12; ++c) acc[r][c] = 0.f;
  for (int kc = 0; kc < DIM_H; kc += 16) {
#pragma unroll
    for (int i = 0; i < 3; ++i) {
      int idx = tid + 256 * i;
      int kr = idx / 48;
      int cc = (idx % 48) * 4;
      *(float4*)&Ws[kr][cc] = *(const float4*)(W2 + (size_t)(kc + kr) * DIM_H + cc);
    }
    __syncthreads();
#pragma unroll
    for (int kk = 0; kk < 16; ++kk) {
      float4 A0 = *(const float4*)&zT[kc + kk][r0];
      float4 B0 = *(const float4*)&Ws[kk][c0];
      float4 B1 = *(const float4*)&Ws[kk][c0 + 4];
      float4 B2 = *(const float4*)&Ws[kk][c0 + 8];
      float a[4] = {A0.x, A0.y, A0.z, A0.w};
      float b[12] = {B0.x, B0.y, B0.z, B0.w, B1.x, B1.y, B1.z, B1.w, B2.x, B2.y, B2.z, B2.w};
#pragma unroll
      for (int r = 0; r < 4; ++r)
#pragma unroll
        for (int c = 0; c < 12; ++c) acc[r][c] = fmaf(a[r], b[c], acc[r][c]);
    }
    __syncthreads();
  }
  // epilogue 2: bias, store, BN partial stats
  float s[12], q[12];
#pragma unroll
  for (int c = 0; c < 12; ++c) {
    s[c] = 0.f; q[c] = 0.f;
    acc[0][c] += b2[c0 + c];
    acc[1][c] += b2[c0 + c];
    acc[2][c] += b2[c0 + c];
    acc[3][c] += b2[c0 + c];
  }
#pragma unroll
  for (int r = 0; r < 4; ++r) {
    int gr = block_row + r0 + r;
    if (gr < N_NODES) {
      float* cp = Z + (size_t)gr * DIM_H + c0;
#pragma unroll
      for (int cq = 0; cq < 12; cq += 4) {
        float4 v;
        v.x = acc[r][cq + 0]; v.y = acc[r][cq + 1];
        v.z = acc[r][cq + 2]; v.w = acc[r][cq + 3];
        *(float4*)(cp + cq) = v;
      }
#pragma unroll
      for (int c = 0; c < 12; ++c) {
        float v = acc[r][c];
        s[c] += v; q[c] += v * v;
      }
    }
  }
  __syncthreads();  // zT reads done; reuse as reduction scratch
  float* ps = &zT[0][0];            // [16][192]
  float* pq = ps + 16 * DIM_H;      // [16][192]
#pragma unroll
  for (int c = 0; c < 12; ++c) {
    ps[mt * DIM_H + c0 + c] = s[c];
    pq[mt * DIM_H + c0 + c] = q[c];
  }
  __syncthreads();
  if (tid < DIM_H) {
    float ts = 0.f, tq = 0.f;
#pragma unroll
    for (int m = 0; m < 16; ++m) {
      ts += ps[m * DIM_H + tid];
      tq += pq[m * DIM_H + tid];
    }
    atomicAdd(&stats[tid], ts);
    atomicAdd(&stats[DIM_H + tid], tq);
  }
}

// ---------------- BN finalize + final apply ----------------
__global__ void k_bn_final(const float* __restrict__ stats, const float* __restrict__ g,
                           const float* __restrict__ b, float* __restrict__ coef) {
  int c = threadIdx.x;  // 192 threads
  float mu = stats[c] * (1.f / N_NODES);
  float var = stats[DIM_H + c] * (1.f / N_NODES) - mu * mu;
  float rs = rsqrtf(var + BN_EPSF);
  float sc = g[c] * rs;
  coef[c] = sc;
  coef[DIM_H + c] = b[c] - mu * sc;
}

__global__ void k_bn_apply(const float* __restrict__ v, const float* __restrict__ coef,
                           float* __restrict__ h) {
  __shared__ float sc[DIM_H], sh[DIM_H];
  if (threadIdx.x < DIM_H) {
    sc[threadIdx.x] = coef[threadIdx.x];
    sh[threadIdx.x] = coef[DIM_H + threadIdx.x];
  }
  __syncthreads();
  const int total4 = N_NODES * DIM_H / 4;
  for (int j = blockIdx.x * blockDim.x + threadIdx.x; j < total4; j += gridDim.x * blockDim.x) {
    float4 x = ((const float4*)v)[j];
    int c = (j * 4) % DIM_H;
    x.x = relu_f(x.x * sc[c + 0] + sh[c + 0]);
    x.y = relu_f(x.y * sc[c + 1] + sh[c + 1]);
    x.z = relu_f(x.z * sc[c + 2] + sh[c + 2]);
    x.w = relu_f(x.w * sc[c + 3] + sh[c + 3]);
    ((float4*)h)[j] = x;
  }
}

// ---------------- seed row projection ----------------
__global__ void k_seed_s2(const float* __restrict__ h, const int* __restrict__ seedp,
                          const float* __restrict__ W2, float* __restrict__ s2) {
  int a = threadIdx.x;  // 192 threads
  int seed = seedp[0];
  const float* hs = h + (size_t)seed * DIM_H;
  float s = 0.f;
  for (int k = 0; k < DIM_H; ++k) s = fmaf(hs[k], W2[(size_t)k * DIM_H + a], s);
  s2[a] = s;
}

// ---------------- attention scores ----------------
__global__ __launch_bounds__(256) void k_attn(const float* __restrict__ h, const float* __restrict__ W1,
                                              const float* __restrict__ s2, const float* __restrict__ wat,
                                              float* __restrict__ e, int M) {
  __shared__ float As[16][64];
  __shared__ float Ws[16][192];
  __shared__ float part[64][17];
  const int tid = threadIdx.x;
  const int block_row = blockIdx.x * 64;
  const int mt = tid >> 4, nt = tid & 15;
  const int r0 = mt * 4, c0 = nt * 12;
  float acc[4][12];
#pragma unroll
  for (int r = 0; r < 4; ++r)
#pragma unroll
    for (int c = 0; c < 12; ++c) acc[r][c] = 0.f;

  for (int kc = 0; kc < DIM_H; kc += 16) {
    {
      int row = tid >> 2;
      int kq = (tid & 3) * 4;
      int gr = block_row + row;
      gr = gr < M ? gr : M - 1;
      const float4 v = *(const float4*)(h + (size_t)gr * DIM_H + kc + kq);
      As[kq + 0][row] = v.x; As[kq + 1][row] = v.y;
      As[kq + 2][row] = v.z; As[kq + 3][row] = v.w;
    }
#pragma unroll
    for (int i = 0; i < 3; ++i) {
      int idx = tid + 256 * i;
      int kr = idx / 48;
      int cc = (idx % 48) * 4;
      *(float4*)&Ws[kr][cc] = *(const float4*)(W1 + (size_t)(kc + kr) * DIM_H + cc);
    }
    __syncthreads();
#pragma unroll
    for (int kk = 0; kk < 16; ++kk) {
      float4 A0 = *(const float4*)&As[kk][r0];
      float4 B0 = *(const float4*)&Ws[kk][c0];
      float4 B1 = *(const float4*)&Ws[kk][c0 + 4];
      float4 B2 = *(const float4*)&Ws[kk][c0 + 8];
      float a[4] = {A0.x, A0.y, A0.z, A0.w};
      float b[12] = {B0.x, B0.y, B0.z, B0.w, B1.x, B1.y, B1.z, B1.w, B2.x, B2.y, B2.z, B2.w};
#pragma unroll
      for (int r = 0; r < 4; ++r)
#pragma unroll
        for (int c = 0; c < 12; ++c) acc[r][c] = fmaf(a[r], b[c], acc[r][c]);
    }
    __syncthreads();
  }
  float s2v[12], wv[12];
#pragma unroll
  for (int c = 0; c < 12; ++c) { s2v[c] = s2[c0 + c]; wv[c] = wat[c0 + c]; }
#pragma unroll
  for (int r = 0; r < 4; ++r) {
    float p = 0.f;
#pragma unroll
    for (int c = 0; c < 12; ++c) p = fmaf(tanhf(acc[r][c] + s2v[c]), wv[c], p);
    part[r0 + r][nt] = p;
  }
  __syncthreads();
  if (tid < 64) {
    float sv = 0.f;
#pragma unroll
    for (int j = 0; j < 16; ++j) sv += part[tid][j];
    sv = sv > 0.f ? sv : 0.2f * sv;
    int gr = block_row + tid;
    if (gr < M) e[gr] = sv;
  }
}

// ---------------- softmax + readout + logit ----------------
__global__ void k_max(const float* __restrict__ e, float* __restrict__ pmax) {
  __shared__ float buf[256];
  float m = -3.4e38f;
  for (int i = blockIdx.x * 256 + threadIdx.x; i < N_NODES; i += 256 * 256) m = fmaxf(m, e[i]);
  buf[threadIdx.x] = m;
  __syncthreads();
  for (int s = 128; s > 0; s >>= 1) {
    if (threadIdx.x < s) buf[threadIdx.x] = fmaxf(buf[threadIdx.x], buf[threadIdx.x + s]);
    __syncthreads();
  }
  if (threadIdx.x == 0) pmax[blockIdx.x] = buf[0];
}

__global__ void k_max2(const float* __restrict__ pmax, float* __restrict__ sc,
                       float* __restrict__ readout) {
  __shared__ float buf[256];
  buf[threadIdx.x] = pmax[threadIdx.x];
  __syncthreads();
  for (int s = 128; s > 0; s >>= 1) {
    if (threadIdx.x < s) buf[threadIdx.x] = fmaxf(buf[threadIdx.x], buf[threadIdx.x + s]);
    __syncthreads();
  }
  if (threadIdx.x == 0) { sc[0] = buf[0]; sc[1] = 0.f; }
  if (threadIdx.x < DIM_H) readout[threadIdx.x] = 0.f;
}

__global__ void k_sumexp(const float* __restrict__ e, float* __restrict__ sc) {
  __shared__ float buf[256];
  float gmax = sc[0];
  float s = 0.f;
  for (int i = blockIdx.x * 256 + threadIdx.x; i < N_NODES; i += 256 * 256) s += expf(e[i] - gmax);
  buf[threadIdx.x] = s;
  __syncthreads();
  for (int t = 128; t > 0; t >>= 1) {
    if (threadIdx.x < t) buf[threadIdx.x] += buf[threadIdx.x + t];
    __syncthreads();
  }
  if (threadIdx.x == 0) atomicAdd(&sc[1], buf[0]);
}

__global__ void k_alpha(const float* __restrict__ e, const float* __restrict__ sc,
                        float* __restrict__ alpha) {
  int i = blockIdx.x * 256 + threadIdx.x;
  if (i < N_NODES) alpha[i] = expf(e[i] - sc[0]) * (1.f / sc[1]);
}

__global__ void k_readout(const float* __restrict__ alpha, const float* __restrict__ h,
                          float* __restrict__ readout) {
  int c = threadIdx.x;  // 192 threads
  float s = 0.f;
  for (int r = blockIdx.x; r < N_NODES; r += gridDim.x) s = fmaf(alpha[r], h[(size_t)r * DIM_H + c], s);
  atomicAdd(&readout[c], s);
}

__global__ void k_logit(const float* __restrict__ readout, const float* __restrict__ cw,
                        const float* __restrict__ cb, float* __restrict__ out) {
  __shared__ float buf[256];
  int tid = threadIdx.x;
  buf[tid] = (tid < DIM_H) ? readout[tid] * cw[tid] : 0.f;
  __syncthreads();
  for (int s = 128; s > 0; s >>= 1) {
    if (tid < s) buf[tid] += buf[tid + s];
    __syncthreads();
  }
  if (tid == 0) out[0] = buf[0] + cb[0];
}

extern "C" void kernel_launch(void* const* d_in, const int* in_sizes, int n_in,
                              void* d_out, int out_size, void* d_ws, size_t ws_size,
                              hipStream_t stream) {
  const float* x      = (const float*)d_in[0];
  const int*   edge   = (const int*)d_in[1];
  const int*   seedp  = (const int*)d_in[2];
  const float* proj_w = (const float*)d_in[3];
  const float* proj_b = (const float*)d_in[4];
  const float* mlp1_w = (const float*)d_in[5];
  const float* mlp1_b = (const float*)d_in[6];
  const float* mlp2_w = (const float*)d_in[7];
  const float* mlp2_b = (const float*)d_in[8];
  const float* eps    = (const float*)d_in[9];
  const float* bn_g   = (const float*)d_in[10];
  const float* bn_b   = (const float*)d_in[11];
  const float* W1     = (const float*)d_in[12];
  const float* W2     = (const float*)d_in[13];
  const float* w_attn = (const float*)d_in[14];
  const float* cls_w  = (const float*)d_in[15];
  const float* cls_b  = (const float*)d_in[16];
  float* out = (float*)d_out;

  char* ws = (char*)d_ws;
  size_t off = 0;
  auto alloc = [&](size_t bytes) -> void* {
    void* p = ws + off;
    off = (off + bytes + 255) & ~(size_t)255;
    return p;
  };
  float* bufP   = (float*)alloc((size_t)N_NODES * DIM_H * 4);
  float* bufQ   = (float*)alloc((size_t)N_NODES * DIM_H * 4);
  float* ebuf   = (float*)alloc((size_t)N_NODES * 4);
  int* rowptr   = (int*)alloc((size_t)(N_NODES + 1) * 4);
  int* cursor   = (int*)alloc((size_t)N_NODES * 4);
  int* csr      = (int*)alloc((size_t)N_EDGES * 4);
  int* part     = (int*)alloc((size_t)N_NODES * 4);
  int* bsum     = (int*)alloc(64 * 4);
  float* stats  = (float*)alloc(2 * DIM_H * 4);
  float* coef   = (float*)alloc(2 * DIM_H * 4);
  float* s2     = (float*)alloc(DIM_H * 4);
  float* pmax   = (float*)alloc(256 * 4);
  float* scal   = (float*)alloc(8 * 4);
  float* rdout  = (float*)alloc(DIM_H * 4);

  const int GRID64 = (N_NODES + 63) / 64;  // 782

  // CSR build
  hipMemsetAsync(cursor, 0, (size_t)N_NODES * 4, stream);
  k_hist<<<(N_EDGES + 255) / 256, 256, 0, stream>>>(edge, cursor);
  k_scanA<<<SCAN_NBLK, 1024, 0, stream>>>(cursor, part, bsum);
  k_scanB<<<1, 64, 0, stream>>>(bsum);
  k_scanC<<<(N_NODES + 255) / 256, 256, 0, stream>>>(part, bsum, rowptr);
  k_copy_int<<<(N_NODES + 255) / 256, 256, 0, stream>>>(rowptr, cursor, N_NODES);
  k_fill<<<(N_EDGES + 255) / 256, 256, 0, stream>>>(edge, cursor, csr);

  // projection: x -> bufP (relu'd h0)
  k_gemm64<DIM_IN, true><<<GRID64, 256, 0, stream>>>(x, proj_w, proj_b, bufP, N_NODES);

  // GIN layers (ping-pong P/Q; BN+relu folded into next gather for l=0,1)
  float* cur = bufP;   // holds f-applied h for l=0 (already relu'd), or pre-BN z with coef for l>=1
  float* nxt = bufQ;
  for (int l = 0; l < N_LAYERS; ++l) {
    if (l == 0)
      k_agg<false><<<N_NODES / 4, 256, 0, stream>>>(cur, rowptr, csr, coef, eps, l, nxt);
    else
      k_agg<true><<<N_NODES / 4, 256, 0, stream>>>(cur, rowptr, csr, coef, eps, l, nxt);
    hipMemsetAsync(stats, 0, 2 * DIM_H * 4, stream);
    k_mlp_fused<<<GRID64, 256, 0, stream>>>(
        nxt, mlp1_w + (size_t)l * DIM_H * DIM_H, mlp1_b + (size_t)l * DIM_H,
        mlp2_w + (size_t)l * DIM_H * DIM_H, mlp2_b + (size_t)l * DIM_H, nxt, stats);
    k_bn_final<<<1, DIM_H, 0, stream>>>(stats, bn_g + (size_t)l * DIM_H, bn_b + (size_t)l * DIM_H, coef);
    // swap: nxt now holds pre-BN z_l (+ coef)
    float* t = cur; cur = nxt; nxt = t;
  }
  // materialize final h = relu(BN(z2)) into nxt
  k_bn_apply<<<2048, 256, 0, stream>>>(cur, coef, nxt);
  float* hfin = nxt;

  // attention + softmax + readout
  k_seed_s2<<<1, DIM_H, 0, stream>>>(hfin, seedp, W2, s2);
  k_attn<<<GRID64, 256, 0, stream>>>(hfin, W1, s2, w_attn, ebuf, N_NODES);
  k_max<<<256, 256, 0, stream>>>(ebuf, pmax);
  k_max2<<<1, 256, 0, stream>>>(pmax, scal, rdout);
  k_sumexp<<<256, 256, 0, stream>>>(ebuf, scal);
  k_alpha<<<(N_NODES + 255) / 256, 256, 0, stream>>>(ebuf, scal, out + 1);
  k_readout<<<256, DIM_H, 0, stream>>>(out + 1, hfin, rdout);
  k_logit<<<1, 256, 0, stream>>>(rdout, cls_w, cls_b, out);
}

// Round 3
// 542.307 us; speedup vs baseline: 1.9225x; 1.7191x over previous
//
#include <hip/hip_runtime.h>
#include <hip/hip_bf16.h>

#define N_NODES 50000
#define N_EDGES 400000
#define DIM_IN  128
#define DIM_H   192
#define N_LAYERS 3
#define BN_EPSF 1e-5f
#define SCAN_NBLK 49  // ceil(50000/1024)

typedef __attribute__((ext_vector_type(8))) short short8;
typedef __attribute__((ext_vector_type(4))) float floatx4;

union FragU { uint4 u; short8 s; };

__device__ __forceinline__ float relu_f(float x) { return x > 0.f ? x : 0.f; }
__device__ __forceinline__ unsigned short f2bf(float x) {
  __hip_bfloat16 h = __float2bfloat16(x);
  return *reinterpret_cast<unsigned short*>(&h);
}
__device__ __forceinline__ float bf2f(unsigned short b) {
  __hip_bfloat16 h;
  *reinterpret_cast<unsigned short*>(&h) = b;
  return __bfloat162float(h);
}

// ---------------- CSR build ----------------
__global__ void k_hist(const int* __restrict__ edge, int* __restrict__ cnt) {
  int e = blockIdx.x * 256 + threadIdx.x;
  if (e < N_EDGES) atomicAdd(&cnt[edge[N_EDGES + e]], 1);
}

__global__ void k_scanA(const int* __restrict__ deg, int* __restrict__ part, int* __restrict__ bsum) {
  __shared__ int buf[1024];
  int g = blockIdx.x * 1024 + threadIdx.x;
  int v = (g < N_NODES) ? deg[g] : 0;
  buf[threadIdx.x] = v;
  __syncthreads();
  for (int off = 1; off < 1024; off <<= 1) {
    int t = (threadIdx.x >= off) ? buf[threadIdx.x - off] : 0;
    __syncthreads();
    buf[threadIdx.x] += t;
    __syncthreads();
  }
  if (g < N_NODES) part[g] = buf[threadIdx.x];
  if (threadIdx.x == 1023) bsum[blockIdx.x] = buf[1023];
}

__global__ void k_scanB(int* __restrict__ bsum) {
  __shared__ int b[64];
  int t = threadIdx.x;
  b[t] = (t < SCAN_NBLK) ? bsum[t] : 0;
  __syncthreads();
  for (int off = 1; off < 64; off <<= 1) {
    int v = (t >= off) ? b[t - off] : 0;
    __syncthreads();
    b[t] += v;
    __syncthreads();
  }
  if (t < SCAN_NBLK) bsum[t] = t ? b[t - 1] : 0;  // exclusive
}

__global__ void k_scanC(const int* __restrict__ part, const int* __restrict__ bsum,
                        int* __restrict__ rowptr) {
  int g = blockIdx.x * 256 + threadIdx.x;
  if (g == 0) rowptr[0] = 0;
  if (g < N_NODES) rowptr[g + 1] = part[g] + bsum[g >> 10];
}

__global__ void k_copy_int(const int* __restrict__ src, int* __restrict__ dst, int n) {
  int i = blockIdx.x * 256 + threadIdx.x;
  if (i < n) dst[i] = src[i];
}

__global__ void k_fill(const int* __restrict__ edge, int* __restrict__ cursor, int* __restrict__ csr) {
  int e = blockIdx.x * 256 + threadIdx.x;
  if (e < N_EDGES) {
    int s = edge[e];
    int d = edge[N_EDGES + e];
    int pos = atomicAdd(&cursor[d], 1);
    csr[pos] = s;
  }
}

// ---------------- weight transpose + bf16 convert: W[K][192] f32 -> WT[192][K] bf16 ----------------
template <int K>
__global__ void k_wt(const float* __restrict__ W, unsigned short* __restrict__ WT) {
  __shared__ float t[32][33];
  int bk = blockIdx.x % (K / 32);
  int bn = blockIdx.x / (K / 32);
  int lx = threadIdx.x & 31, ly = threadIdx.x >> 5;  // 32x8
#pragma unroll
  for (int i = 0; i < 4; ++i) {
    int k = bk * 32 + ly + i * 8;
    int n = bn * 32 + lx;
    t[ly + i * 8][lx] = W[(size_t)k * DIM_H + n];
  }
  __syncthreads();
#pragma unroll
  for (int i = 0; i < 4; ++i) {
    int n = bn * 32 + ly + i * 8;
    int k = bk * 32 + lx;
    WT[(size_t)n * K + k] = f2bf(t[lx][ly + i * 8]);
  }
}

// ---------------- aggregation (bf16 in/out, optional fused BN+ReLU) ----------------
template <bool BN>
__global__ void k_agg(const unsigned short* __restrict__ z, const int* __restrict__ rowptr,
                      const int* __restrict__ csr, const float* __restrict__ coef,
                      const float* __restrict__ eps, int l, unsigned short* __restrict__ outA) {
  int wid = threadIdx.x >> 6;
  int lane = threadIdx.x & 63;
  int node = blockIdx.x * 4 + wid;
  if (node >= N_NODES) return;
  int c = lane * 3;
  float sc0 = 1.f, sc1 = 1.f, sc2 = 1.f, sh0 = 0.f, sh1 = 0.f, sh2 = 0.f;
  if (BN) {
    sc0 = coef[c]; sc1 = coef[c + 1]; sc2 = coef[c + 2];
    sh0 = coef[DIM_H + c]; sh1 = coef[DIM_H + c + 1]; sh2 = coef[DIM_H + c + 2];
  }
  float a0 = 0.f, a1 = 0.f, a2 = 0.f;
  int beg = rowptr[node], end = rowptr[node + 1];
  int j = beg;
#define ACCROW(S)                                                       \
  {                                                                     \
    const unsigned short* p = z + (size_t)(S)*DIM_H + c;                \
    float v0 = bf2f(p[0]), v1 = bf2f(p[1]), v2 = bf2f(p[2]);            \
    if (BN) {                                                           \
      v0 = relu_f(v0 * sc0 + sh0);                                      \
      v1 = relu_f(v1 * sc1 + sh1);                                      \
      v2 = relu_f(v2 * sc2 + sh2);                                      \
    }                                                                   \
    a0 += v0; a1 += v1; a2 += v2;                                       \
  }
  for (; j + 4 <= end; j += 4) {
    int s0 = csr[j], s1 = csr[j + 1], s2 = csr[j + 2], s3 = csr[j + 3];
    ACCROW(s0) ACCROW(s1) ACCROW(s2) ACCROW(s3)
  }
  for (; j < end; ++j) {
    int s = csr[j];
    ACCROW(s)
  }
#undef ACCROW
  float ep = 1.f + eps[l];
  const unsigned short* p = z + (size_t)node * DIM_H + c;
  float v0 = bf2f(p[0]), v1 = bf2f(p[1]), v2 = bf2f(p[2]);
  if (BN) {
    v0 = relu_f(v0 * sc0 + sh0);
    v1 = relu_f(v1 * sc1 + sh1);
    v2 = relu_f(v2 * sc2 + sh2);
  }
  unsigned short* o = outA + (size_t)node * DIM_H + c;
  o[0] = f2bf(ep * v0 + a0);
  o[1] = f2bf(ep * v1 + a1);
  o[2] = f2bf(ep * v2 + a2);
}

// ---------------- MFMA projection: C = relu(x_f32[M,128] @ Wt^T + b) -> bf16 ----------------
__global__ __launch_bounds__(256) void k_proj(const float* __restrict__ A,
                                              const unsigned short* __restrict__ WT,
                                              const float* __restrict__ bias,
                                              unsigned short* __restrict__ C) {
  constexpr int K = DIM_IN, KFR = K / 8, KS = K / 32;
  __shared__ uint4 a_lds[KFR * 64];  // 16 KB, frag (kidx,row)
  const int tid = threadIdx.x;
  const int rbase = blockIdx.x * 64;
#pragma unroll
  for (int i = 0; i < KFR / 4; ++i) {
    int row = tid >> 2;
    int kidx = i * 4 + (tid & 3);
    int gr = rbase + row;
    gr = gr < N_NODES ? gr : N_NODES - 1;
    const float* ap = A + (size_t)gr * K + kidx * 8;
    float4 v0 = *(const float4*)ap;
    float4 v1 = *(const float4*)(ap + 4);
    union { uint4 u; unsigned short h[8]; } fr;
    fr.h[0] = f2bf(v0.x); fr.h[1] = f2bf(v0.y); fr.h[2] = f2bf(v0.z); fr.h[3] = f2bf(v0.w);
    fr.h[4] = f2bf(v1.x); fr.h[5] = f2bf(v1.y); fr.h[6] = f2bf(v1.z); fr.h[7] = f2bf(v1.w);
    a_lds[kidx * 64 + row] = fr.u;
  }
  __syncthreads();
  const int lane = tid & 63, wv = tid >> 6;
  const int wr = wv >> 1, wc = wv & 1;
  const int kq = lane >> 4, lr = lane & 15;
  floatx4 zero4 = {0.f, 0.f, 0.f, 0.f};
  floatx4 acc[2][6];
#pragma unroll
  for (int m = 0; m < 2; ++m)
#pragma unroll
    for (int n = 0; n < 6; ++n) acc[m][n] = zero4;
#pragma unroll
  for (int ks = 0; ks < KS; ++ks) {
    int kidx = ks * 4 + kq;
    FragU a0, a1, b[6];
    a0.u = a_lds[kidx * 64 + wr * 32 + lr];
    a1.u = a_lds[kidx * 64 + wr * 32 + 16 + lr];
#pragma unroll
    for (int n = 0; n < 6; ++n) {
      int col = wc * 96 + n * 16 + lr;
      b[n].u = *(const uint4*)(WT + (size_t)col * K + kidx * 8);
    }
#pragma unroll
    for (int n = 0; n < 6; ++n) {
      acc[0][n] = __builtin_amdgcn_mfma_f32_16x16x32_bf16(a0.s, b[n].s, acc[0][n], 0, 0, 0);
      acc[1][n] = __builtin_amdgcn_mfma_f32_16x16x32_bf16(a1.s, b[n].s, acc[1][n], 0, 0, 0);
    }
  }
#pragma unroll
  for (int n = 0; n < 6; ++n) {
    int col = wc * 96 + n * 16 + lr;
    float bb = bias[col];
#pragma unroll
    for (int m = 0; m < 2; ++m)
#pragma unroll
      for (int j = 0; j < 4; ++j) {
        int row = rbase + wr * 32 + m * 16 + kq * 4 + j;
        if (row < N_NODES) C[(size_t)row * DIM_H + col] = f2bf(relu_f(acc[m][n][j] + bb));
      }
  }
}

// ---------------- fused MLP (MFMA): Z = relu(A@W1+b1)@W2+b2 (bf16), + BN stats ----------------
__global__ __launch_bounds__(256) void k_mlp(const unsigned short* __restrict__ A,
                                             const unsigned short* __restrict__ WT1,
                                             const float* __restrict__ b1,
                                             const unsigned short* __restrict__ WT2,
                                             const float* __restrict__ b2,
                                             unsigned short* __restrict__ Z,
                                             float* __restrict__ stats) {
  constexpr int K = DIM_H, KFR = K / 8, KS = K / 32;  // 24, 6
  __shared__ uint4 a_lds[KFR * 64];  // 24 KB
  __shared__ uint4 z_lds[KFR * 64];  // 24 KB
  const int tid = threadIdx.x;
  const int rbase = blockIdx.x * 64;
#pragma unroll
  for (int i = 0; i < KFR / 4; ++i) {
    int row = tid >> 2;
    int kidx = i * 4 + (tid & 3);
    int gr = rbase + row;
    gr = gr < N_NODES ? gr : N_NODES - 1;
    a_lds[kidx * 64 + row] = *(const uint4*)(A + (size_t)gr * K + kidx * 8);
  }
  __syncthreads();
  const int lane = tid & 63, wv = tid >> 6;
  const int wr = wv >> 1, wc = wv & 1;
  const int kq = lane >> 4, lr = lane & 15;
  floatx4 zero4 = {0.f, 0.f, 0.f, 0.f};
  floatx4 acc[2][6];
#pragma unroll
  for (int m = 0; m < 2; ++m)
#pragma unroll
    for (int n = 0; n < 6; ++n) acc[m][n] = zero4;
  // ---- stage 1 ----
#pragma unroll
  for (int ks = 0; ks < KS; ++ks) {
    int kidx = ks * 4 + kq;
    FragU a0, a1, b[6];
    a0.u = a_lds[kidx * 64 + wr * 32 + lr];
    a1.u = a_lds[kidx * 64 + wr * 32 + 16 + lr];
#pragma unroll
    for (int n = 0; n < 6; ++n) {
      int col = wc * 96 + n * 16 + lr;
      b[n].u = *(const uint4*)(WT1 + (size_t)col * K + kidx * 8);
    }
#pragma unroll
    for (int n = 0; n < 6; ++n) {
      acc[0][n] = __builtin_amdgcn_mfma_f32_16x16x32_bf16(a0.s, b[n].s, acc[0][n], 0, 0, 0);
      acc[1][n] = __builtin_amdgcn_mfma_f32_16x16x32_bf16(a1.s, b[n].s, acc[1][n], 0, 0, 0);
    }
  }
  // epilogue 1: z1 = relu(acc+b1) -> z_lds (packed frags)
  {
    unsigned short* zl = (unsigned short*)z_lds;
#pragma unroll
    for (int n = 0; n < 6; ++n) {
      int col = wc * 96 + n * 16 + lr;
      float bb = b1[col];
#pragma unroll
      for (int m = 0; m < 2; ++m)
#pragma unroll
        for (int j = 0; j < 4; ++j) {
          int rowl = wr * 32 + m * 16 + kq * 4 + j;
          zl[((col >> 3) * 64 + rowl) * 8 + (col & 7)] = f2bf(relu_f(acc[m][n][j] + bb));
        }
    }
  }
  __syncthreads();
  // ---- stage 2 ----
#pragma unroll
  for (int m = 0; m < 2; ++m)
#pragma unroll
    for (int n = 0; n < 6; ++n) acc[m][n] = zero4;
#pragma unroll
  for (int ks = 0; ks < KS; ++ks) {
    int kidx = ks * 4 + kq;
    FragU a0, a1, b[6];
    a0.u = z_lds[kidx * 64 + wr * 32 + lr];
    a1.u = z_lds[kidx * 64 + wr * 32 + 16 + lr];
#pragma unroll
    for (int n = 0; n < 6; ++n) {
      int col = wc * 96 + n * 16 + lr;
      b[n].u = *(const uint4*)(WT2 + (size_t)col * K + kidx * 8);
    }
#pragma unroll
    for (int n = 0; n < 6; ++n) {
      acc[0][n] = __builtin_amdgcn_mfma_f32_16x16x32_bf16(a0.s, b[n].s, acc[0][n], 0, 0, 0);
      acc[1][n] = __builtin_amdgcn_mfma_f32_16x16x32_bf16(a1.s, b[n].s, acc[1][n], 0, 0, 0);
    }
  }
  // epilogue 2: Z = acc + b2 (bf16 store) + BN partial stats
  float s6[6], q6[6];
#pragma unroll
  for (int n = 0; n < 6; ++n) { s6[n] = 0.f; q6[n] = 0.f; }
#pragma unroll
  for (int n = 0; n < 6; ++n) {
    int col = wc * 96 + n * 16 + lr;
    float bb = b2[col];
#pragma unroll
    for (int m = 0; m < 2; ++m)
#pragma unroll
      for (int j = 0; j < 4; ++j) {
        int row = rbase + wr * 32 + m * 16 + kq * 4 + j;
        if (row < N_NODES) {
          float v = acc[m][n][j] + bb;
          Z[(size_t)row * DIM_H + col] = f2bf(v);
          s6[n] += v;
          q6[n] += v * v;
        }
      }
  }
  __syncthreads();  // all z_lds/a_lds reads complete; reuse as stat scratch
  float* ps = (float*)z_lds;  // [192][8]
  float* pq = (float*)a_lds;  // [192][8]
  int grp = wr * 4 + kq;
#pragma unroll
  for (int n = 0; n < 6; ++n) {
    int col = wc * 96 + n * 16 + lr;
    ps[col * 8 + grp] = s6[n];
    pq[col * 8 + grp] = q6[n];
  }
  __syncthreads();
  if (tid < DIM_H) {
    float ts = 0.f, tq = 0.f;
#pragma unroll
    for (int g = 0; g < 8; ++g) {
      ts += ps[tid * 8 + g];
      tq += pq[tid * 8 + g];
    }
    atomicAdd(&stats[tid], ts);
    atomicAdd(&stats[DIM_H + tid], tq);
  }
}

// ---------------- BN finalize + final apply (bf16) ----------------
__global__ void k_bn_final(const float* __restrict__ stats, const float* __restrict__ g,
                           const float* __restrict__ b, float* __restrict__ coef) {
  int c = threadIdx.x;  // 192
  float mu = stats[c] * (1.f / N_NODES);
  float var = stats[DIM_H + c] * (1.f / N_NODES) - mu * mu;
  float rs = rsqrtf(var + BN_EPSF);
  float sc = g[c] * rs;
  coef[c] = sc;
  coef[DIM_H + c] = b[c] - mu * sc;
}

__global__ void k_bn_apply(const unsigned short* __restrict__ z, const float* __restrict__ coef,
                           unsigned short* __restrict__ h) {
  __shared__ float sc[DIM_H], sh[DIM_H];
  if (threadIdx.x < DIM_H) {
    sc[threadIdx.x] = coef[threadIdx.x];
    sh[threadIdx.x] = coef[DIM_H + threadIdx.x];
  }
  __syncthreads();
  const int total8 = N_NODES * DIM_H / 8;
  for (int j = blockIdx.x * blockDim.x + threadIdx.x; j < total8; j += gridDim.x * blockDim.x) {
    union { uint4 u; unsigned short h[8]; } v, o;
    v.u = ((const uint4*)z)[j];
    int c = (j * 8) % DIM_H;
#pragma unroll
    for (int t = 0; t < 8; ++t)
      o.h[t] = f2bf(relu_f(bf2f(v.h[t]) * sc[c + t] + sh[c + t]));
    ((uint4*)h)[j] = o.u;
  }
}

// ---------------- seed row projection ----------------
__global__ void k_seed_s2(const unsigned short* __restrict__ h, const int* __restrict__ seedp,
                          const float* __restrict__ W2, float* __restrict__ s2) {
  int a = threadIdx.x;  // 192
  int seed = seedp[0];
  const unsigned short* hs = h + (size_t)seed * DIM_H;
  float s = 0.f;
  for (int k = 0; k < DIM_H; ++k) s = fmaf(bf2f(hs[k]), W2[(size_t)k * DIM_H + a], s);
  s2[a] = s;
}

// ---------------- attention scores (MFMA) ----------------
__global__ __launch_bounds__(256) void k_attnm(const unsigned short* __restrict__ H,
                                               const unsigned short* __restrict__ WT,
                                               const float* __restrict__ s2,
                                               const float* __restrict__ wat,
                                               float* __restrict__ e) {
  constexpr int K = DIM_H, KFR = K / 8, KS = K / 32;
  __shared__ uint4 a_lds[KFR * 64];
  __shared__ float part[64][33];
  const int tid = threadIdx.x;
  const int rbase = blockIdx.x * 64;
#pragma unroll
  for (int i = 0; i < KFR / 4; ++i) {
    int row = tid >> 2;
    int kidx = i * 4 + (tid & 3);
    int gr = rbase + row;
    gr = gr < N_NODES ? gr : N_NODES - 1;
    a_lds[kidx * 64 + row] = *(const uint4*)(H + (size_t)gr * K + kidx * 8);
  }
  __syncthreads();
  const int lane = tid & 63, wv = tid >> 6;
  const int wr = wv >> 1, wc = wv & 1;
  const int kq = lane >> 4, lr = lane & 15;
  floatx4 zero4 = {0.f, 0.f, 0.f, 0.f};
  floatx4 acc[2][6];
#pragma unroll
  for (int m = 0; m < 2; ++m)
#pragma unroll
    for (int n = 0; n < 6; ++n) acc[m][n] = zero4;
#pragma unroll
  for (int ks = 0; ks < KS; ++ks) {
    int kidx = ks * 4 + kq;
    FragU a0, a1, b[6];
    a0.u = a_lds[kidx * 64 + wr * 32 + lr];
    a1.u = a_lds[kidx * 64 + wr * 32 + 16 + lr];
#pragma unroll
    for (int n = 0; n < 6; ++n) {
      int col = wc * 96 + n * 16 + lr;
      b[n].u = *(const uint4*)(WT + (size_t)col * K + kidx * 8);
    }
#pragma unroll
    for (int n = 0; n < 6; ++n) {
      acc[0][n] = __builtin_amdgcn_mfma_f32_16x16x32_bf16(a0.s, b[n].s, acc[0][n], 0, 0, 0);
      acc[1][n] = __builtin_amdgcn_mfma_f32_16x16x32_bf16(a1.s, b[n].s, acc[1][n], 0, 0, 0);
    }
  }
  float p[8];
#pragma unroll
  for (int t = 0; t < 8; ++t) p[t] = 0.f;
#pragma unroll
  for (int n = 0; n < 6; ++n) {
    int col = wc * 96 + n * 16 + lr;
    float s2c = s2[col];
    float wv_ = wat[col];
#pragma unroll
    for (int m = 0; m < 2; ++m)
#pragma unroll
      for (int j = 0; j < 4; ++j)
        p[m * 4 + j] = fmaf(tanhf(acc[m][n][j] + s2c), wv_, p[m * 4 + j]);
  }
#pragma unroll
  for (int m = 0; m < 2; ++m)
#pragma unroll
    for (int j = 0; j < 4; ++j) {
      int rowl = wr * 32 + m * 16 + kq * 4 + j;
      part[rowl][wc * 16 + lr] = p[m * 4 + j];
    }
  __syncthreads();
  if (tid < 64) {
    float s = 0.f;
#pragma unroll
    for (int i = 0; i < 32; ++i) s += part[tid][i];
    s = s > 0.f ? s : 0.2f * s;
    int gr = rbase + tid;
    if (gr < N_NODES) e[gr] = s;
  }
}

// ---------------- softmax + readout + logit ----------------
__global__ void k_max(const float* __restrict__ e, float* __restrict__ pmax) {
  __shared__ float buf[256];
  float m = -3.4e38f;
  for (int i = blockIdx.x * 256 + threadIdx.x; i < N_NODES; i += 256 * 256) m = fmaxf(m, e[i]);
  buf[threadIdx.x] = m;
  __syncthreads();
  for (int s = 128; s > 0; s >>= 1) {
    if (threadIdx.x < s) buf[threadIdx.x] = fmaxf(buf[threadIdx.x], buf[threadIdx.x + s]);
    __syncthreads();
  }
  if (threadIdx.x == 0) pmax[blockIdx.x] = buf[0];
}

__global__ void k_max2(const float* __restrict__ pmax, float* __restrict__ sc,
                       float* __restrict__ readout) {
  __shared__ float buf[256];
  buf[threadIdx.x] = pmax[threadIdx.x];
  __syncthreads();
  for (int s = 128; s > 0; s >>= 1) {
    if (threadIdx.x < s) buf[threadIdx.x] = fmaxf(buf[threadIdx.x], buf[threadIdx.x + s]);
    __syncthreads();
  }
  if (threadIdx.x == 0) { sc[0] = buf[0]; sc[1] = 0.f; }
  if (threadIdx.x < DIM_H) readout[threadIdx.x] = 0.f;
}

__global__ void k_sumexp(const float* __restrict__ e, float* __restrict__ sc) {
  __shared__ float buf[256];
  float gmax = sc[0];
  float s = 0.f;
  for (int i = blockIdx.x * 256 + threadIdx.x; i < N_NODES; i += 256 * 256) s += expf(e[i] - gmax);
  buf[threadIdx.x] = s;
  __syncthreads();
  for (int t = 128; t > 0; t >>= 1) {
    if (threadIdx.x < t) buf[threadIdx.x] += buf[threadIdx.x + t];
    __syncthreads();
  }
  if (threadIdx.x == 0) atomicAdd(&sc[1], buf[0]);
}

__global__ void k_alpha(const float* __restrict__ e, const float* __restrict__ sc,
                        float* __restrict__ alpha) {
  int i = blockIdx.x * 256 + threadIdx.x;
  if (i < N_NODES) alpha[i] = expf(e[i] - sc[0]) * (1.f / sc[1]);
}

__global__ void k_readout(const float* __restrict__ alpha, const unsigned short* __restrict__ h,
                          float* __restrict__ readout) {
  int c = threadIdx.x;  // 192
  float s = 0.f;
  for (int r = blockIdx.x; r < N_NODES; r += gridDim.x)
    s = fmaf(alpha[r], bf2f(h[(size_t)r * DIM_H + c]), s);
  atomicAdd(&readout[c], s);
}

__global__ void k_logit(const float* __restrict__ readout, const float* __restrict__ cw,
                        const float* __restrict__ cb, float* __restrict__ out) {
  __shared__ float buf[256];
  int tid = threadIdx.x;
  buf[tid] = (tid < DIM_H) ? readout[tid] * cw[tid] : 0.f;
  __syncthreads();
  for (int s = 128; s > 0; s >>= 1) {
    if (tid < s) buf[tid] += buf[tid + s];
    __syncthreads();
  }
  if (tid == 0) out[0] = buf[0] + cb[0];
}

extern "C" void kernel_launch(void* const* d_in, const int* in_sizes, int n_in,
                              void* d_out, int out_size, void* d_ws, size_t ws_size,
                              hipStream_t stream) {
  const float* x      = (const float*)d_in[0];
  const int*   edge   = (const int*)d_in[1];
  const int*   seedp  = (const int*)d_in[2];
  const float* proj_w = (const float*)d_in[3];
  const float* proj_b = (const float*)d_in[4];
  const float* mlp1_w = (const float*)d_in[5];
  const float* mlp1_b = (const float*)d_in[6];
  const float* mlp2_w = (const float*)d_in[7];
  const float* mlp2_b = (const float*)d_in[8];
  const float* eps    = (const float*)d_in[9];
  const float* bn_g   = (const float*)d_in[10];
  const float* bn_b   = (const float*)d_in[11];
  const float* W1     = (const float*)d_in[12];
  const float* W2     = (const float*)d_in[13];
  const float* w_attn = (const float*)d_in[14];
  const float* cls_w  = (const float*)d_in[15];
  const float* cls_b  = (const float*)d_in[16];
  float* out = (float*)d_out;

  char* ws = (char*)d_ws;
  size_t off = 0;
  auto alloc = [&](size_t bytes) -> void* {
    void* p = ws + off;
    off = (off + bytes + 255) & ~(size_t)255;
    return p;
  };
  unsigned short* buf0 = (unsigned short*)alloc((size_t)N_NODES * DIM_H * 2);
  unsigned short* buf1 = (unsigned short*)alloc((size_t)N_NODES * DIM_H * 2);
  float* ebuf   = (float*)alloc((size_t)N_NODES * 4);
  int* rowptr   = (int*)alloc((size_t)(N_NODES + 1) * 4);
  int* cursor   = (int*)alloc((size_t)N_NODES * 4);
  int* csr      = (int*)alloc((size_t)N_EDGES * 4);
  int* part     = (int*)alloc((size_t)N_NODES * 4);
  int* bsum     = (int*)alloc(64 * 4);
  float* stats  = (float*)alloc(2 * DIM_H * 4);
  float* coef   = (float*)alloc(2 * DIM_H * 4);
  float* s2     = (float*)alloc(DIM_H * 4);
  float* pmax   = (float*)alloc(256 * 4);
  float* scal   = (float*)alloc(8 * 4);
  float* rdout  = (float*)alloc(DIM_H * 4);
  unsigned short* WTproj = (unsigned short*)alloc((size_t)DIM_H * DIM_IN * 2);
  unsigned short* WT1[N_LAYERS], *WT2[N_LAYERS];
  for (int l = 0; l < N_LAYERS; ++l) {
    WT1[l] = (unsigned short*)alloc((size_t)DIM_H * DIM_H * 2);
    WT2[l] = (unsigned short*)alloc((size_t)DIM_H * DIM_H * 2);
  }
  unsigned short* WTa = (unsigned short*)alloc((size_t)DIM_H * DIM_H * 2);

  const int GRID64 = (N_NODES + 63) / 64;  // 782

  // weight transpose/convert
  k_wt<DIM_IN><<<(DIM_IN / 32) * 6, 256, 0, stream>>>(proj_w, WTproj);
  for (int l = 0; l < N_LAYERS; ++l) {
    k_wt<DIM_H><<<36, 256, 0, stream>>>(mlp1_w + (size_t)l * DIM_H * DIM_H, WT1[l]);
    k_wt<DIM_H><<<36, 256, 0, stream>>>(mlp2_w + (size_t)l * DIM_H * DIM_H, WT2[l]);
  }
  k_wt<DIM_H><<<36, 256, 0, stream>>>(W1, WTa);

  // CSR build
  hipMemsetAsync(cursor, 0, (size_t)N_NODES * 4, stream);
  k_hist<<<(N_EDGES + 255) / 256, 256, 0, stream>>>(edge, cursor);
  k_scanA<<<SCAN_NBLK, 1024, 0, stream>>>(cursor, part, bsum);
  k_scanB<<<1, 64, 0, stream>>>(bsum);
  k_scanC<<<(N_NODES + 255) / 256, 256, 0, stream>>>(part, bsum, rowptr);
  k_copy_int<<<(N_NODES + 255) / 256, 256, 0, stream>>>(rowptr, cursor, N_NODES);
  k_fill<<<(N_EDGES + 255) / 256, 256, 0, stream>>>(edge, cursor, csr);

  // projection: x -> buf0 (relu'd h0, bf16)
  k_proj<<<GRID64, 256, 0, stream>>>(x, WTproj, proj_b, buf0);

  // GIN layers (ping-pong)
  unsigned short* cur = buf0;
  unsigned short* nxt = buf1;
  for (int l = 0; l < N_LAYERS; ++l) {
    if (l == 0)
      k_agg<false><<<N_NODES / 4, 256, 0, stream>>>(cur, rowptr, csr, coef, eps, l, nxt);
    else
      k_agg<true><<<N_NODES / 4, 256, 0, stream>>>(cur, rowptr, csr, coef, eps, l, nxt);
    hipMemsetAsync(stats, 0, 2 * DIM_H * 4, stream);
    k_mlp<<<GRID64, 256, 0, stream>>>(nxt, WT1[l], mlp1_b + (size_t)l * DIM_H,
                                      WT2[l], mlp2_b + (size_t)l * DIM_H, nxt, stats);
    k_bn_final<<<1, DIM_H, 0, stream>>>(stats, bn_g + (size_t)l * DIM_H, bn_b + (size_t)l * DIM_H, coef);
    unsigned short* t = cur; cur = nxt; nxt = t;
  }
  // final h = relu(BN(z2)) -> nxt
  k_bn_apply<<<2048, 256, 0, stream>>>(cur, coef, nxt);
  unsigned short* hfin = nxt;

  // attention + softmax + readout
  k_seed_s2<<<1, DIM_H, 0, stream>>>(hfin, seedp, W2, s2);
  k_attnm<<<GRID64, 256, 0, stream>>>(hfin, WTa, s2, w_attn, ebuf);
  k_max<<<256, 256, 0, stream>>>(ebuf, pmax);
  k_max2<<<1, 256, 0, stream>>>(pmax, scal, rdout);
  k_sumexp<<<256, 256, 0, stream>>>(ebuf, scal);
  k_alpha<<<(N_NODES + 255) / 256, 256, 0, stream>>>(ebuf, scal, out + 1);
  k_readout<<<256, DIM_H, 0, stream>>>(out + 1, hfin, rdout);
  k_logit<<<1, 256, 0, stream>>>(rdout, cls_w, cls_b, out);
}

// Round 4
// 440.561 us; speedup vs baseline: 2.3665x; 1.2309x over previous
//
#include <hip/hip_runtime.h>
#include <hip/hip_bf16.h>

#define N_NODES 50000
#define N_EDGES 400000
#define DIM_IN  128
#define DIM_H   192
#define N_LAYERS 3
#define BN_EPSF 1e-5f
#define SCAN_NBLK 49  // ceil(50000/1024)

typedef __attribute__((ext_vector_type(8))) short short8;
typedef __attribute__((ext_vector_type(4))) float floatx4;

union FragU { uint4 u; short8 s; };

__device__ __forceinline__ float relu_f(float x) { return x > 0.f ? x : 0.f; }
__device__ __forceinline__ unsigned short f2bf(float x) {
  __hip_bfloat16 h = __float2bfloat16(x);
  return *reinterpret_cast<unsigned short*>(&h);
}
__device__ __forceinline__ float bf2f(unsigned short b) {
  return __uint_as_float(((unsigned)b) << 16);
}
__device__ __forceinline__ float bflo(unsigned u) { return __uint_as_float(u << 16); }
__device__ __forceinline__ float bfhi(unsigned u) { return __uint_as_float(u & 0xffff0000u); }

// ---------------- CSR build ----------------
__global__ void k_hist(const int* __restrict__ edge, int* __restrict__ cnt) {
  int e = blockIdx.x * 256 + threadIdx.x;
  if (e < N_EDGES) atomicAdd(&cnt[edge[N_EDGES + e]], 1);
}

__global__ void k_scanA(const int* __restrict__ deg, int* __restrict__ part, int* __restrict__ bsum) {
  __shared__ int buf[1024];
  int g = blockIdx.x * 1024 + threadIdx.x;
  int v = (g < N_NODES) ? deg[g] : 0;
  buf[threadIdx.x] = v;
  __syncthreads();
  for (int off = 1; off < 1024; off <<= 1) {
    int t = (threadIdx.x >= off) ? buf[threadIdx.x - off] : 0;
    __syncthreads();
    buf[threadIdx.x] += t;
    __syncthreads();
  }
  if (g < N_NODES) part[g] = buf[threadIdx.x];
  if (threadIdx.x == 1023) bsum[blockIdx.x] = buf[1023];
}

__global__ void k_scanB(int* __restrict__ bsum) {
  __shared__ int b[64];
  int t = threadIdx.x;
  b[t] = (t < SCAN_NBLK) ? bsum[t] : 0;
  __syncthreads();
  for (int off = 1; off < 64; off <<= 1) {
    int v = (t >= off) ? b[t - off] : 0;
    __syncthreads();
    b[t] += v;
    __syncthreads();
  }
  if (t < SCAN_NBLK) bsum[t] = t ? b[t - 1] : 0;  // exclusive
}

// writes rowptr AND cursor (= rowptr start offsets)
__global__ void k_scanC(const int* __restrict__ part, const int* __restrict__ bsum,
                        int* __restrict__ rowptr, int* __restrict__ cursor) {
  int g = blockIdx.x * 256 + threadIdx.x;
  if (g == 0) { rowptr[0] = 0; cursor[0] = 0; }
  if (g < N_NODES) {
    int v = part[g] + bsum[g >> 10];
    rowptr[g + 1] = v;
    if (g + 1 < N_NODES) cursor[g + 1] = v;
  }
}

__global__ void k_fill(const int* __restrict__ edge, int* __restrict__ cursor, int* __restrict__ csr) {
  int e = blockIdx.x * 256 + threadIdx.x;
  if (e < N_EDGES) {
    int s = edge[e];
    int d = edge[N_EDGES + e];
    int pos = atomicAdd(&cursor[d], 1);
    csr[pos] = s;
  }
}

// ---------------- weight pack: all matrices -> frag layout [K/8][192] uint4 bf16 ----------------
__global__ void k_wtp(const float* __restrict__ m1, const float* __restrict__ m2,
                      const float* __restrict__ wa, const float* __restrict__ pw,
                      uint4* __restrict__ outp) {
  const int NH = 7 * 24 * 192;  // 7 K=192 matrices
  const int NP = 16 * 192;      // proj K=128
  int idx = blockIdx.x * 256 + threadIdx.x;
  if (idx >= NH + NP) return;
  union { uint4 u; unsigned short h[8]; } fr;
  if (idx < NH) {
    int mat = idx / (24 * 192);
    int rem = idx - mat * (24 * 192);
    int kidx = rem / 192, col = rem - kidx * 192;
    const float* src = mat < 3 ? m1 + (size_t)mat * (DIM_H * DIM_H)
                     : (mat < 6 ? m2 + (size_t)(mat - 3) * (DIM_H * DIM_H) : wa);
#pragma unroll
    for (int t = 0; t < 8; ++t) fr.h[t] = f2bf(src[(size_t)(kidx * 8 + t) * DIM_H + col]);
  } else {
    int rem = idx - NH;
    int kidx = rem / 192, col = rem - kidx * 192;
#pragma unroll
    for (int t = 0; t < 8; ++t) fr.h[t] = f2bf(pw[(size_t)(kidx * 8 + t) * DIM_H + col]);
  }
  outp[idx] = fr.u;
}

// ---------------- aggregation: 1 node/wave, lanes 0-47, 4 cols each ----------------
template <bool BN>
__global__ void k_agg(const unsigned short* __restrict__ z, const int* __restrict__ rowptr,
                      const int* __restrict__ csr, const float* __restrict__ coef,
                      const float* __restrict__ eps, int l, unsigned short* __restrict__ outA) {
  int wid = threadIdx.x >> 6, lane = threadIdx.x & 63;
  int node = blockIdx.x * 4 + wid;
  if (node >= N_NODES || lane >= 48) return;
  int c = lane * 4;
  float4 sc4 = {1.f, 1.f, 1.f, 1.f}, sh4 = {0.f, 0.f, 0.f, 0.f};
  if (BN) {
    sc4 = *(const float4*)(coef + c);
    sh4 = *(const float4*)(coef + DIM_H + c);
  }
  float a0 = 0.f, a1 = 0.f, a2 = 0.f, a3 = 0.f;
  int beg = rowptr[node], end = rowptr[node + 1];
#define ACCU(U)                                                          \
  {                                                                      \
    float v0 = bflo((U).x), v1 = bfhi((U).x);                            \
    float v2 = bflo((U).y), v3 = bfhi((U).y);                            \
    if (BN) {                                                            \
      v0 = relu_f(v0 * sc4.x + sh4.x);                                   \
      v1 = relu_f(v1 * sc4.y + sh4.y);                                   \
      v2 = relu_f(v2 * sc4.z + sh4.z);                                   \
      v3 = relu_f(v3 * sc4.w + sh4.w);                                   \
    }                                                                    \
    a0 += v0; a1 += v1; a2 += v2; a3 += v3;                              \
  }
  int j = beg;
  for (; j + 2 <= end; j += 2) {
    int s0 = csr[j], s1 = csr[j + 1];
    uint2 u0 = *(const uint2*)(z + (size_t)s0 * DIM_H + c);
    uint2 u1 = *(const uint2*)(z + (size_t)s1 * DIM_H + c);
    ACCU(u0) ACCU(u1)
  }
  if (j < end) {
    int s0 = csr[j];
    uint2 u0 = *(const uint2*)(z + (size_t)s0 * DIM_H + c);
    ACCU(u0)
  }
#undef ACCU
  float ep = 1.f + eps[l];
  uint2 us = *(const uint2*)(z + (size_t)node * DIM_H + c);
  {
    float v0 = bflo(us.x), v1 = bfhi(us.x), v2 = bflo(us.y), v3 = bfhi(us.y);
    if (BN) {
      v0 = relu_f(v0 * sc4.x + sh4.x);
      v1 = relu_f(v1 * sc4.y + sh4.y);
      v2 = relu_f(v2 * sc4.z + sh4.z);
      v3 = relu_f(v3 * sc4.w + sh4.w);
    }
    a0 += ep * v0; a1 += ep * v1; a2 += ep * v2; a3 += ep * v3;
  }
  uint2 o;
  o.x = (unsigned)f2bf(a0) | ((unsigned)f2bf(a1) << 16);
  o.y = (unsigned)f2bf(a2) | ((unsigned)f2bf(a3) << 16);
  *(uint2*)(outA + (size_t)node * DIM_H + c) = o;
}

// ---------------- MFMA stage helper: 64 rows x 48 cols per wave, B double-buffered ----------------
template <int KS>
__device__ __forceinline__ void mfma_stage(const uint4* a_lds, const uint4* __restrict__ Bp,
                                           int colbase, int kq, int lr, floatx4 (&acc)[4][3]) {
  FragU bcur[3], bnxt[3];
#pragma unroll
  for (int n = 0; n < 3; ++n) bcur[n].u = Bp[kq * 192 + colbase + n * 16 + lr];
#pragma unroll
  for (int ks = 0; ks < KS; ++ks) {
    if (ks + 1 < KS) {
      int kn = (ks + 1) * 4 + kq;
#pragma unroll
      for (int n = 0; n < 3; ++n) bnxt[n].u = Bp[kn * 192 + colbase + n * 16 + lr];
    }
    int kidx = ks * 4 + kq;
    FragU a[4];
#pragma unroll
    for (int m = 0; m < 4; ++m) a[m].u = a_lds[kidx * 64 + m * 16 + lr];
#pragma unroll
    for (int n = 0; n < 3; ++n)
#pragma unroll
      for (int m = 0; m < 4; ++m)
        acc[m][n] = __builtin_amdgcn_mfma_f32_16x16x32_bf16(a[m].s, bcur[n].s, acc[m][n], 0, 0, 0);
    if (ks + 1 < KS) {
#pragma unroll
      for (int n = 0; n < 3; ++n) bcur[n] = bnxt[n];
    }
  }
}

// ---------------- MFMA projection: C = relu(x_f32[M,128] @ W + b) -> bf16 ----------------
__global__ __launch_bounds__(256) void k_proj(const float* __restrict__ A,
                                              const uint4* __restrict__ Bp,
                                              const float* __restrict__ bias,
                                              unsigned short* __restrict__ C) {
  __shared__ uint4 a_lds[16 * 64];  // 16 KB
  const int tid = threadIdx.x;
  const int rbase = blockIdx.x * 64;
#pragma unroll
  for (int i = 0; i < 4; ++i) {
    int row = tid >> 2, kidx = i * 4 + (tid & 3);
    int gr = rbase + row;
    gr = gr < N_NODES ? gr : N_NODES - 1;
    const float* ap = A + (size_t)gr * DIM_IN + kidx * 8;
    float4 v0 = *(const float4*)ap;
    float4 v1 = *(const float4*)(ap + 4);
    union { uint4 u; unsigned short h[8]; } fr;
    fr.h[0] = f2bf(v0.x); fr.h[1] = f2bf(v0.y); fr.h[2] = f2bf(v0.z); fr.h[3] = f2bf(v0.w);
    fr.h[4] = f2bf(v1.x); fr.h[5] = f2bf(v1.y); fr.h[6] = f2bf(v1.z); fr.h[7] = f2bf(v1.w);
    a_lds[kidx * 64 + row] = fr.u;
  }
  __syncthreads();
  const int lane = tid & 63, w = tid >> 6;
  const int kq = lane >> 4, lr = lane & 15;
  const int colbase = w * 48;
  floatx4 acc[4][3];
  floatx4 zero4 = {0.f, 0.f, 0.f, 0.f};
#pragma unroll
  for (int m = 0; m < 4; ++m)
#pragma unroll
    for (int n = 0; n < 3; ++n) acc[m][n] = zero4;
  mfma_stage<4>(a_lds, Bp, colbase, kq, lr, acc);
#pragma unroll
  for (int n = 0; n < 3; ++n) {
    int col = colbase + n * 16 + lr;
    float bb = bias[col];
#pragma unroll
    for (int m = 0; m < 4; ++m)
#pragma unroll
      for (int j = 0; j < 4; ++j) {
        int row = rbase + m * 16 + kq * 4 + j;
        if (row < N_NODES) C[(size_t)row * DIM_H + col] = f2bf(relu_f(acc[m][n][j] + bb));
      }
  }
}

// ---------------- fused MLP (MFMA): Z = relu(A@W1+b1)@W2+b2 (bf16), + BN stats ----------------
__global__ __launch_bounds__(256) void k_mlp(const unsigned short* __restrict__ A,
                                             const uint4* __restrict__ B1p, const float* __restrict__ b1,
                                             const uint4* __restrict__ B2p, const float* __restrict__ b2,
                                             unsigned short* __restrict__ Z, float* __restrict__ stats) {
  __shared__ uint4 a_lds[24 * 64];  // 24 KB (A, then z1, then stat scratch)
  const int tid = threadIdx.x;
  const int rbase = blockIdx.x * 64;
#pragma unroll
  for (int i = 0; i < 6; ++i) {
    int row = tid >> 2, kidx = i * 4 + (tid & 3);
    int gr = rbase + row;
    gr = gr < N_NODES ? gr : N_NODES - 1;
    a_lds[kidx * 64 + row] = *(const uint4*)(A + (size_t)gr * DIM_H + kidx * 8);
  }
  __syncthreads();
  const int lane = tid & 63, w = tid >> 6;
  const int kq = lane >> 4, lr = lane & 15;
  const int colbase = w * 48;
  floatx4 zero4 = {0.f, 0.f, 0.f, 0.f};
  floatx4 acc[4][3];
#pragma unroll
  for (int m = 0; m < 4; ++m)
#pragma unroll
    for (int n = 0; n < 3; ++n) acc[m][n] = zero4;
  mfma_stage<6>(a_lds, B1p, colbase, kq, lr, acc);
  __syncthreads();  // all stage-1 reads of a_lds complete
  {
    unsigned short* zl = (unsigned short*)a_lds;
#pragma unroll
    for (int n = 0; n < 3; ++n) {
      int col = colbase + n * 16 + lr;
      float bb = b1[col];
#pragma unroll
      for (int m = 0; m < 4; ++m)
#pragma unroll
        for (int j = 0; j < 4; ++j) {
          int rowl = m * 16 + kq * 4 + j;
          zl[(col >> 3) * 512 + rowl * 8 + (col & 7)] = f2bf(relu_f(acc[m][n][j] + bb));
        }
    }
  }
  __syncthreads();
#pragma unroll
  for (int m = 0; m < 4; ++m)
#pragma unroll
    for (int n = 0; n < 3; ++n) acc[m][n] = zero4;
  mfma_stage<6>(a_lds, B2p, colbase, kq, lr, acc);
  // epilogue: bias, bf16 store, BN partial stats
  float s3[3], q3[3];
#pragma unroll
  for (int n = 0; n < 3; ++n) { s3[n] = 0.f; q3[n] = 0.f; }
#pragma unroll
  for (int n = 0; n < 3; ++n) {
    int col = colbase + n * 16 + lr;
    float bb = b2[col];
#pragma unroll
    for (int m = 0; m < 4; ++m)
#pragma unroll
      for (int j = 0; j < 4; ++j) {
        int row = rbase + m * 16 + kq * 4 + j;
        if (row < N_NODES) {
          float v = acc[m][n][j] + bb;
          Z[(size_t)row * DIM_H + col] = f2bf(v);
          s3[n] += v;
          q3[n] += v * v;
        }
      }
  }
  __syncthreads();  // stage-2 a_lds reads done; reuse as stat scratch
  float* ps = (float*)a_lds;       // [192][4]
  float* pq = ps + DIM_H * 4;      // [192][4]
#pragma unroll
  for (int n = 0; n < 3; ++n) {
    int col = colbase + n * 16 + lr;
    ps[col * 4 + kq] = s3[n];
    pq[col * 4 + kq] = q3[n];
  }
  __syncthreads();
  if (tid < DIM_H) {
    float ts = 0.f, tq = 0.f;
#pragma unroll
    for (int g = 0; g < 4; ++g) {
      ts += ps[tid * 4 + g];
      tq += pq[tid * 4 + g];
    }
    atomicAdd(&stats[tid], ts);
    atomicAdd(&stats[DIM_H + tid], tq);
  }
}

// ---------------- BN finalize ----------------
__global__ void k_bn_final(const float* __restrict__ stats, const float* __restrict__ g,
                           const float* __restrict__ b, float* __restrict__ coef) {
  int c = threadIdx.x;  // 192
  float mu = stats[c] * (1.f / N_NODES);
  float var = stats[DIM_H + c] * (1.f / N_NODES) - mu * mu;
  float rs = rsqrtf(var + BN_EPSF);
  float sc = g[c] * rs;
  coef[c] = sc;
  coef[DIM_H + c] = b[c] - mu * sc;
}

// ---------------- seed row projection (BN fused on load) ----------------
__global__ void k_seed_s2(const unsigned short* __restrict__ Zin, const float* __restrict__ coef,
                          const int* __restrict__ seedp, const float* __restrict__ W2,
                          float* __restrict__ s2) {
  __shared__ float hs[DIM_H];
  int a = threadIdx.x;  // 192
  int seed = seedp[0];
  hs[a] = relu_f(bf2f(Zin[(size_t)seed * DIM_H + a]) * coef[a] + coef[DIM_H + a]);
  __syncthreads();
  float s = 0.f;
  for (int k = 0; k < DIM_H; ++k) s = fmaf(hs[k], W2[(size_t)k * DIM_H + a], s);
  s2[a] = s;
}

// ---------------- attention scores (BN fused staging, fast tanh, block expsum) ----------------
__global__ __launch_bounds__(256) void k_attnm(const unsigned short* __restrict__ Zin,
                                               const float* __restrict__ coef,
                                               const uint4* __restrict__ Bp,
                                               const float* __restrict__ s2,
                                               const float* __restrict__ wat,
                                               float* __restrict__ e, float* __restrict__ scal) {
  __shared__ uint4 a_lds[24 * 64];  // reused as part[64][65] + esum[64]
  const int tid = threadIdx.x;
  const int rbase = blockIdx.x * 64;
#pragma unroll
  for (int i = 0; i < 6; ++i) {
    int row = tid >> 2, kidx = i * 4 + (tid & 3);
    int gr = rbase + row;
    gr = gr < N_NODES ? gr : N_NODES - 1;
    union { uint4 u; unsigned short h[8]; } v, o;
    v.u = *(const uint4*)(Zin + (size_t)gr * DIM_H + kidx * 8);
    const float4 s0 = *(const float4*)(coef + kidx * 8);
    const float4 s1 = *(const float4*)(coef + kidx * 8 + 4);
    const float4 t0 = *(const float4*)(coef + DIM_H + kidx * 8);
    const float4 t1 = *(const float4*)(coef + DIM_H + kidx * 8 + 4);
    o.h[0] = f2bf(relu_f(bf2f(v.h[0]) * s0.x + t0.x));
    o.h[1] = f2bf(relu_f(bf2f(v.h[1]) * s0.y + t0.y));
    o.h[2] = f2bf(relu_f(bf2f(v.h[2]) * s0.z + t0.z));
    o.h[3] = f2bf(relu_f(bf2f(v.h[3]) * s0.w + t0.w));
    o.h[4] = f2bf(relu_f(bf2f(v.h[4]) * s1.x + t1.x));
    o.h[5] = f2bf(relu_f(bf2f(v.h[5]) * s1.y + t1.y));
    o.h[6] = f2bf(relu_f(bf2f(v.h[6]) * s1.z + t1.z));
    o.h[7] = f2bf(relu_f(bf2f(v.h[7]) * s1.w + t1.w));
    a_lds[kidx * 64 + row] = o.u;
  }
  __syncthreads();
  const int lane = tid & 63, w = tid >> 6;
  const int kq = lane >> 4, lr = lane & 15;
  const int colbase = w * 48;
  floatx4 zero4 = {0.f, 0.f, 0.f, 0.f};
  floatx4 acc[4][3];
#pragma unroll
  for (int m = 0; m < 4; ++m)
#pragma unroll
    for (int n = 0; n < 3; ++n) acc[m][n] = zero4;
  mfma_stage<6>(a_lds, Bp, colbase, kq, lr, acc);
  float p[16];
#pragma unroll
  for (int t = 0; t < 16; ++t) p[t] = 0.f;
#pragma unroll
  for (int n = 0; n < 3; ++n) {
    int col = colbase + n * 16 + lr;
    float s2c = s2[col];
    float wv = wat[col];
#pragma unroll
    for (int m = 0; m < 4; ++m)
#pragma unroll
      for (int j = 0; j < 4; ++j) {
        float xv = acc[m][n][j] + s2c;
        xv = fminf(fmaxf(xv, -10.f), 10.f);
        float t = __expf(2.f * xv);
        p[m * 4 + j] = fmaf((t - 1.f) / (t + 1.f), wv, p[m * 4 + j]);
      }
  }
  __syncthreads();  // a_lds MFMA reads done
  float* part = (float*)a_lds;  // [64][65]
#pragma unroll
  for (int m = 0; m < 4; ++m)
#pragma unroll
    for (int j = 0; j < 4; ++j)
      part[(m * 16 + kq * 4 + j) * 65 + w * 16 + lr] = p[m * 4 + j];
  __syncthreads();
  float* esum = part + 64 * 65;
  if (tid < 64) {
    float s = 0.f;
#pragma unroll
    for (int i = 0; i < 64; ++i) s += part[tid * 65 + i];
    s = s > 0.f ? s : 0.2f * s;
    int gr = rbase + tid;
    bool valid = gr < N_NODES;
    if (valid) e[gr] = s;
    esum[tid] = valid ? __expf(s) : 0.f;
  }
  __syncthreads();
  if (tid == 0) {
    float s = 0.f;
    for (int i = 0; i < 64; ++i) s += esum[i];
    atomicAdd(&scal[0], s);
  }
}

// ---------------- readout: alpha = exp(e)/S, write alpha, rdout[c] = sum alpha*h ----------------
__global__ void k_readout(const float* __restrict__ e, const float* __restrict__ scal,
                          const unsigned short* __restrict__ Zin, const float* __restrict__ coef,
                          float* __restrict__ alpha, float* __restrict__ rdout) {
  __shared__ float sc[DIM_H], sh[DIM_H];
  int c = threadIdx.x;  // 192
  sc[c] = coef[c];
  sh[c] = coef[DIM_H + c];
  __syncthreads();
  float invS = 1.f / scal[0];
  float s = 0.f;
  for (int r = blockIdx.x; r < N_NODES; r += gridDim.x) {
    float aw = __expf(e[r]) * invS;
    if (c == 0) alpha[r] = aw;
    float hv = relu_f(bf2f(Zin[(size_t)r * DIM_H + c]) * sc[c] + sh[c]);
    s = fmaf(aw, hv, s);
  }
  atomicAdd(&rdout[c], s);
}

__global__ void k_logit(const float* __restrict__ rdout, const float* __restrict__ cw,
                        const float* __restrict__ cb, float* __restrict__ out) {
  __shared__ float buf[256];
  int tid = threadIdx.x;
  buf[tid] = (tid < DIM_H) ? rdout[tid] * cw[tid] : 0.f;
  __syncthreads();
  for (int s = 128; s > 0; s >>= 1) {
    if (tid < s) buf[tid] += buf[tid + s];
    __syncthreads();
  }
  if (tid == 0) out[0] = buf[0] + cb[0];
}

extern "C" void kernel_launch(void* const* d_in, const int* in_sizes, int n_in,
                              void* d_out, int out_size, void* d_ws, size_t ws_size,
                              hipStream_t stream) {
  const float* x      = (const float*)d_in[0];
  const int*   edge   = (const int*)d_in[1];
  const int*   seedp  = (const int*)d_in[2];
  const float* proj_w = (const float*)d_in[3];
  const float* proj_b = (const float*)d_in[4];
  const float* mlp1_w = (const float*)d_in[5];
  const float* mlp1_b = (const float*)d_in[6];
  const float* mlp2_w = (const float*)d_in[7];
  const float* mlp2_b = (const float*)d_in[8];
  const float* eps    = (const float*)d_in[9];
  const float* bn_g   = (const float*)d_in[10];
  const float* bn_b   = (const float*)d_in[11];
  const float* W1     = (const float*)d_in[12];
  const float* W2     = (const float*)d_in[13];
  const float* w_attn = (const float*)d_in[14];
  const float* cls_w  = (const float*)d_in[15];
  const float* cls_b  = (const float*)d_in[16];
  float* out = (float*)d_out;

  char* ws = (char*)d_ws;
  size_t off = 0;
  auto alloc = [&](size_t bytes) -> void* {
    void* p = ws + off;
    off = (off + bytes + 255) & ~(size_t)255;
    return p;
  };
  unsigned short* buf0 = (unsigned short*)alloc((size_t)N_NODES * DIM_H * 2);
  unsigned short* buf1 = (unsigned short*)alloc((size_t)N_NODES * DIM_H * 2);
  float* ebuf   = (float*)alloc((size_t)N_NODES * 4);
  int* rowptr   = (int*)alloc((size_t)(N_NODES + 1) * 4);
  int* cursor   = (int*)alloc((size_t)(N_NODES + 1) * 4);
  int* csr      = (int*)alloc((size_t)N_EDGES * 4);
  int* part     = (int*)alloc((size_t)N_NODES * 4);
  int* bsum     = (int*)alloc(64 * 4);
  float* stats  = (float*)alloc(2 * DIM_H * 4);
  float* coef   = (float*)alloc(2 * DIM_H * 4);
  float* s2     = (float*)alloc(DIM_H * 4);
  float* scalrd = (float*)alloc(256 * 4);  // [0]=expsum, +64: rdout[192]
  float* scal   = scalrd;
  float* rdout  = scalrd + 64;
  uint4* WTall  = (uint4*)alloc((size_t)(7 * 24 * 192 + 16 * 192) * 16);

  const uint4* B1p[N_LAYERS] = {WTall, WTall + 4608, WTall + 2 * 4608};
  const uint4* B2p[N_LAYERS] = {WTall + 3 * 4608, WTall + 4 * 4608, WTall + 5 * 4608};
  const uint4* Bap = WTall + 6 * 4608;
  const uint4* Bpp = WTall + 7 * 4608;

  const int GRID64 = (N_NODES + 63) / 64;  // 782

  // weight pack
  k_wtp<<<(7 * 24 * 192 + 16 * 192 + 255) / 256, 256, 0, stream>>>(mlp1_w, mlp2_w, W1, proj_w, WTall);

  // CSR build
  hipMemsetAsync(cursor, 0, (size_t)(N_NODES + 1) * 4, stream);
  k_hist<<<(N_EDGES + 255) / 256, 256, 0, stream>>>(edge, cursor);
  k_scanA<<<SCAN_NBLK, 1024, 0, stream>>>(cursor, part, bsum);
  k_scanB<<<1, 64, 0, stream>>>(bsum);
  k_scanC<<<(N_NODES + 255) / 256, 256, 0, stream>>>(part, bsum, rowptr, cursor);
  k_fill<<<(N_EDGES + 255) / 256, 256, 0, stream>>>(edge, cursor, csr);

  // projection: x -> buf0 (relu'd h0, bf16)
  k_proj<<<GRID64, 256, 0, stream>>>(x, Bpp, proj_b, buf0);

  // GIN layers (ping-pong; BN+relu folded into next consumer)
  unsigned short* cur = buf0;
  unsigned short* nxt = buf1;
  for (int l = 0; l < N_LAYERS; ++l) {
    if (l == 0)
      k_agg<false><<<(N_NODES + 3) / 4, 256, 0, stream>>>(cur, rowptr, csr, coef, eps, l, nxt);
    else
      k_agg<true><<<(N_NODES + 3) / 4, 256, 0, stream>>>(cur, rowptr, csr, coef, eps, l, nxt);
    hipMemsetAsync(stats, 0, 2 * DIM_H * 4, stream);
    k_mlp<<<GRID64, 256, 0, stream>>>(nxt, B1p[l], mlp1_b + (size_t)l * DIM_H,
                                      B2p[l], mlp2_b + (size_t)l * DIM_H, nxt, stats);
    k_bn_final<<<1, DIM_H, 0, stream>>>(stats, bn_g + (size_t)l * DIM_H, bn_b + (size_t)l * DIM_H, coef);
    unsigned short* t = cur; cur = nxt; nxt = t;
  }
  // cur = pre-BN z2; coef = layer-2 BN; BN fused into all consumers below

  hipMemsetAsync(scalrd, 0, 256 * 4, stream);
  k_seed_s2<<<1, DIM_H, 0, stream>>>(cur, coef, seedp, W2, s2);
  k_attnm<<<GRID64, 256, 0, stream>>>(cur, coef, Bap, s2, w_attn, ebuf, scal);
  k_readout<<<256, DIM_H, 0, stream>>>(ebuf, scal, cur, coef, out + 1, rdout);
  k_logit<<<1, 256, 0, stream>>>(rdout, cls_w, cls_b, out);
}

// Round 5
// 404.304 us; speedup vs baseline: 2.5787x; 1.0897x over previous
//
#include <hip/hip_runtime.h>
#include <hip/hip_bf16.h>

#define N_NODES 50000
#define N_EDGES 400000
#define DIM_IN  128
#define DIM_H   192
#define N_LAYERS 3
#define BN_EPSF 1e-5f
#define SCAN_NBLK 49  // ceil(50000/1024)
#define INV_N (1.f / N_NODES)

typedef __attribute__((ext_vector_type(8))) short short8;
typedef __attribute__((ext_vector_type(4))) float floatx4;

union FragU { uint4 u; short8 s; };

__device__ __forceinline__ float relu_f(float x) { return x > 0.f ? x : 0.f; }
__device__ __forceinline__ unsigned short f2bf(float x) {
  __hip_bfloat16 h = __float2bfloat16(x);
  return *reinterpret_cast<unsigned short*>(&h);
}
__device__ __forceinline__ float bf2f(unsigned short b) {
  return __uint_as_float(((unsigned)b) << 16);
}
__device__ __forceinline__ float bflo(unsigned u) { return __uint_as_float(u << 16); }
__device__ __forceinline__ float bfhi(unsigned u) { return __uint_as_float(u & 0xffff0000u); }

// ---------------- CSR build ----------------
__global__ void k_hist(const int* __restrict__ edge, int* __restrict__ cnt) {
  int e = blockIdx.x * 256 + threadIdx.x;
  if (e < N_EDGES) atomicAdd(&cnt[edge[N_EDGES + e]], 1);
}

__global__ void k_scanA(const int* __restrict__ deg, int* __restrict__ part, int* __restrict__ bsum) {
  __shared__ int buf[1024];
  int g = blockIdx.x * 1024 + threadIdx.x;
  int v = (g < N_NODES) ? deg[g] : 0;
  buf[threadIdx.x] = v;
  __syncthreads();
  for (int off = 1; off < 1024; off <<= 1) {
    int t = (threadIdx.x >= off) ? buf[threadIdx.x - off] : 0;
    __syncthreads();
    buf[threadIdx.x] += t;
    __syncthreads();
  }
  if (g < N_NODES) part[g] = buf[threadIdx.x];
  if (threadIdx.x == 1023) bsum[blockIdx.x] = buf[1023];
}

__global__ void k_scanB(int* __restrict__ bsum) {
  __shared__ int b[64];
  int t = threadIdx.x;
  b[t] = (t < SCAN_NBLK) ? bsum[t] : 0;
  __syncthreads();
  for (int off = 1; off < 64; off <<= 1) {
    int v = (t >= off) ? b[t - off] : 0;
    __syncthreads();
    b[t] += v;
    __syncthreads();
  }
  if (t < SCAN_NBLK) bsum[t] = t ? b[t - 1] : 0;  // exclusive
}

// writes rowptr AND cursor (= rowptr start offsets)
__global__ void k_scanC(const int* __restrict__ part, const int* __restrict__ bsum,
                        int* __restrict__ rowptr, int* __restrict__ cursor) {
  int g = blockIdx.x * 256 + threadIdx.x;
  if (g == 0) { rowptr[0] = 0; cursor[0] = 0; }
  if (g < N_NODES) {
    int v = part[g] + bsum[g >> 10];
    rowptr[g + 1] = v;
    if (g + 1 < N_NODES) cursor[g + 1] = v;
  }
}

__global__ void k_fill(const int* __restrict__ edge, int* __restrict__ cursor, int* __restrict__ csr) {
  int e = blockIdx.x * 256 + threadIdx.x;
  if (e < N_EDGES) {
    int s = edge[e];
    int d = edge[N_EDGES + e];
    int pos = atomicAdd(&cursor[d], 1);
    csr[pos] = s;
  }
}

// ---------------- weight pack: all matrices -> frag layout [K/8][192] uint4 bf16 ----------------
__global__ void k_wtp(const float* __restrict__ m1, const float* __restrict__ m2,
                      const float* __restrict__ wa, const float* __restrict__ pw,
                      uint4* __restrict__ outp) {
  const int NH = 7 * 24 * 192;  // 7 K=192 matrices
  const int NP = 16 * 192;      // proj K=128
  int idx = blockIdx.x * 256 + threadIdx.x;
  if (idx >= NH + NP) return;
  union { uint4 u; unsigned short h[8]; } fr;
  if (idx < NH) {
    int mat = idx / (24 * 192);
    int rem = idx - mat * (24 * 192);
    int kidx = rem / 192, col = rem - kidx * 192;
    const float* src = mat < 3 ? m1 + (size_t)mat * (DIM_H * DIM_H)
                     : (mat < 6 ? m2 + (size_t)(mat - 3) * (DIM_H * DIM_H) : wa);
#pragma unroll
    for (int t = 0; t < 8; ++t) fr.h[t] = f2bf(src[(size_t)(kidx * 8 + t) * DIM_H + col]);
  } else {
    int rem = idx - NH;
    int kidx = rem / 192, col = rem - kidx * 192;
#pragma unroll
    for (int t = 0; t < 8; ++t) fr.h[t] = f2bf(pw[(size_t)(kidx * 8 + t) * DIM_H + col]);
  }
  outp[idx] = fr.u;
}

// ---------------- aggregation: 1 node/wave, lanes 0-47, 4 cols each; BN coef from stats ----------------
template <bool BN>
__global__ void k_agg(const unsigned short* __restrict__ z, const int* __restrict__ rowptr,
                      const int* __restrict__ csr, const float* __restrict__ stats,
                      const float* __restrict__ bng, const float* __restrict__ bnb,
                      const float* __restrict__ eps, int l, unsigned short* __restrict__ outA) {
  int wid = threadIdx.x >> 6, lane = threadIdx.x & 63;
  int node = blockIdx.x * 4 + wid;
  if (node >= N_NODES || lane >= 48) return;
  int c = lane * 4;
  float4 sc4 = {1.f, 1.f, 1.f, 1.f}, sh4 = {0.f, 0.f, 0.f, 0.f};
  if (BN) {
    float4 st = *(const float4*)(stats + c);
    float4 sq = *(const float4*)(stats + DIM_H + c);
    float4 g4 = *(const float4*)(bng + c);
    float4 b4 = *(const float4*)(bnb + c);
    float mu, rs;
    mu = st.x * INV_N; rs = rsqrtf(sq.x * INV_N - mu * mu + BN_EPSF); sc4.x = g4.x * rs; sh4.x = b4.x - mu * sc4.x;
    mu = st.y * INV_N; rs = rsqrtf(sq.y * INV_N - mu * mu + BN_EPSF); sc4.y = g4.y * rs; sh4.y = b4.y - mu * sc4.y;
    mu = st.z * INV_N; rs = rsqrtf(sq.z * INV_N - mu * mu + BN_EPSF); sc4.z = g4.z * rs; sh4.z = b4.z - mu * sc4.z;
    mu = st.w * INV_N; rs = rsqrtf(sq.w * INV_N - mu * mu + BN_EPSF); sc4.w = g4.w * rs; sh4.w = b4.w - mu * sc4.w;
  }
  float a0 = 0.f, a1 = 0.f, a2 = 0.f, a3 = 0.f;
  int beg = rowptr[node], end = rowptr[node + 1];
#define ACCU(U)                                                          \
  {                                                                      \
    float v0 = bflo((U).x), v1 = bfhi((U).x);                            \
    float v2 = bflo((U).y), v3 = bfhi((U).y);                            \
    if (BN) {                                                            \
      v0 = relu_f(v0 * sc4.x + sh4.x);                                   \
      v1 = relu_f(v1 * sc4.y + sh4.y);                                   \
      v2 = relu_f(v2 * sc4.z + sh4.z);                                   \
      v3 = relu_f(v3 * sc4.w + sh4.w);                                   \
    }                                                                    \
    a0 += v0; a1 += v1; a2 += v2; a3 += v3;                              \
  }
  int j = beg;
  for (; j + 2 <= end; j += 2) {
    int s0 = csr[j], s1 = csr[j + 1];
    uint2 u0 = *(const uint2*)(z + (size_t)s0 * DIM_H + c);
    uint2 u1 = *(const uint2*)(z + (size_t)s1 * DIM_H + c);
    ACCU(u0) ACCU(u1)
  }
  if (j < end) {
    int s0 = csr[j];
    uint2 u0 = *(const uint2*)(z + (size_t)s0 * DIM_H + c);
    ACCU(u0)
  }
#undef ACCU
  float ep = 1.f + eps[l];
  uint2 us = *(const uint2*)(z + (size_t)node * DIM_H + c);
  {
    float v0 = bflo(us.x), v1 = bfhi(us.x), v2 = bflo(us.y), v3 = bfhi(us.y);
    if (BN) {
      v0 = relu_f(v0 * sc4.x + sh4.x);
      v1 = relu_f(v1 * sc4.y + sh4.y);
      v2 = relu_f(v2 * sc4.z + sh4.z);
      v3 = relu_f(v3 * sc4.w + sh4.w);
    }
    a0 += ep * v0; a1 += ep * v1; a2 += ep * v2; a3 += ep * v3;
  }
  uint2 o;
  o.x = (unsigned)f2bf(a0) | ((unsigned)f2bf(a1) << 16);
  o.y = (unsigned)f2bf(a2) | ((unsigned)f2bf(a3) << 16);
  *(uint2*)(outA + (size_t)node * DIM_H + c) = o;
}

// ---------------- MFMA stage helper: MT*16 rows x 48 cols per wave, B double-buffered ----------------
template <int KS, int MT>
__device__ __forceinline__ void mfma_stage(const uint4* a_lds, const uint4* __restrict__ Bp,
                                           int colbase, int kq, int lr, floatx4 (&acc)[MT][3]) {
  FragU bcur[3], bnxt[3];
#pragma unroll
  for (int n = 0; n < 3; ++n) bcur[n].u = Bp[kq * 192 + colbase + n * 16 + lr];
#pragma unroll
  for (int ks = 0; ks < KS; ++ks) {
    if (ks + 1 < KS) {
      int kn = (ks + 1) * 4 + kq;
#pragma unroll
      for (int n = 0; n < 3; ++n) bnxt[n].u = Bp[kn * 192 + colbase + n * 16 + lr];
    }
    int kidx = ks * 4 + kq;
    FragU a[MT];
#pragma unroll
    for (int m = 0; m < MT; ++m) a[m].u = a_lds[kidx * (MT * 16) + m * 16 + lr];
#pragma unroll
    for (int n = 0; n < 3; ++n)
#pragma unroll
      for (int m = 0; m < MT; ++m)
        acc[m][n] = __builtin_amdgcn_mfma_f32_16x16x32_bf16(a[m].s, bcur[n].s, acc[m][n], 0, 0, 0);
    if (ks + 1 < KS) {
#pragma unroll
      for (int n = 0; n < 3; ++n) bcur[n] = bnxt[n];
    }
  }
}

// ---------------- MFMA projection: C = relu(x_f32[M,128] @ W + b) -> bf16 ----------------
__global__ __launch_bounds__(256) void k_proj(const float* __restrict__ A,
                                              const uint4* __restrict__ Bp,
                                              const float* __restrict__ bias,
                                              unsigned short* __restrict__ C) {
  __shared__ uint4 a_lds[16 * 64];  // 16 KB
  const int tid = threadIdx.x;
  const int rbase = blockIdx.x * 64;
#pragma unroll
  for (int i = 0; i < 4; ++i) {
    int row = tid >> 2, kidx = i * 4 + (tid & 3);
    int gr = rbase + row;
    gr = gr < N_NODES ? gr : N_NODES - 1;
    const float* ap = A + (size_t)gr * DIM_IN + kidx * 8;
    float4 v0 = *(const float4*)ap;
    float4 v1 = *(const float4*)(ap + 4);
    union { uint4 u; unsigned short h[8]; } fr;
    fr.h[0] = f2bf(v0.x); fr.h[1] = f2bf(v0.y); fr.h[2] = f2bf(v0.z); fr.h[3] = f2bf(v0.w);
    fr.h[4] = f2bf(v1.x); fr.h[5] = f2bf(v1.y); fr.h[6] = f2bf(v1.z); fr.h[7] = f2bf(v1.w);
    a_lds[kidx * 64 + row] = fr.u;
  }
  __syncthreads();
  const int lane = tid & 63, w = tid >> 6;
  const int kq = lane >> 4, lr = lane & 15;
  const int colbase = w * 48;
  floatx4 acc[4][3];
  floatx4 zero4 = {0.f, 0.f, 0.f, 0.f};
#pragma unroll
  for (int m = 0; m < 4; ++m)
#pragma unroll
    for (int n = 0; n < 3; ++n) acc[m][n] = zero4;
  mfma_stage<4, 4>(a_lds, Bp, colbase, kq, lr, acc);
#pragma unroll
  for (int n = 0; n < 3; ++n) {
    int col = colbase + n * 16 + lr;
    float bb = bias[col];
#pragma unroll
    for (int m = 0; m < 4; ++m)
#pragma unroll
      for (int j = 0; j < 4; ++j) {
        int row = rbase + m * 16 + kq * 4 + j;
        if (row < N_NODES) C[(size_t)row * DIM_H + col] = f2bf(relu_f(acc[m][n][j] + bb));
      }
  }
}

// ---------------- fused MLP (MFMA, BM=32): Z = relu(A@W1+b1)@W2+b2 (bf16), + BN stats ----------------
__global__ __launch_bounds__(256) void k_mlp(const unsigned short* __restrict__ A,
                                             const uint4* __restrict__ B1p, const float* __restrict__ b1,
                                             const uint4* __restrict__ B2p, const float* __restrict__ b2,
                                             unsigned short* __restrict__ Z, float* __restrict__ stats) {
  __shared__ uint4 a_lds[24 * 32];  // 12 KB (A, then z1, then stat scratch)
  const int tid = threadIdx.x;
  const int rbase = blockIdx.x * 32;
#pragma unroll
  for (int i = 0; i < 3; ++i) {
    int row = tid >> 3, kidx = i * 8 + (tid & 7);
    int gr = rbase + row;
    gr = gr < N_NODES ? gr : N_NODES - 1;
    a_lds[kidx * 32 + row] = *(const uint4*)(A + (size_t)gr * DIM_H + kidx * 8);
  }
  __syncthreads();
  const int lane = tid & 63, w = tid >> 6;
  const int kq = lane >> 4, lr = lane & 15;
  const int colbase = w * 48;
  floatx4 zero4 = {0.f, 0.f, 0.f, 0.f};
  floatx4 acc[2][3];
#pragma unroll
  for (int m = 0; m < 2; ++m)
#pragma unroll
    for (int n = 0; n < 3; ++n) acc[m][n] = zero4;
  mfma_stage<6, 2>(a_lds, B1p, colbase, kq, lr, acc);
  __syncthreads();  // all stage-1 reads of a_lds complete
  {
    unsigned short* zl = (unsigned short*)a_lds;
#pragma unroll
    for (int n = 0; n < 3; ++n) {
      int col = colbase + n * 16 + lr;
      float bb = b1[col];
#pragma unroll
      for (int m = 0; m < 2; ++m)
#pragma unroll
        for (int j = 0; j < 4; ++j) {
          int rowl = m * 16 + kq * 4 + j;
          zl[(col >> 3) * 256 + rowl * 8 + (col & 7)] = f2bf(relu_f(acc[m][n][j] + bb));
        }
    }
  }
  __syncthreads();
#pragma unroll
  for (int m = 0; m < 2; ++m)
#pragma unroll
    for (int n = 0; n < 3; ++n) acc[m][n] = zero4;
  mfma_stage<6, 2>(a_lds, B2p, colbase, kq, lr, acc);
  // epilogue: bias, bf16 store, BN partial stats
  float s3[3], q3[3];
#pragma unroll
  for (int n = 0; n < 3; ++n) { s3[n] = 0.f; q3[n] = 0.f; }
#pragma unroll
  for (int n = 0; n < 3; ++n) {
    int col = colbase + n * 16 + lr;
    float bb = b2[col];
#pragma unroll
    for (int m = 0; m < 2; ++m)
#pragma unroll
      for (int j = 0; j < 4; ++j) {
        int row = rbase + m * 16 + kq * 4 + j;
        if (row < N_NODES) {
          float v = acc[m][n][j] + bb;
          Z[(size_t)row * DIM_H + col] = f2bf(v);
          s3[n] += v;
          q3[n] += v * v;
        }
      }
  }
  __syncthreads();  // stage-2 a_lds reads done; reuse as stat scratch
  float* ps = (float*)a_lds;       // [192][4]
  float* pq = ps + DIM_H * 4;      // [192][4]
#pragma unroll
  for (int n = 0; n < 3; ++n) {
    int col = colbase + n * 16 + lr;
    ps[col * 4 + kq] = s3[n];
    pq[col * 4 + kq] = q3[n];
  }
  __syncthreads();
  if (tid < DIM_H) {
    float ts = 0.f, tq = 0.f;
#pragma unroll
    for (int g = 0; g < 4; ++g) {
      ts += ps[tid * 4 + g];
      tq += pq[tid * 4 + g];
    }
    atomicAdd(&stats[tid], ts);
    atomicAdd(&stats[DIM_H + tid], tq);
  }
}

// ---------------- seed row projection (BN from stats, 4 k-groups) ----------------
__global__ void k_seed_s2(const unsigned short* __restrict__ Zin, const float* __restrict__ stats,
                          const float* __restrict__ bng, const float* __restrict__ bnb,
                          const int* __restrict__ seedp, const float* __restrict__ W2,
                          float* __restrict__ s2) {
  __shared__ float hs[DIM_H];
  __shared__ float red[4][DIM_H];
  int tid = threadIdx.x;  // 768 threads
  if (tid < DIM_H) {
    int seed = seedp[0];
    float mu = stats[tid] * INV_N;
    float rs = rsqrtf(stats[DIM_H + tid] * INV_N - mu * mu + BN_EPSF);
    float sc = bng[tid] * rs;
    float sh = bnb[tid] - mu * sc;
    hs[tid] = relu_f(bf2f(Zin[(size_t)seed * DIM_H + tid]) * sc + sh);
  }
  __syncthreads();
  int a = tid % DIM_H, grp = tid / DIM_H;  // grp 0..3
  float s = 0.f;
  for (int k = grp * 48; k < grp * 48 + 48; ++k) s = fmaf(hs[k], W2[(size_t)k * DIM_H + a], s);
  red[grp][a] = s;
  __syncthreads();
  if (tid < DIM_H) s2[tid] = red[0][tid] + red[1][tid] + red[2][tid] + red[3][tid];
}

// ---------------- attention: stores p=exp(leaky(e)) and accumulates expsum ----------------
__global__ __launch_bounds__(256) void k_attnm(const unsigned short* __restrict__ Zin,
                                               const float* __restrict__ stats,
                                               const float* __restrict__ bng,
                                               const float* __restrict__ bnb,
                                               const uint4* __restrict__ Bp,
                                               const float* __restrict__ s2,
                                               const float* __restrict__ wat,
                                               float* __restrict__ p, float* __restrict__ scal) {
  __shared__ uint4 a_lds[24 * 64];  // reused as part[64][65]
  __shared__ float cs[DIM_H], ch[DIM_H];
  const int tid = threadIdx.x;
  const int rbase = blockIdx.x * 64;
  if (tid < DIM_H) {
    float mu = stats[tid] * INV_N;
    float rs = rsqrtf(stats[DIM_H + tid] * INV_N - mu * mu + BN_EPSF);
    float sc = bng[tid] * rs;
    cs[tid] = sc;
    ch[tid] = bnb[tid] - mu * sc;
  }
  __syncthreads();
#pragma unroll
  for (int i = 0; i < 6; ++i) {
    int row = tid >> 2, kidx = i * 4 + (tid & 3);
    int gr = rbase + row;
    gr = gr < N_NODES ? gr : N_NODES - 1;
    union { uint4 u; unsigned short h[8]; } v, o;
    v.u = *(const uint4*)(Zin + (size_t)gr * DIM_H + kidx * 8);
#pragma unroll
    for (int t = 0; t < 8; ++t)
      o.h[t] = f2bf(relu_f(bf2f(v.h[t]) * cs[kidx * 8 + t] + ch[kidx * 8 + t]));
    a_lds[kidx * 64 + row] = o.u;
  }
  __syncthreads();
  const int lane = tid & 63, w = tid >> 6;
  const int kq = lane >> 4, lr = lane & 15;
  const int colbase = w * 48;
  floatx4 zero4 = {0.f, 0.f, 0.f, 0.f};
  floatx4 acc[4][3];
#pragma unroll
  for (int m = 0; m < 4; ++m)
#pragma unroll
    for (int n = 0; n < 3; ++n) acc[m][n] = zero4;
  mfma_stage<6, 4>(a_lds, Bp, colbase, kq, lr, acc);
  float pv[16];
#pragma unroll
  for (int t = 0; t < 16; ++t) pv[t] = 0.f;
#pragma unroll
  for (int n = 0; n < 3; ++n) {
    int col = colbase + n * 16 + lr;
    float s2c = s2[col];
    float wv = wat[col];
#pragma unroll
    for (int m = 0; m < 4; ++m)
#pragma unroll
      for (int j = 0; j < 4; ++j) {
        float xv = acc[m][n][j] + s2c;
        xv = fminf(fmaxf(xv, -10.f), 10.f);
        float t = __expf(2.f * xv);
        pv[m * 4 + j] = fmaf((t - 1.f) / (t + 1.f), wv, pv[m * 4 + j]);
      }
  }
  __syncthreads();  // a_lds MFMA reads done
  float* part = (float*)a_lds;  // [64][65]
#pragma unroll
  for (int m = 0; m < 4; ++m)
#pragma unroll
    for (int j = 0; j < 4; ++j)
      part[(m * 16 + kq * 4 + j) * 65 + w * 16 + lr] = pv[m * 4 + j];
  __syncthreads();
  if (tid < 64) {
    float s = 0.f;
#pragma unroll
    for (int i = 0; i < 64; ++i) s += part[tid * 65 + i];
    s = s > 0.f ? s : 0.2f * s;
    float pe = __expf(s);
    int gr = rbase + tid;
    bool valid = gr < N_NODES;
    if (valid) p[gr] = pe;
    pe = valid ? pe : 0.f;
#pragma unroll
    for (int off = 32; off > 0; off >>= 1) pe += __shfl_xor(pe, off);
    if (tid == 0) atomicAdd(&scal[0], pe);
  }
}

// ---------------- alpha = p / S ----------------
__global__ void k_alpha(const float* __restrict__ p, const float* __restrict__ scal,
                        float* __restrict__ alpha) {
  int i = blockIdx.x * 256 + threadIdx.x;
  if (i < N_NODES) alpha[i] = p[i] * (1.f / scal[0]);
}

// ---------------- readout partial: rdout[c] += sum_r p_r * h_r[c]  (unnormalized) ----------------
#define RD_BLOCKS 512
__global__ __launch_bounds__(256) void k_readout(const float* __restrict__ p,
                                                 const unsigned short* __restrict__ Zin,
                                                 const float* __restrict__ stats,
                                                 const float* __restrict__ bng,
                                                 const float* __restrict__ bnb,
                                                 float* __restrict__ rdout) {
  __shared__ float red[4][DIM_H];
  const int tid = threadIdx.x;
  const int w = tid >> 6, lane = tid & 63;
  const int rpb = (N_NODES + RD_BLOCKS - 1) / RD_BLOCKS;  // 98
  int rbeg = blockIdx.x * rpb;
  int rend = rbeg + rpb;
  rend = rend < N_NODES ? rend : N_NODES;
  float a0 = 0.f, a1 = 0.f, a2 = 0.f, a3 = 0.f;
  if (lane < 48) {
    int c = lane * 4;
    float4 st = *(const float4*)(stats + c);
    float4 sq = *(const float4*)(stats + DIM_H + c);
    float4 g4 = *(const float4*)(bng + c);
    float4 b4 = *(const float4*)(bnb + c);
    float4 sc4, sh4;
    float mu, rs;
    mu = st.x * INV_N; rs = rsqrtf(sq.x * INV_N - mu * mu + BN_EPSF); sc4.x = g4.x * rs; sh4.x = b4.x - mu * sc4.x;
    mu = st.y * INV_N; rs = rsqrtf(sq.y * INV_N - mu * mu + BN_EPSF); sc4.y = g4.y * rs; sh4.y = b4.y - mu * sc4.y;
    mu = st.z * INV_N; rs = rsqrtf(sq.z * INV_N - mu * mu + BN_EPSF); sc4.z = g4.z * rs; sh4.z = b4.z - mu * sc4.z;
    mu = st.w * INV_N; rs = rsqrtf(sq.w * INV_N - mu * mu + BN_EPSF); sc4.w = g4.w * rs; sh4.w = b4.w - mu * sc4.w;
#pragma unroll 2
    for (int r = rbeg + w; r < rend; r += 4) {
      float pw = p[r];
      uint2 u = *(const uint2*)(Zin + (size_t)r * DIM_H + c);
      float v0 = relu_f(bflo(u.x) * sc4.x + sh4.x);
      float v1 = relu_f(bfhi(u.x) * sc4.y + sh4.y);
      float v2 = relu_f(bflo(u.y) * sc4.z + sh4.z);
      float v3 = relu_f(bfhi(u.y) * sc4.w + sh4.w);
      a0 = fmaf(pw, v0, a0); a1 = fmaf(pw, v1, a1);
      a2 = fmaf(pw, v2, a2); a3 = fmaf(pw, v3, a3);
    }
    float4 o = {a0, a1, a2, a3};
    *(float4*)&red[w][c] = o;
  }
  __syncthreads();
  if (tid < DIM_H) {
    float s = red[0][tid] + red[1][tid] + red[2][tid] + red[3][tid];
    atomicAdd(&rdout[tid], s);
  }
}

__global__ void k_logit(const float* __restrict__ rdout, const float* __restrict__ scal,
                        const float* __restrict__ cw, const float* __restrict__ cb,
                        float* __restrict__ out) {
  __shared__ float buf[256];
  int tid = threadIdx.x;
  buf[tid] = (tid < DIM_H) ? rdout[tid] * cw[tid] : 0.f;
  __syncthreads();
  for (int s = 128; s > 0; s >>= 1) {
    if (tid < s) buf[tid] += buf[tid + s];
    __syncthreads();
  }
  if (tid == 0) out[0] = buf[0] * (1.f / scal[0]) + cb[0];
}

extern "C" void kernel_launch(void* const* d_in, const int* in_sizes, int n_in,
                              void* d_out, int out_size, void* d_ws, size_t ws_size,
                              hipStream_t stream) {
  const float* x      = (const float*)d_in[0];
  const int*   edge   = (const int*)d_in[1];
  const int*   seedp  = (const int*)d_in[2];
  const float* proj_w = (const float*)d_in[3];
  const float* proj_b = (const float*)d_in[4];
  const float* mlp1_w = (const float*)d_in[5];
  const float* mlp1_b = (const float*)d_in[6];
  const float* mlp2_w = (const float*)d_in[7];
  const float* mlp2_b = (const float*)d_in[8];
  const float* eps    = (const float*)d_in[9];
  const float* bn_g   = (const float*)d_in[10];
  const float* bn_b   = (const float*)d_in[11];
  const float* W1     = (const float*)d_in[12];
  const float* W2     = (const float*)d_in[13];
  const float* w_attn = (const float*)d_in[14];
  const float* cls_w  = (const float*)d_in[15];
  const float* cls_b  = (const float*)d_in[16];
  float* out = (float*)d_out;

  char* ws = (char*)d_ws;
  size_t off = 0;
  auto alloc = [&](size_t bytes) -> void* {
    void* p = ws + off;
    off = (off + bytes + 255) & ~(size_t)255;
    return p;
  };
  unsigned short* buf0 = (unsigned short*)alloc((size_t)N_NODES * DIM_H * 2);
  unsigned short* buf1 = (unsigned short*)alloc((size_t)N_NODES * DIM_H * 2);
  float* pbuf   = (float*)alloc((size_t)N_NODES * 4);
  int* rowptr   = (int*)alloc((size_t)(N_NODES + 1) * 4);
  int* cursor   = (int*)alloc((size_t)(N_NODES + 1) * 4);
  int* csr      = (int*)alloc((size_t)N_EDGES * 4);
  int* part     = (int*)alloc((size_t)N_NODES * 4);
  int* bsum     = (int*)alloc(64 * 4);
  float* stats  = (float*)alloc(2 * DIM_H * 4);
  float* s2     = (float*)alloc(DIM_H * 4);
  float* scalrd = (float*)alloc(256 * 4);  // [0]=expsum, +64: rdout[192]
  float* scal   = scalrd;
  float* rdout  = scalrd + 64;
  uint4* WTall  = (uint4*)alloc((size_t)(7 * 24 * 192 + 16 * 192) * 16);

  const uint4* B1p[N_LAYERS] = {WTall, WTall + 4608, WTall + 2 * 4608};
  const uint4* B2p[N_LAYERS] = {WTall + 3 * 4608, WTall + 4 * 4608, WTall + 5 * 4608};
  const uint4* Bap = WTall + 6 * 4608;
  const uint4* Bpp = WTall + 7 * 4608;

  const int GRID64 = (N_NODES + 63) / 64;   // 782
  const int GRID32 = (N_NODES + 31) / 32;   // 1563

  // weight pack
  k_wtp<<<(7 * 24 * 192 + 16 * 192 + 255) / 256, 256, 0, stream>>>(mlp1_w, mlp2_w, W1, proj_w, WTall);

  // CSR build
  hipMemsetAsync(cursor, 0, (size_t)(N_NODES + 1) * 4, stream);
  k_hist<<<(N_EDGES + 255) / 256, 256, 0, stream>>>(edge, cursor);
  k_scanA<<<SCAN_NBLK, 1024, 0, stream>>>(cursor, part, bsum);
  k_scanB<<<1, 64, 0, stream>>>(bsum);
  k_scanC<<<(N_NODES + 255) / 256, 256, 0, stream>>>(part, bsum, rowptr, cursor);
  k_fill<<<(N_EDGES + 255) / 256, 256, 0, stream>>>(edge, cursor, csr);

  // projection: x -> buf0 (relu'd h0, bf16)
  k_proj<<<GRID64, 256, 0, stream>>>(x, Bpp, proj_b, buf0);

  // GIN layers (ping-pong; BN+relu folded into next consumer, coef computed from stats inline)
  unsigned short* cur = buf0;
  unsigned short* nxt = buf1;
  for (int l = 0; l < N_LAYERS; ++l) {
    const float* g_prev = bn_g + (size_t)(l - 1) * DIM_H;
    const float* b_prev = bn_b + (size_t)(l - 1) * DIM_H;
    if (l == 0)
      k_agg<false><<<(N_NODES + 3) / 4, 256, 0, stream>>>(cur, rowptr, csr, stats, g_prev, b_prev, eps, l, nxt);
    else
      k_agg<true><<<(N_NODES + 3) / 4, 256, 0, stream>>>(cur, rowptr, csr, stats, g_prev, b_prev, eps, l, nxt);
    hipMemsetAsync(stats, 0, 2 * DIM_H * 4, stream);
    k_mlp<<<GRID32, 256, 0, stream>>>(nxt, B1p[l], mlp1_b + (size_t)l * DIM_H,
                                      B2p[l], mlp2_b + (size_t)l * DIM_H, nxt, stats);
    unsigned short* t = cur; cur = nxt; nxt = t;
  }
  // cur = pre-BN z2; stats = layer-2 stats; BN fused into all consumers below
  const float* g2 = bn_g + (size_t)2 * DIM_H;
  const float* b2c = bn_b + (size_t)2 * DIM_H;

  hipMemsetAsync(scalrd, 0, 256 * 4, stream);
  k_seed_s2<<<1, 768, 0, stream>>>(cur, stats, g2, b2c, seedp, W2, s2);
  k_attnm<<<GRID64, 256, 0, stream>>>(cur, stats, g2, b2c, Bap, s2, w_attn, pbuf, scal);
  k_alpha<<<(N_NODES + 255) / 256, 256, 0, stream>>>(pbuf, scal, out + 1);
  k_readout<<<RD_BLOCKS, 256, 0, stream>>>(pbuf, cur, stats, g2, b2c, rdout);
  k_logit<<<1, 256, 0, stream>>>(rdout, scal, cls_w, cls_b, out);
}

// Round 6
// 397.441 us; speedup vs baseline: 2.6233x; 1.0173x over previous
//
#include <hip/hip_runtime.h>
#include <hip/hip_bf16.h>

#define N_NODES 50000
#define N_EDGES 400000
#define DIM_IN  128
#define DIM_H   192
#define N_LAYERS 3
#define BN_EPSF 1e-5f
#define SCAN_NBLK 49  // ceil(50000/1024)
#define INV_N (1.f / N_NODES)

typedef __attribute__((ext_vector_type(8))) short short8;
typedef __attribute__((ext_vector_type(4))) float floatx4;

union FragU { uint4 u; short8 s; };

__device__ __forceinline__ float relu_f(float x) { return x > 0.f ? x : 0.f; }
__device__ __forceinline__ unsigned short f2bf(float x) {
  __hip_bfloat16 h = __float2bfloat16(x);
  return *reinterpret_cast<unsigned short*>(&h);
}
__device__ __forceinline__ float bf2f(unsigned short b) {
  return __uint_as_float(((unsigned)b) << 16);
}
__device__ __forceinline__ float bflo(unsigned u) { return __uint_as_float(u << 16); }
__device__ __forceinline__ float bfhi(unsigned u) { return __uint_as_float(u & 0xffff0000u); }

// ---------------- CSR build ----------------
__global__ void k_hist(const int* __restrict__ edge, int* __restrict__ cnt) {
  int e = blockIdx.x * 256 + threadIdx.x;
  if (e < N_EDGES) atomicAdd(&cnt[edge[N_EDGES + e]], 1);
}

__global__ void k_scanA(const int* __restrict__ deg, int* __restrict__ part, int* __restrict__ bsum) {
  __shared__ int buf[1024];
  int g = blockIdx.x * 1024 + threadIdx.x;
  int v = (g < N_NODES) ? deg[g] : 0;
  buf[threadIdx.x] = v;
  __syncthreads();
  for (int off = 1; off < 1024; off <<= 1) {
    int t = (threadIdx.x >= off) ? buf[threadIdx.x - off] : 0;
    __syncthreads();
    buf[threadIdx.x] += t;
    __syncthreads();
  }
  if (g < N_NODES) part[g] = buf[threadIdx.x];
  if (threadIdx.x == 1023) bsum[blockIdx.x] = buf[1023];
}

__global__ void k_scanB(int* __restrict__ bsum) {
  __shared__ int b[64];
  int t = threadIdx.x;
  b[t] = (t < SCAN_NBLK) ? bsum[t] : 0;
  __syncthreads();
  for (int off = 1; off < 64; off <<= 1) {
    int v = (t >= off) ? b[t - off] : 0;
    __syncthreads();
    b[t] += v;
    __syncthreads();
  }
  if (t < SCAN_NBLK) bsum[t] = t ? b[t - 1] : 0;  // exclusive
}

// writes rowptr AND cursor (= rowptr start offsets)
__global__ void k_scanC(const int* __restrict__ part, const int* __restrict__ bsum,
                        int* __restrict__ rowptr, int* __restrict__ cursor) {
  int g = blockIdx.x * 256 + threadIdx.x;
  if (g == 0) { rowptr[0] = 0; cursor[0] = 0; }
  if (g < N_NODES) {
    int v = part[g] + bsum[g >> 10];
    rowptr[g + 1] = v;
    if (g + 1 < N_NODES) cursor[g + 1] = v;
  }
}

__global__ void k_fill(const int* __restrict__ edge, int* __restrict__ cursor, int* __restrict__ csr) {
  int e = blockIdx.x * 256 + threadIdx.x;
  if (e < N_EDGES) {
    int s = edge[e];
    int d = edge[N_EDGES + e];
    int pos = atomicAdd(&cursor[d], 1);
    csr[pos] = s;
  }
}

// ---------------- weight pack: all matrices -> frag layout [K/8][192] uint4 bf16 ----------------
__global__ void k_wtp(const float* __restrict__ m1, const float* __restrict__ m2,
                      const float* __restrict__ wa, const float* __restrict__ pw,
                      uint4* __restrict__ outp) {
  const int NH = 7 * 24 * 192;  // 7 K=192 matrices
  const int NP = 16 * 192;      // proj K=128
  int idx = blockIdx.x * 256 + threadIdx.x;
  if (idx >= NH + NP) return;
  union { uint4 u; unsigned short h[8]; } fr;
  if (idx < NH) {
    int mat = idx / (24 * 192);
    int rem = idx - mat * (24 * 192);
    int kidx = rem / 192, col = rem - kidx * 192;
    const float* src = mat < 3 ? m1 + (size_t)mat * (DIM_H * DIM_H)
                     : (mat < 6 ? m2 + (size_t)(mat - 3) * (DIM_H * DIM_H) : wa);
#pragma unroll
    for (int t = 0; t < 8; ++t) fr.h[t] = f2bf(src[(size_t)(kidx * 8 + t) * DIM_H + col]);
  } else {
    int rem = idx - NH;
    int kidx = rem / 192, col = rem - kidx * 192;
#pragma unroll
    for (int t = 0; t < 8; ++t) fr.h[t] = f2bf(pw[(size_t)(kidx * 8 + t) * DIM_H + col]);
  }
  outp[idx] = fr.u;
}

// ---------------- aggregation: 1 node/wave, lanes 0-47, 4 cols each; BN coef from stats ----------------
template <bool BN>
__global__ void k_agg(const unsigned short* __restrict__ z, const int* __restrict__ rowptr,
                      const int* __restrict__ csr, const float* __restrict__ stats,
                      const float* __restrict__ bng, const float* __restrict__ bnb,
                      const float* __restrict__ eps, int l, unsigned short* __restrict__ outA) {
  int wid = threadIdx.x >> 6, lane = threadIdx.x & 63;
  int node = blockIdx.x * 4 + wid;
  if (node >= N_NODES || lane >= 48) return;
  int c = lane * 4;
  float4 sc4 = {1.f, 1.f, 1.f, 1.f}, sh4 = {0.f, 0.f, 0.f, 0.f};
  if (BN) {
    float4 st = *(const float4*)(stats + c);
    float4 sq = *(const float4*)(stats + DIM_H + c);
    float4 g4 = *(const float4*)(bng + c);
    float4 b4 = *(const float4*)(bnb + c);
    float mu, rs;
    mu = st.x * INV_N; rs = rsqrtf(sq.x * INV_N - mu * mu + BN_EPSF); sc4.x = g4.x * rs; sh4.x = b4.x - mu * sc4.x;
    mu = st.y * INV_N; rs = rsqrtf(sq.y * INV_N - mu * mu + BN_EPSF); sc4.y = g4.y * rs; sh4.y = b4.y - mu * sc4.y;
    mu = st.z * INV_N; rs = rsqrtf(sq.z * INV_N - mu * mu + BN_EPSF); sc4.z = g4.z * rs; sh4.z = b4.z - mu * sc4.z;
    mu = st.w * INV_N; rs = rsqrtf(sq.w * INV_N - mu * mu + BN_EPSF); sc4.w = g4.w * rs; sh4.w = b4.w - mu * sc4.w;
  }
  float a0 = 0.f, a1 = 0.f, a2 = 0.f, a3 = 0.f;
  int beg = rowptr[node], end = rowptr[node + 1];
#define ACCU(U)                                                          \
  {                                                                      \
    float v0 = bflo((U).x), v1 = bfhi((U).x);                            \
    float v2 = bflo((U).y), v3 = bfhi((U).y);                            \
    if (BN) {                                                            \
      v0 = relu_f(v0 * sc4.x + sh4.x);                                   \
      v1 = relu_f(v1 * sc4.y + sh4.y);                                   \
      v2 = relu_f(v2 * sc4.z + sh4.z);                                   \
      v3 = relu_f(v3 * sc4.w + sh4.w);                                   \
    }                                                                    \
    a0 += v0; a1 += v1; a2 += v2; a3 += v3;                              \
  }
  int j = beg;
  for (; j + 2 <= end; j += 2) {
    int s0 = csr[j], s1 = csr[j + 1];
    uint2 u0 = *(const uint2*)(z + (size_t)s0 * DIM_H + c);
    uint2 u1 = *(const uint2*)(z + (size_t)s1 * DIM_H + c);
    ACCU(u0) ACCU(u1)
  }
  if (j < end) {
    int s0 = csr[j];
    uint2 u0 = *(const uint2*)(z + (size_t)s0 * DIM_H + c);
    ACCU(u0)
  }
#undef ACCU
  float ep = 1.f + eps[l];
  uint2 us = *(const uint2*)(z + (size_t)node * DIM_H + c);
  {
    float v0 = bflo(us.x), v1 = bfhi(us.x), v2 = bflo(us.y), v3 = bfhi(us.y);
    if (BN) {
      v0 = relu_f(v0 * sc4.x + sh4.x);
      v1 = relu_f(v1 * sc4.y + sh4.y);
      v2 = relu_f(v2 * sc4.z + sh4.z);
      v3 = relu_f(v3 * sc4.w + sh4.w);
    }
    a0 += ep * v0; a1 += ep * v1; a2 += ep * v2; a3 += ep * v3;
  }
  uint2 o;
  o.x = (unsigned)f2bf(a0) | ((unsigned)f2bf(a1) << 16);
  o.y = (unsigned)f2bf(a2) | ((unsigned)f2bf(a3) << 16);
  *(uint2*)(outA + (size_t)node * DIM_H + c) = o;
}

// ---------------- bulk B loader + MFMA stage on pre-loaded B ----------------
template <int KS>
__device__ __forceinline__ void load_b(const uint4* __restrict__ Bp, int colbase, int kq, int lr,
                                       FragU (&b)[KS][3]) {
#pragma unroll
  for (int ks = 0; ks < KS; ++ks)
#pragma unroll
    for (int n = 0; n < 3; ++n)
      b[ks][n].u = Bp[(ks * 4 + kq) * 192 + colbase + n * 16 + lr];
}

template <int KS, int MT>
__device__ __forceinline__ void mfma_stage_pre(const uint4* a_lds, const FragU (&b)[KS][3],
                                               int kq, int lr, floatx4 (&acc)[MT][3]) {
#pragma unroll
  for (int ks = 0; ks < KS; ++ks) {
    int kidx = ks * 4 + kq;
    FragU a[MT];
#pragma unroll
    for (int m = 0; m < MT; ++m) a[m].u = a_lds[kidx * (MT * 16) + m * 16 + lr];
#pragma unroll
    for (int n = 0; n < 3; ++n)
#pragma unroll
      for (int m = 0; m < MT; ++m)
        acc[m][n] = __builtin_amdgcn_mfma_f32_16x16x32_bf16(a[m].s, b[ks][n].s, acc[m][n], 0, 0, 0);
  }
}

// ---------------- MFMA projection: C = relu(x_f32[M,128] @ W + b) -> bf16 ----------------
__global__ __launch_bounds__(256) void k_proj(const float* __restrict__ A,
                                              const uint4* __restrict__ Bp,
                                              const float* __restrict__ bias,
                                              unsigned short* __restrict__ C) {
  __shared__ uint4 a_lds[16 * 64];  // 16 KB
  const int tid = threadIdx.x;
  const int rbase = blockIdx.x * 64;
  const int lane = tid & 63, w = tid >> 6;
  const int kq = lane >> 4, lr = lane & 15;
  const int colbase = w * 48;
  FragU b[4][3];
  load_b<4>(Bp, colbase, kq, lr, b);  // B in flight during A staging
#pragma unroll
  for (int i = 0; i < 4; ++i) {
    int row = tid >> 2, kidx = i * 4 + (tid & 3);
    int gr = rbase + row;
    gr = gr < N_NODES ? gr : N_NODES - 1;
    const float* ap = A + (size_t)gr * DIM_IN + kidx * 8;
    float4 v0 = *(const float4*)ap;
    float4 v1 = *(const float4*)(ap + 4);
    union { uint4 u; unsigned short h[8]; } fr;
    fr.h[0] = f2bf(v0.x); fr.h[1] = f2bf(v0.y); fr.h[2] = f2bf(v0.z); fr.h[3] = f2bf(v0.w);
    fr.h[4] = f2bf(v1.x); fr.h[5] = f2bf(v1.y); fr.h[6] = f2bf(v1.z); fr.h[7] = f2bf(v1.w);
    a_lds[kidx * 64 + row] = fr.u;
  }
  __syncthreads();
  floatx4 acc[4][3];
  floatx4 zero4 = {0.f, 0.f, 0.f, 0.f};
#pragma unroll
  for (int m = 0; m < 4; ++m)
#pragma unroll
    for (int n = 0; n < 3; ++n) acc[m][n] = zero4;
  mfma_stage_pre<4, 4>(a_lds, b, kq, lr, acc);
#pragma unroll
  for (int n = 0; n < 3; ++n) {
    int col = colbase + n * 16 + lr;
    float bb = bias[col];
#pragma unroll
    for (int m = 0; m < 4; ++m)
#pragma unroll
      for (int j = 0; j < 4; ++j) {
        int row = rbase + m * 16 + kq * 4 + j;
        if (row < N_NODES) C[(size_t)row * DIM_H + col] = f2bf(relu_f(acc[m][n][j] + bb));
      }
  }
}

// ---------------- fused MLP (MFMA, BM=32): Z = relu(A@W1+b1)@W2+b2 (bf16), + BN stats ----------------
__global__ __launch_bounds__(256) void k_mlp(const unsigned short* __restrict__ A,
                                             const uint4* __restrict__ B1p, const float* __restrict__ b1,
                                             const uint4* __restrict__ B2p, const float* __restrict__ b2,
                                             unsigned short* __restrict__ Z, float* __restrict__ stats) {
  __shared__ uint4 a_lds[24 * 32];  // 12 KB (A, then z1, then stat scratch)
  const int tid = threadIdx.x;
  const int rbase = blockIdx.x * 32;
  const int lane = tid & 63, w = tid >> 6;
  const int kq = lane >> 4, lr = lane & 15;
  const int colbase = w * 48;
  // issue A loads first, then the full stage-1 B batch; LDS write only waits on A
  uint4 areg[3];
  int arow = tid >> 3;
  int agr = rbase + arow;
  agr = agr < N_NODES ? agr : N_NODES - 1;
#pragma unroll
  for (int i = 0; i < 3; ++i) {
    int kidx = i * 8 + (tid & 7);
    areg[i] = *(const uint4*)(A + (size_t)agr * DIM_H + kidx * 8);
  }
  FragU b1r[6][3];
  load_b<6>(B1p, colbase, kq, lr, b1r);
#pragma unroll
  for (int i = 0; i < 3; ++i) {
    int kidx = i * 8 + (tid & 7);
    a_lds[kidx * 32 + arow] = areg[i];
  }
  __syncthreads();
  floatx4 zero4 = {0.f, 0.f, 0.f, 0.f};
  floatx4 acc[2][3];
#pragma unroll
  for (int m = 0; m < 2; ++m)
#pragma unroll
    for (int n = 0; n < 3; ++n) acc[m][n] = zero4;
  mfma_stage_pre<6, 2>(a_lds, b1r, kq, lr, acc);
  // stage-2 B batch: in flight across the two barriers + z1 epilogue
  FragU b2r[6][3];
  load_b<6>(B2p, colbase, kq, lr, b2r);
  __syncthreads();  // all stage-1 reads of a_lds complete
  {
    unsigned short* zl = (unsigned short*)a_lds;
#pragma unroll
    for (int n = 0; n < 3; ++n) {
      int col = colbase + n * 16 + lr;
      float bb = b1[col];
#pragma unroll
      for (int m = 0; m < 2; ++m)
#pragma unroll
        for (int j = 0; j < 4; ++j) {
          int rowl = m * 16 + kq * 4 + j;
          zl[(col >> 3) * 256 + rowl * 8 + (col & 7)] = f2bf(relu_f(acc[m][n][j] + bb));
        }
    }
  }
  __syncthreads();
#pragma unroll
  for (int m = 0; m < 2; ++m)
#pragma unroll
    for (int n = 0; n < 3; ++n) acc[m][n] = zero4;
  mfma_stage_pre<6, 2>(a_lds, b2r, kq, lr, acc);
  // epilogue: bias, bf16 store, BN partial stats
  float s3[3], q3[3];
#pragma unroll
  for (int n = 0; n < 3; ++n) { s3[n] = 0.f; q3[n] = 0.f; }
#pragma unroll
  for (int n = 0; n < 3; ++n) {
    int col = colbase + n * 16 + lr;
    float bb = b2[col];
#pragma unroll
    for (int m = 0; m < 2; ++m)
#pragma unroll
      for (int j = 0; j < 4; ++j) {
        int row = rbase + m * 16 + kq * 4 + j;
        if (row < N_NODES) {
          float v = acc[m][n][j] + bb;
          Z[(size_t)row * DIM_H + col] = f2bf(v);
          s3[n] += v;
          q3[n] += v * v;
        }
      }
  }
  __syncthreads();  // stage-2 a_lds reads done; reuse as stat scratch
  float* ps = (float*)a_lds;       // [192][4]
  float* pq = ps + DIM_H * 4;      // [192][4]
#pragma unroll
  for (int n = 0; n < 3; ++n) {
    int col = colbase + n * 16 + lr;
    ps[col * 4 + kq] = s3[n];
    pq[col * 4 + kq] = q3[n];
  }
  __syncthreads();
  if (tid < DIM_H) {
    float ts = 0.f, tq = 0.f;
#pragma unroll
    for (int g = 0; g < 4; ++g) {
      ts += ps[tid * 4 + g];
      tq += pq[tid * 4 + g];
    }
    atomicAdd(&stats[tid], ts);
    atomicAdd(&stats[DIM_H + tid], tq);
  }
}

// ---------------- seed row projection (BN from stats, 4 k-groups) ----------------
__global__ void k_seed_s2(const unsigned short* __restrict__ Zin, const float* __restrict__ stats,
                          const float* __restrict__ bng, const float* __restrict__ bnb,
                          const int* __restrict__ seedp, const float* __restrict__ W2,
                          float* __restrict__ s2) {
  __shared__ float hs[DIM_H];
  __shared__ float red[4][DIM_H];
  int tid = threadIdx.x;  // 768 threads
  if (tid < DIM_H) {
    int seed = seedp[0];
    float mu = stats[tid] * INV_N;
    float rs = rsqrtf(stats[DIM_H + tid] * INV_N - mu * mu + BN_EPSF);
    float sc = bng[tid] * rs;
    float sh = bnb[tid] - mu * sc;
    hs[tid] = relu_f(bf2f(Zin[(size_t)seed * DIM_H + tid]) * sc + sh);
  }
  __syncthreads();
  int a = tid % DIM_H, grp = tid / DIM_H;  // grp 0..3
  float s = 0.f;
  for (int k = grp * 48; k < grp * 48 + 48; ++k) s = fmaf(hs[k], W2[(size_t)k * DIM_H + a], s);
  red[grp][a] = s;
  __syncthreads();
  if (tid < DIM_H) s2[tid] = red[0][tid] + red[1][tid] + red[2][tid] + red[3][tid];
}

// ---------------- attention: stores p=exp(leaky(e)) and accumulates expsum ----------------
__global__ __launch_bounds__(256) void k_attnm(const unsigned short* __restrict__ Zin,
                                               const float* __restrict__ stats,
                                               const float* __restrict__ bng,
                                               const float* __restrict__ bnb,
                                               const uint4* __restrict__ Bp,
                                               const float* __restrict__ s2,
                                               const float* __restrict__ wat,
                                               float* __restrict__ p, float* __restrict__ scal) {
  __shared__ uint4 a_lds[24 * 64];  // reused as part[64][65]
  __shared__ float cs[DIM_H], ch[DIM_H];
  const int tid = threadIdx.x;
  const int rbase = blockIdx.x * 64;
  const int lane = tid & 63, w = tid >> 6;
  const int kq = lane >> 4, lr = lane & 15;
  const int colbase = w * 48;
  FragU b[6][3];
  load_b<6>(Bp, colbase, kq, lr, b);  // in flight during coef + staging
  if (tid < DIM_H) {
    float mu = stats[tid] * INV_N;
    float rs = rsqrtf(stats[DIM_H + tid] * INV_N - mu * mu + BN_EPSF);
    float sc = bng[tid] * rs;
    cs[tid] = sc;
    ch[tid] = bnb[tid] - mu * sc;
  }
  __syncthreads();
#pragma unroll
  for (int i = 0; i < 6; ++i) {
    int row = tid >> 2, kidx = i * 4 + (tid & 3);
    int gr = rbase + row;
    gr = gr < N_NODES ? gr : N_NODES - 1;
    union { uint4 u; unsigned short h[8]; } v, o;
    v.u = *(const uint4*)(Zin + (size_t)gr * DIM_H + kidx * 8);
#pragma unroll
    for (int t = 0; t < 8; ++t)
      o.h[t] = f2bf(relu_f(bf2f(v.h[t]) * cs[kidx * 8 + t] + ch[kidx * 8 + t]));
    a_lds[kidx * 64 + row] = o.u;
  }
  __syncthreads();
  floatx4 zero4 = {0.f, 0.f, 0.f, 0.f};
  floatx4 acc[4][3];
#pragma unroll
  for (int m = 0; m < 4; ++m)
#pragma unroll
    for (int n = 0; n < 3; ++n) acc[m][n] = zero4;
  mfma_stage_pre<6, 4>(a_lds, b, kq, lr, acc);
  float pv[16];
#pragma unroll
  for (int t = 0; t < 16; ++t) pv[t] = 0.f;
#pragma unroll
  for (int n = 0; n < 3; ++n) {
    int col = colbase + n * 16 + lr;
    float s2c = s2[col];
    float wv = wat[col];
#pragma unroll
    for (int m = 0; m < 4; ++m)
#pragma unroll
      for (int j = 0; j < 4; ++j) {
        float xv = acc[m][n][j] + s2c;
        xv = fminf(fmaxf(xv, -10.f), 10.f);
        float t = __expf(2.f * xv);
        pv[m * 4 + j] = fmaf((t - 1.f) / (t + 1.f), wv, pv[m * 4 + j]);
      }
  }
  __syncthreads();  // a_lds MFMA reads done
  float* part = (float*)a_lds;  // [64][65]
#pragma unroll
  for (int m = 0; m < 4; ++m)
#pragma unroll
    for (int j = 0; j < 4; ++j)
      part[(m * 16 + kq * 4 + j) * 65 + w * 16 + lr] = pv[m * 4 + j];
  __syncthreads();
  if (tid < 64) {
    float s = 0.f;
#pragma unroll
    for (int i = 0; i < 64; ++i) s += part[tid * 65 + i];
    s = s > 0.f ? s : 0.2f * s;
    float pe = __expf(s);
    int gr = rbase + tid;
    bool valid = gr < N_NODES;
    if (valid) p[gr] = pe;
    pe = valid ? pe : 0.f;
#pragma unroll
    for (int off = 32; off > 0; off >>= 1) pe += __shfl_xor(pe, off);
    if (tid == 0) atomicAdd(&scal[0], pe);
  }
}

// ---------------- alpha = p / S ----------------
__global__ void k_alpha(const float* __restrict__ p, const float* __restrict__ scal,
                        float* __restrict__ alpha) {
  int i = blockIdx.x * 256 + threadIdx.x;
  if (i < N_NODES) alpha[i] = p[i] * (1.f / scal[0]);
}

// ---------------- readout partial: rdout[c] += sum_r p_r * h_r[c]  (unnormalized) ----------------
#define RD_BLOCKS 512
__global__ __launch_bounds__(256) void k_readout(const float* __restrict__ p,
                                                 const unsigned short* __restrict__ Zin,
                                                 const float* __restrict__ stats,
                                                 const float* __restrict__ bng,
                                                 const float* __restrict__ bnb,
                                                 float* __restrict__ rdout) {
  __shared__ float red[4][DIM_H];
  const int tid = threadIdx.x;
  const int w = tid >> 6, lane = tid & 63;
  const int rpb = (N_NODES + RD_BLOCKS - 1) / RD_BLOCKS;  // 98
  int rbeg = blockIdx.x * rpb;
  int rend = rbeg + rpb;
  rend = rend < N_NODES ? rend : N_NODES;
  float a0 = 0.f, a1 = 0.f, a2 = 0.f, a3 = 0.f;
  if (lane < 48) {
    int c = lane * 4;
    float4 st = *(const float4*)(stats + c);
    float4 sq = *(const float4*)(stats + DIM_H + c);
    float4 g4 = *(const float4*)(bng + c);
    float4 b4 = *(const float4*)(bnb + c);
    float4 sc4, sh4;
    float mu, rs;
    mu = st.x * INV_N; rs = rsqrtf(sq.x * INV_N - mu * mu + BN_EPSF); sc4.x = g4.x * rs; sh4.x = b4.x - mu * sc4.x;
    mu = st.y * INV_N; rs = rsqrtf(sq.y * INV_N - mu * mu + BN_EPSF); sc4.y = g4.y * rs; sh4.y = b4.y - mu * sc4.y;
    mu = st.z * INV_N; rs = rsqrtf(sq.z * INV_N - mu * mu + BN_EPSF); sc4.z = g4.z * rs; sh4.z = b4.z - mu * sc4.z;
    mu = st.w * INV_N; rs = rsqrtf(sq.w * INV_N - mu * mu + BN_EPSF); sc4.w = g4.w * rs; sh4.w = b4.w - mu * sc4.w;
#pragma unroll 2
    for (int r = rbeg + w; r < rend; r += 4) {
      float pw = p[r];
      uint2 u = *(const uint2*)(Zin + (size_t)r * DIM_H + c);
      float v0 = relu_f(bflo(u.x) * sc4.x + sh4.x);
      float v1 = relu_f(bfhi(u.x) * sc4.y + sh4.y);
      float v2 = relu_f(bflo(u.y) * sc4.z + sh4.z);
      float v3 = relu_f(bfhi(u.y) * sc4.w + sh4.w);
      a0 = fmaf(pw, v0, a0); a1 = fmaf(pw, v1, a1);
      a2 = fmaf(pw, v2, a2); a3 = fmaf(pw, v3, a3);
    }
    float4 o = {a0, a1, a2, a3};
    *(float4*)&red[w][c] = o;
  }
  __syncthreads();
  if (tid < DIM_H) {
    float s = red[0][tid] + red[1][tid] + red[2][tid] + red[3][tid];
    atomicAdd(&rdout[tid], s);
  }
}

__global__ void k_logit(const float* __restrict__ rdout, const float* __restrict__ scal,
                        const float* __restrict__ cw, const float* __restrict__ cb,
                        float* __restrict__ out) {
  __shared__ float buf[256];
  int tid = threadIdx.x;
  buf[tid] = (tid < DIM_H) ? rdout[tid] * cw[tid] : 0.f;
  __syncthreads();
  for (int s = 128; s > 0; s >>= 1) {
    if (tid < s) buf[tid] += buf[tid + s];
    __syncthreads();
  }
  if (tid == 0) out[0] = buf[0] * (1.f / scal[0]) + cb[0];
}

extern "C" void kernel_launch(void* const* d_in, const int* in_sizes, int n_in,
                              void* d_out, int out_size, void* d_ws, size_t ws_size,
                              hipStream_t stream) {
  const float* x      = (const float*)d_in[0];
  const int*   edge   = (const int*)d_in[1];
  const int*   seedp  = (const int*)d_in[2];
  const float* proj_w = (const float*)d_in[3];
  const float* proj_b = (const float*)d_in[4];
  const float* mlp1_w = (const float*)d_in[5];
  const float* mlp1_b = (const float*)d_in[6];
  const float* mlp2_w = (const float*)d_in[7];
  const float* mlp2_b = (const float*)d_in[8];
  const float* eps    = (const float*)d_in[9];
  const float* bn_g   = (const float*)d_in[10];
  const float* bn_b   = (const float*)d_in[11];
  const float* W1     = (const float*)d_in[12];
  const float* W2     = (const float*)d_in[13];
  const float* w_attn = (const float*)d_in[14];
  const float* cls_w  = (const float*)d_in[15];
  const float* cls_b  = (const float*)d_in[16];
  float* out = (float*)d_out;

  char* ws = (char*)d_ws;
  size_t off = 0;
  auto alloc = [&](size_t bytes) -> void* {
    void* p = ws + off;
    off = (off + bytes + 255) & ~(size_t)255;
    return p;
  };
  unsigned short* buf0 = (unsigned short*)alloc((size_t)N_NODES * DIM_H * 2);
  unsigned short* buf1 = (unsigned short*)alloc((size_t)N_NODES * DIM_H * 2);
  float* pbuf   = (float*)alloc((size_t)N_NODES * 4);
  int* rowptr   = (int*)alloc((size_t)(N_NODES + 1) * 4);
  int* cursor   = (int*)alloc((size_t)(N_NODES + 1) * 4);
  int* csr      = (int*)alloc((size_t)N_EDGES * 4);
  int* part     = (int*)alloc((size_t)N_NODES * 4);
  int* bsum     = (int*)alloc(64 * 4);
  float* stats  = (float*)alloc(2 * DIM_H * 4);
  float* s2     = (float*)alloc(DIM_H * 4);
  float* scalrd = (float*)alloc(256 * 4);  // [0]=expsum, +64: rdout[192]
  float* scal   = scalrd;
  float* rdout  = scalrd + 64;
  uint4* WTall  = (uint4*)alloc((size_t)(7 * 24 * 192 + 16 * 192) * 16);

  const uint4* B1p[N_LAYERS] = {WTall, WTall + 4608, WTall + 2 * 4608};
  const uint4* B2p[N_LAYERS] = {WTall + 3 * 4608, WTall + 4 * 4608, WTall + 5 * 4608};
  const uint4* Bap = WTall + 6 * 4608;
  const uint4* Bpp = WTall + 7 * 4608;

  const int GRID64 = (N_NODES + 63) / 64;   // 782
  const int GRID32 = (N_NODES + 31) / 32;   // 1563

  // weight pack
  k_wtp<<<(7 * 24 * 192 + 16 * 192 + 255) / 256, 256, 0, stream>>>(mlp1_w, mlp2_w, W1, proj_w, WTall);

  // CSR build
  hipMemsetAsync(cursor, 0, (size_t)(N_NODES + 1) * 4, stream);
  k_hist<<<(N_EDGES + 255) / 256, 256, 0, stream>>>(edge, cursor);
  k_scanA<<<SCAN_NBLK, 1024, 0, stream>>>(cursor, part, bsum);
  k_scanB<<<1, 64, 0, stream>>>(bsum);
  k_scanC<<<(N_NODES + 255) / 256, 256, 0, stream>>>(part, bsum, rowptr, cursor);
  k_fill<<<(N_EDGES + 255) / 256, 256, 0, stream>>>(edge, cursor, csr);

  // projection: x -> buf0 (relu'd h0, bf16)
  k_proj<<<GRID64, 256, 0, stream>>>(x, Bpp, proj_b, buf0);

  // GIN layers (ping-pong; BN+relu folded into next consumer, coef computed from stats inline)
  unsigned short* cur = buf0;
  unsigned short* nxt = buf1;
  for (int l = 0; l < N_LAYERS; ++l) {
    const float* g_prev = bn_g + (size_t)(l - 1) * DIM_H;
    const float* b_prev = bn_b + (size_t)(l - 1) * DIM_H;
    if (l == 0)
      k_agg<false><<<(N_NODES + 3) / 4, 256, 0, stream>>>(cur, rowptr, csr, stats, g_prev, b_prev, eps, l, nxt);
    else
      k_agg<true><<<(N_NODES + 3) / 4, 256, 0, stream>>>(cur, rowptr, csr, stats, g_prev, b_prev, eps, l, nxt);
    hipMemsetAsync(stats, 0, 2 * DIM_H * 4, stream);
    k_mlp<<<GRID32, 256, 0, stream>>>(nxt, B1p[l], mlp1_b + (size_t)l * DIM_H,
                                      B2p[l], mlp2_b + (size_t)l * DIM_H, nxt, stats);
    unsigned short* t = cur; cur = nxt; nxt = t;
  }
  // cur = pre-BN z2; stats = layer-2 stats; BN fused into all consumers below
  const float* g2 = bn_g + (size_t)2 * DIM_H;
  const float* b2c = bn_b + (size_t)2 * DIM_H;

  hipMemsetAsync(scalrd, 0, 256 * 4, stream);
  k_seed_s2<<<1, 768, 0, stream>>>(cur, stats, g2, b2c, seedp, W2, s2);
  k_attnm<<<GRID64, 256, 0, stream>>>(cur, stats, g2, b2c, Bap, s2, w_attn, pbuf, scal);
  k_alpha<<<(N_NODES + 255) / 256, 256, 0, stream>>>(pbuf, scal, out + 1);
  k_readout<<<RD_BLOCKS, 256, 0, stream>>>(pbuf, cur, stats, g2, b2c, rdout);
  k_logit<<<1, 256, 0, stream>>>(rdout, scal, cls_w, cls_b, out);
}

// Round 7
// 338.640 us; speedup vs baseline: 3.0788x; 1.1736x over previous
//
#include <hip/hip_runtime.h>
#include <hip/hip_bf16.h>

#define N_NODES 50000
#define N_EDGES 400000
#define DIM_IN  128
#define DIM_H   192
#define N_LAYERS 3
#define BN_EPSF 1e-5f
#define SCAN_NBLK 49  // ceil(50000/1024)
#define INV_N (1.f / N_NODES)
#define NSHADOW 8
#define SSTRIDE 384   // per-shadow: [0..191]=sum, [192..383]=sumsq

typedef __attribute__((ext_vector_type(8))) short short8;
typedef __attribute__((ext_vector_type(4))) float floatx4;

union FragU { uint4 u; short8 s; };

__device__ __forceinline__ float relu_f(float x) { return x > 0.f ? x : 0.f; }
__device__ __forceinline__ unsigned short f2bf(float x) {
  __hip_bfloat16 h = __float2bfloat16(x);
  return *reinterpret_cast<unsigned short*>(&h);
}
__device__ __forceinline__ float bf2f(unsigned short b) {
  return __uint_as_float(((unsigned)b) << 16);
}
__device__ __forceinline__ float bflo(unsigned u) { return __uint_as_float(u << 16); }
__device__ __forceinline__ float bfhi(unsigned u) { return __uint_as_float(u & 0xffff0000u); }

// ---------------- CSR build ----------------
__global__ void k_hist(const int* __restrict__ edge, int* __restrict__ cnt) {
  int e = blockIdx.x * 256 + threadIdx.x;
  if (e < N_EDGES) atomicAdd(&cnt[edge[N_EDGES + e]], 1);
}

__global__ void k_scanA(const int* __restrict__ deg, int* __restrict__ part, int* __restrict__ bsum) {
  __shared__ int buf[1024];
  int g = blockIdx.x * 1024 + threadIdx.x;
  int v = (g < N_NODES) ? deg[g] : 0;
  buf[threadIdx.x] = v;
  __syncthreads();
  for (int off = 1; off < 1024; off <<= 1) {
    int t = (threadIdx.x >= off) ? buf[threadIdx.x - off] : 0;
    __syncthreads();
    buf[threadIdx.x] += t;
    __syncthreads();
  }
  if (g < N_NODES) part[g] = buf[threadIdx.x];
  if (threadIdx.x == 1023) bsum[blockIdx.x] = buf[1023];
}

__global__ void k_scanB(int* __restrict__ bsum) {
  __shared__ int b[64];
  int t = threadIdx.x;
  b[t] = (t < SCAN_NBLK) ? bsum[t] : 0;
  __syncthreads();
  for (int off = 1; off < 64; off <<= 1) {
    int v = (t >= off) ? b[t - off] : 0;
    __syncthreads();
    b[t] += v;
    __syncthreads();
  }
  if (t < SCAN_NBLK) bsum[t] = t ? b[t - 1] : 0;  // exclusive
}

// writes rowptr AND cursor (= rowptr start offsets)
__global__ void k_scanC(const int* __restrict__ part, const int* __restrict__ bsum,
                        int* __restrict__ rowptr, int* __restrict__ cursor) {
  int g = blockIdx.x * 256 + threadIdx.x;
  if (g == 0) { rowptr[0] = 0; cursor[0] = 0; }
  if (g < N_NODES) {
    int v = part[g] + bsum[g >> 10];
    rowptr[g + 1] = v;
    if (g + 1 < N_NODES) cursor[g + 1] = v;
  }
}

__global__ void k_fill(const int* __restrict__ edge, int* __restrict__ cursor, int* __restrict__ csr) {
  int e = blockIdx.x * 256 + threadIdx.x;
  if (e < N_EDGES) {
    int s = edge[e];
    int d = edge[N_EDGES + e];
    int pos = atomicAdd(&cursor[d], 1);
    csr[pos] = s;
  }
}

// ---------------- weight pack: all matrices -> frag layout [K/8][192] uint4 bf16 ----------------
__global__ void k_wtp(const float* __restrict__ m1, const float* __restrict__ m2,
                      const float* __restrict__ wa, const float* __restrict__ pw,
                      uint4* __restrict__ outp) {
  const int NH = 7 * 24 * 192;  // 7 K=192 matrices
  const int NP = 16 * 192;      // proj K=128
  int idx = blockIdx.x * 256 + threadIdx.x;
  if (idx >= NH + NP) return;
  union { uint4 u; unsigned short h[8]; } fr;
  if (idx < NH) {
    int mat = idx / (24 * 192);
    int rem = idx - mat * (24 * 192);
    int kidx = rem / 192, col = rem - kidx * 192;
    const float* src = mat < 3 ? m1 + (size_t)mat * (DIM_H * DIM_H)
                     : (mat < 6 ? m2 + (size_t)(mat - 3) * (DIM_H * DIM_H) : wa);
#pragma unroll
    for (int t = 0; t < 8; ++t) fr.h[t] = f2bf(src[(size_t)(kidx * 8 + t) * DIM_H + col]);
  } else {
    int rem = idx - NH;
    int kidx = rem / 192, col = rem - kidx * 192;
#pragma unroll
    for (int t = 0; t < 8; ++t) fr.h[t] = f2bf(pw[(size_t)(kidx * 8 + t) * DIM_H + col]);
  }
  outp[idx] = fr.u;
}

// ---------------- aggregation: 1 node/wave, lanes 0-47, 4 cols each; BN coef from shadow stats ----------------
template <bool BN>
__global__ void k_agg(const unsigned short* __restrict__ z, const int* __restrict__ rowptr,
                      const int* __restrict__ csr, const float* __restrict__ stats,
                      const float* __restrict__ bng, const float* __restrict__ bnb,
                      const float* __restrict__ eps, int l, unsigned short* __restrict__ outA) {
  int wid = threadIdx.x >> 6, lane = threadIdx.x & 63;
  int node = blockIdx.x * 4 + wid;
  if (node >= N_NODES || lane >= 48) return;
  int c = lane * 4;
  float4 sc4 = {1.f, 1.f, 1.f, 1.f}, sh4 = {0.f, 0.f, 0.f, 0.f};
  if (BN) {
    float4 st = {0.f, 0.f, 0.f, 0.f}, sq = {0.f, 0.f, 0.f, 0.f};
#pragma unroll
    for (int g = 0; g < NSHADOW; ++g) {
      const float* sp = stats + g * SSTRIDE;
      float4 a = *(const float4*)(sp + c);
      float4 b = *(const float4*)(sp + DIM_H + c);
      st.x += a.x; st.y += a.y; st.z += a.z; st.w += a.w;
      sq.x += b.x; sq.y += b.y; sq.z += b.z; sq.w += b.w;
    }
    float4 g4 = *(const float4*)(bng + c);
    float4 b4 = *(const float4*)(bnb + c);
    float mu, rs;
    mu = st.x * INV_N; rs = rsqrtf(sq.x * INV_N - mu * mu + BN_EPSF); sc4.x = g4.x * rs; sh4.x = b4.x - mu * sc4.x;
    mu = st.y * INV_N; rs = rsqrtf(sq.y * INV_N - mu * mu + BN_EPSF); sc4.y = g4.y * rs; sh4.y = b4.y - mu * sc4.y;
    mu = st.z * INV_N; rs = rsqrtf(sq.z * INV_N - mu * mu + BN_EPSF); sc4.z = g4.z * rs; sh4.z = b4.z - mu * sc4.z;
    mu = st.w * INV_N; rs = rsqrtf(sq.w * INV_N - mu * mu + BN_EPSF); sc4.w = g4.w * rs; sh4.w = b4.w - mu * sc4.w;
  }
  float a0 = 0.f, a1 = 0.f, a2 = 0.f, a3 = 0.f;
  int beg = rowptr[node], end = rowptr[node + 1];
#define ACCU(U)                                                          \
  {                                                                      \
    float v0 = bflo((U).x), v1 = bfhi((U).x);                            \
    float v2 = bflo((U).y), v3 = bfhi((U).y);                            \
    if (BN) {                                                            \
      v0 = relu_f(v0 * sc4.x + sh4.x);                                   \
      v1 = relu_f(v1 * sc4.y + sh4.y);                                   \
      v2 = relu_f(v2 * sc4.z + sh4.z);                                   \
      v3 = relu_f(v3 * sc4.w + sh4.w);                                   \
    }                                                                    \
    a0 += v0; a1 += v1; a2 += v2; a3 += v3;                              \
  }
  int j = beg;
  for (; j + 4 <= end; j += 4) {
    int s0 = csr[j], s1 = csr[j + 1], s2 = csr[j + 2], s3 = csr[j + 3];
    uint2 u0 = *(const uint2*)(z + (size_t)s0 * DIM_H + c);
    uint2 u1 = *(const uint2*)(z + (size_t)s1 * DIM_H + c);
    uint2 u2 = *(const uint2*)(z + (size_t)s2 * DIM_H + c);
    uint2 u3 = *(const uint2*)(z + (size_t)s3 * DIM_H + c);
    ACCU(u0) ACCU(u1) ACCU(u2) ACCU(u3)
  }
  for (; j < end; ++j) {
    int s0 = csr[j];
    uint2 u0 = *(const uint2*)(z + (size_t)s0 * DIM_H + c);
    ACCU(u0)
  }
#undef ACCU
  float ep = 1.f + eps[l];
  uint2 us = *(const uint2*)(z + (size_t)node * DIM_H + c);
  {
    float v0 = bflo(us.x), v1 = bfhi(us.x), v2 = bflo(us.y), v3 = bfhi(us.y);
    if (BN) {
      v0 = relu_f(v0 * sc4.x + sh4.x);
      v1 = relu_f(v1 * sc4.y + sh4.y);
      v2 = relu_f(v2 * sc4.z + sh4.z);
      v3 = relu_f(v3 * sc4.w + sh4.w);
    }
    a0 += ep * v0; a1 += ep * v1; a2 += ep * v2; a3 += ep * v3;
  }
  uint2 o;
  o.x = (unsigned)f2bf(a0) | ((unsigned)f2bf(a1) << 16);
  o.y = (unsigned)f2bf(a2) | ((unsigned)f2bf(a3) << 16);
  *(uint2*)(outA + (size_t)node * DIM_H + c) = o;
}

// ---------------- bulk B loader + MFMA stage on pre-loaded B ----------------
template <int KS>
__device__ __forceinline__ void load_b(const uint4* __restrict__ Bp, int colbase, int kq, int lr,
                                       FragU (&b)[KS][3]) {
#pragma unroll
  for (int ks = 0; ks < KS; ++ks)
#pragma unroll
    for (int n = 0; n < 3; ++n)
      b[ks][n].u = Bp[(ks * 4 + kq) * 192 + colbase + n * 16 + lr];
}

template <int KS, int MT>
__device__ __forceinline__ void mfma_stage_pre(const uint4* a_lds, const FragU (&b)[KS][3],
                                               int kq, int lr, floatx4 (&acc)[MT][3]) {
#pragma unroll
  for (int ks = 0; ks < KS; ++ks) {
    int kidx = ks * 4 + kq;
    FragU a[MT];
#pragma unroll
    for (int m = 0; m < MT; ++m) a[m].u = a_lds[kidx * (MT * 16) + m * 16 + lr];
#pragma unroll
    for (int n = 0; n < 3; ++n)
#pragma unroll
      for (int m = 0; m < MT; ++m)
        acc[m][n] = __builtin_amdgcn_mfma_f32_16x16x32_bf16(a[m].s, b[ks][n].s, acc[m][n], 0, 0, 0);
  }
}

// ---------------- MFMA projection: C = relu(x_f32[M,128] @ W + b) -> bf16 ----------------
__global__ __launch_bounds__(256) void k_proj(const float* __restrict__ A,
                                              const uint4* __restrict__ Bp,
                                              const float* __restrict__ bias,
                                              unsigned short* __restrict__ C) {
  __shared__ uint4 a_lds[16 * 64];  // 16 KB
  const int tid = threadIdx.x;
  const int rbase = blockIdx.x * 64;
  const int lane = tid & 63, w = tid >> 6;
  const int kq = lane >> 4, lr = lane & 15;
  const int colbase = w * 48;
  FragU b[4][3];
  load_b<4>(Bp, colbase, kq, lr, b);  // B in flight during A staging
#pragma unroll
  for (int i = 0; i < 4; ++i) {
    int row = tid >> 2, kidx = i * 4 + (tid & 3);
    int gr = rbase + row;
    gr = gr < N_NODES ? gr : N_NODES - 1;
    const float* ap = A + (size_t)gr * DIM_IN + kidx * 8;
    float4 v0 = *(const float4*)ap;
    float4 v1 = *(const float4*)(ap + 4);
    union { uint4 u; unsigned short h[8]; } fr;
    fr.h[0] = f2bf(v0.x); fr.h[1] = f2bf(v0.y); fr.h[2] = f2bf(v0.z); fr.h[3] = f2bf(v0.w);
    fr.h[4] = f2bf(v1.x); fr.h[5] = f2bf(v1.y); fr.h[6] = f2bf(v1.z); fr.h[7] = f2bf(v1.w);
    a_lds[kidx * 64 + row] = fr.u;
  }
  __syncthreads();
  floatx4 acc[4][3];
  floatx4 zero4 = {0.f, 0.f, 0.f, 0.f};
#pragma unroll
  for (int m = 0; m < 4; ++m)
#pragma unroll
    for (int n = 0; n < 3; ++n) acc[m][n] = zero4;
  mfma_stage_pre<4, 4>(a_lds, b, kq, lr, acc);
#pragma unroll
  for (int n = 0; n < 3; ++n) {
    int col = colbase + n * 16 + lr;
    float bb = bias[col];
#pragma unroll
    for (int m = 0; m < 4; ++m)
#pragma unroll
      for (int j = 0; j < 4; ++j) {
        int row = rbase + m * 16 + kq * 4 + j;
        if (row < N_NODES) C[(size_t)row * DIM_H + col] = f2bf(relu_f(acc[m][n][j] + bb));
      }
  }
}

// ---------------- k_mlp helpers ----------------
__device__ __forceinline__ void z_epi(floatx4 (&acc)[2][3], unsigned short* zl, const float* __restrict__ b1,
                                      int colbase, int kq, int lr) {
#pragma unroll
  for (int n = 0; n < 3; ++n) {
    int col = colbase + n * 16 + lr;
    float bb = b1[col];
#pragma unroll
    for (int m = 0; m < 2; ++m)
#pragma unroll
      for (int j = 0; j < 4; ++j) {
        int rowl = m * 16 + kq * 4 + j;
        zl[(col >> 3) * 256 + rowl * 8 + (col & 7)] = f2bf(relu_f(acc[m][n][j] + bb));
      }
  }
}

__device__ __forceinline__ void out_epi(floatx4 (&acc)[2][3], unsigned short* __restrict__ Z,
                                        const float* __restrict__ b2, int rb, int colbase, int kq, int lr,
                                        float (&s3)[3], float (&q3)[3]) {
#pragma unroll
  for (int n = 0; n < 3; ++n) {
    int col = colbase + n * 16 + lr;
    float bb = b2[col];
#pragma unroll
    for (int m = 0; m < 2; ++m)
#pragma unroll
      for (int j = 0; j < 4; ++j) {
        int row = rb + m * 16 + kq * 4 + j;
        if (row < N_NODES) {
          float v = acc[m][n][j] + bb;
          Z[(size_t)row * DIM_H + col] = f2bf(v);
          s3[n] += v;
          q3[n] += v * v;
        }
      }
  }
}

// ---------------- fused MLP (MFMA, BM=64 = 2x32 tiles, B reused): Z = relu(A@W1+b1)@W2+b2 ----------------
__global__ __launch_bounds__(256, 3) void k_mlp(const unsigned short* __restrict__ A,
                                                const uint4* __restrict__ B1p, const float* __restrict__ b1,
                                                const uint4* __restrict__ B2p, const float* __restrict__ b2,
                                                unsigned short* __restrict__ Z, float* __restrict__ stats) {
  __shared__ uint4 a_lds[2][24 * 32];  // 24 KB (A tiles, then z1 tiles, then stat scratch)
  const int tid = threadIdx.x;
  const int rbase = blockIdx.x * 64;
  const int lane = tid & 63, w = tid >> 6;
  const int kq = lane >> 4, lr = lane & 15;
  const int colbase = w * 48;
  // A loads for both tiles issued first; B1 batch next; LDS writes wait only on A
  uint4 areg[2][3];
  const int arow = tid >> 3;
#pragma unroll
  for (int t = 0; t < 2; ++t) {
    int agr = rbase + t * 32 + arow;
    agr = agr < N_NODES ? agr : N_NODES - 1;
#pragma unroll
    for (int i = 0; i < 3; ++i) {
      int kidx = i * 8 + (tid & 7);
      areg[t][i] = *(const uint4*)(A + (size_t)agr * DIM_H + kidx * 8);
    }
  }
  FragU b1r[6][3];
  load_b<6>(B1p, colbase, kq, lr, b1r);
#pragma unroll
  for (int t = 0; t < 2; ++t)
#pragma unroll
    for (int i = 0; i < 3; ++i) {
      int kidx = i * 8 + (tid & 7);
      a_lds[t][kidx * 32 + arow] = areg[t][i];
    }
  __syncthreads();
  floatx4 zero4 = {0.f, 0.f, 0.f, 0.f};
  floatx4 acc0[2][3], acc1[2][3];
#pragma unroll
  for (int m = 0; m < 2; ++m)
#pragma unroll
    for (int n = 0; n < 3; ++n) { acc0[m][n] = zero4; acc1[m][n] = zero4; }
  mfma_stage_pre<6, 2>(a_lds[0], b1r, kq, lr, acc0);
  mfma_stage_pre<6, 2>(a_lds[1], b1r, kq, lr, acc1);
  // stage-2 B batch: in flight across the barriers + z1 epilogues (b1r dead after this point)
  FragU b2r[6][3];
  load_b<6>(B2p, colbase, kq, lr, b2r);
  __syncthreads();  // all stage-1 reads of a_lds complete
  z_epi(acc0, (unsigned short*)a_lds[0], b1, colbase, kq, lr);
  z_epi(acc1, (unsigned short*)a_lds[1], b1, colbase, kq, lr);
  __syncthreads();
#pragma unroll
  for (int m = 0; m < 2; ++m)
#pragma unroll
    for (int n = 0; n < 3; ++n) { acc0[m][n] = zero4; acc1[m][n] = zero4; }
  mfma_stage_pre<6, 2>(a_lds[0], b2r, kq, lr, acc0);
  mfma_stage_pre<6, 2>(a_lds[1], b2r, kq, lr, acc1);
  float s3[3] = {0.f, 0.f, 0.f}, q3[3] = {0.f, 0.f, 0.f};
  out_epi(acc0, Z, b2, rbase, colbase, kq, lr, s3, q3);
  out_epi(acc1, Z, b2, rbase + 32, colbase, kq, lr, s3, q3);
  __syncthreads();  // stage-2 a_lds reads done; reuse as stat scratch
  float* ps = (float*)a_lds;       // [192][4]
  float* pq = ps + DIM_H * 4;      // [192][4]
#pragma unroll
  for (int n = 0; n < 3; ++n) {
    int col = colbase + n * 16 + lr;
    ps[col * 4 + kq] = s3[n];
    pq[col * 4 + kq] = q3[n];
  }
  __syncthreads();
  if (tid < DIM_H) {
    float ts = 0.f, tq = 0.f;
#pragma unroll
    for (int g = 0; g < 4; ++g) {
      ts += ps[tid * 4 + g];
      tq += pq[tid * 4 + g];
    }
    float* sp = stats + (blockIdx.x & (NSHADOW - 1)) * SSTRIDE;
    atomicAdd(&sp[tid], ts);
    atomicAdd(&sp[DIM_H + tid], tq);
  }
}

// ---------------- seed row projection (BN from shadow stats, 4 k-groups) ----------------
__global__ void k_seed_s2(const unsigned short* __restrict__ Zin, const float* __restrict__ stats,
                          const float* __restrict__ bng, const float* __restrict__ bnb,
                          const int* __restrict__ seedp, const float* __restrict__ W2,
                          float* __restrict__ s2) {
  __shared__ float hs[DIM_H];
  __shared__ float red[4][DIM_H];
  int tid = threadIdx.x;  // 768 threads
  if (tid < DIM_H) {
    int seed = seedp[0];
    float ts = 0.f, tq = 0.f;
#pragma unroll
    for (int g = 0; g < NSHADOW; ++g) {
      ts += stats[g * SSTRIDE + tid];
      tq += stats[g * SSTRIDE + DIM_H + tid];
    }
    float mu = ts * INV_N;
    float rs = rsqrtf(tq * INV_N - mu * mu + BN_EPSF);
    float sc = bng[tid] * rs;
    float sh = bnb[tid] - mu * sc;
    hs[tid] = relu_f(bf2f(Zin[(size_t)seed * DIM_H + tid]) * sc + sh);
  }
  __syncthreads();
  int a = tid % DIM_H, grp = tid / DIM_H;  // grp 0..3
  float s = 0.f;
  for (int k = grp * 48; k < grp * 48 + 48; ++k) s = fmaf(hs[k], W2[(size_t)k * DIM_H + a], s);
  red[grp][a] = s;
  __syncthreads();
  if (tid < DIM_H) s2[tid] = red[0][tid] + red[1][tid] + red[2][tid] + red[3][tid];
}

// ---------------- attention: stores p=exp(leaky(e)) and accumulates expsum ----------------
__global__ __launch_bounds__(256, 3) void k_attnm(const unsigned short* __restrict__ Zin,
                                                  const float* __restrict__ stats,
                                                  const float* __restrict__ bng,
                                                  const float* __restrict__ bnb,
                                                  const uint4* __restrict__ Bp,
                                                  const float* __restrict__ s2,
                                                  const float* __restrict__ wat,
                                                  float* __restrict__ p, float* __restrict__ scal) {
  __shared__ uint4 a_lds[24 * 64];  // reused as part[64][65]
  __shared__ float cs[DIM_H], ch[DIM_H];
  const int tid = threadIdx.x;
  const int rbase = blockIdx.x * 64;
  const int lane = tid & 63, w = tid >> 6;
  const int kq = lane >> 4, lr = lane & 15;
  const int colbase = w * 48;
  FragU b[6][3];
  load_b<6>(Bp, colbase, kq, lr, b);  // in flight during coef + staging
  if (tid < DIM_H) {
    float ts = 0.f, tq = 0.f;
#pragma unroll
    for (int g = 0; g < NSHADOW; ++g) {
      ts += stats[g * SSTRIDE + tid];
      tq += stats[g * SSTRIDE + DIM_H + tid];
    }
    float mu = ts * INV_N;
    float rs = rsqrtf(tq * INV_N - mu * mu + BN_EPSF);
    float sc = bng[tid] * rs;
    cs[tid] = sc;
    ch[tid] = bnb[tid] - mu * sc;
  }
  __syncthreads();
#pragma unroll
  for (int i = 0; i < 6; ++i) {
    int row = tid >> 2, kidx = i * 4 + (tid & 3);
    int gr = rbase + row;
    gr = gr < N_NODES ? gr : N_NODES - 1;
    union { uint4 u; unsigned short h[8]; } v, o;
    v.u = *(const uint4*)(Zin + (size_t)gr * DIM_H + kidx * 8);
#pragma unroll
    for (int t = 0; t < 8; ++t)
      o.h[t] = f2bf(relu_f(bf2f(v.h[t]) * cs[kidx * 8 + t] + ch[kidx * 8 + t]));
    a_lds[kidx * 64 + row] = o.u;
  }
  __syncthreads();
  floatx4 zero4 = {0.f, 0.f, 0.f, 0.f};
  floatx4 acc[4][3];
#pragma unroll
  for (int m = 0; m < 4; ++m)
#pragma unroll
    for (int n = 0; n < 3; ++n) acc[m][n] = zero4;
  mfma_stage_pre<6, 4>(a_lds, b, kq, lr, acc);
  float pv[16];
#pragma unroll
  for (int t = 0; t < 16; ++t) pv[t] = 0.f;
#pragma unroll
  for (int n = 0; n < 3; ++n) {
    int col = colbase + n * 16 + lr;
    float s2c = s2[col];
    float wv = wat[col];
#pragma unroll
    for (int m = 0; m < 4; ++m)
#pragma unroll
      for (int j = 0; j < 4; ++j) {
        float xv = acc[m][n][j] + s2c;
        xv = fminf(fmaxf(xv, -10.f), 10.f);
        float t = __expf(2.f * xv);
        pv[m * 4 + j] = fmaf((t - 1.f) / (t + 1.f), wv, pv[m * 4 + j]);
      }
  }
  __syncthreads();  // a_lds MFMA reads done
  float* part = (float*)a_lds;  // [64][65]
#pragma unroll
  for (int m = 0; m < 4; ++m)
#pragma unroll
    for (int j = 0; j < 4; ++j)
      part[(m * 16 + kq * 4 + j) * 65 + w * 16 + lr] = pv[m * 4 + j];
  __syncthreads();
  if (tid < 64) {
    float s = 0.f;
#pragma unroll
    for (int i = 0; i < 64; ++i) s += part[tid * 65 + i];
    s = s > 0.f ? s : 0.2f * s;
    float pe = __expf(s);
    int gr = rbase + tid;
    bool valid = gr < N_NODES;
    if (valid) p[gr] = pe;
    pe = valid ? pe : 0.f;
#pragma unroll
    for (int off = 32; off > 0; off >>= 1) pe += __shfl_xor(pe, off);
    if (tid == 0) atomicAdd(&scal[0], pe);
  }
}

// ---------------- alpha = p / S ----------------
__global__ void k_alpha(const float* __restrict__ p, const float* __restrict__ scal,
                        float* __restrict__ alpha) {
  int i = blockIdx.x * 256 + threadIdx.x;
  if (i < N_NODES) alpha[i] = p[i] * (1.f / scal[0]);
}

// ---------------- readout partial: rdout[c] += sum_r p_r * h_r[c]  (unnormalized) ----------------
#define RD_BLOCKS 512
__global__ __launch_bounds__(256) void k_readout(const float* __restrict__ p,
                                                 const unsigned short* __restrict__ Zin,
                                                 const float* __restrict__ stats,
                                                 const float* __restrict__ bng,
                                                 const float* __restrict__ bnb,
                                                 float* __restrict__ rdout) {
  __shared__ float red[4][DIM_H];
  const int tid = threadIdx.x;
  const int w = tid >> 6, lane = tid & 63;
  const int rpb = (N_NODES + RD_BLOCKS - 1) / RD_BLOCKS;  // 98
  int rbeg = blockIdx.x * rpb;
  int rend = rbeg + rpb;
  rend = rend < N_NODES ? rend : N_NODES;
  float a0 = 0.f, a1 = 0.f, a2 = 0.f, a3 = 0.f;
  if (lane < 48) {
    int c = lane * 4;
    float4 st = {0.f, 0.f, 0.f, 0.f}, sq = {0.f, 0.f, 0.f, 0.f};
#pragma unroll
    for (int g = 0; g < NSHADOW; ++g) {
      const float* sp = stats + g * SSTRIDE;
      float4 a = *(const float4*)(sp + c);
      float4 b = *(const float4*)(sp + DIM_H + c);
      st.x += a.x; st.y += a.y; st.z += a.z; st.w += a.w;
      sq.x += b.x; sq.y += b.y; sq.z += b.z; sq.w += b.w;
    }
    float4 g4 = *(const float4*)(bng + c);
    float4 b4 = *(const float4*)(bnb + c);
    float4 sc4, sh4;
    float mu, rs;
    mu = st.x * INV_N; rs = rsqrtf(sq.x * INV_N - mu * mu + BN_EPSF); sc4.x = g4.x * rs; sh4.x = b4.x - mu * sc4.x;
    mu = st.y * INV_N; rs = rsqrtf(sq.y * INV_N - mu * mu + BN_EPSF); sc4.y = g4.y * rs; sh4.y = b4.y - mu * sc4.y;
    mu = st.z * INV_N; rs = rsqrtf(sq.z * INV_N - mu * mu + BN_EPSF); sc4.z = g4.z * rs; sh4.z = b4.z - mu * sc4.z;
    mu = st.w * INV_N; rs = rsqrtf(sq.w * INV_N - mu * mu + BN_EPSF); sc4.w = g4.w * rs; sh4.w = b4.w - mu * sc4.w;
#pragma unroll 2
    for (int r = rbeg + w; r < rend; r += 4) {
      float pw = p[r];
      uint2 u = *(const uint2*)(Zin + (size_t)r * DIM_H + c);
      float v0 = relu_f(bflo(u.x) * sc4.x + sh4.x);
      float v1 = relu_f(bfhi(u.x) * sc4.y + sh4.y);
      float v2 = relu_f(bflo(u.y) * sc4.z + sh4.z);
      float v3 = relu_f(bfhi(u.y) * sc4.w + sh4.w);
      a0 = fmaf(pw, v0, a0); a1 = fmaf(pw, v1, a1);
      a2 = fmaf(pw, v2, a2); a3 = fmaf(pw, v3, a3);
    }
    float4 o = {a0, a1, a2, a3};
    *(float4*)&red[w][c] = o;
  }
  __syncthreads();
  if (tid < DIM_H) {
    float s = red[0][tid] + red[1][tid] + red[2][tid] + red[3][tid];
    atomicAdd(&rdout[tid], s);
  }
}

__global__ void k_logit(const float* __restrict__ rdout, const float* __restrict__ scal,
                        const float* __restrict__ cw, const float* __restrict__ cb,
                        float* __restrict__ out) {
  __shared__ float buf[256];
  int tid = threadIdx.x;
  buf[tid] = (tid < DIM_H) ? rdout[tid] * cw[tid] : 0.f;
  __syncthreads();
  for (int s = 128; s > 0; s >>= 1) {
    if (tid < s) buf[tid] += buf[tid + s];
    __syncthreads();
  }
  if (tid == 0) out[0] = buf[0] * (1.f / scal[0]) + cb[0];
}

extern "C" void kernel_launch(void* const* d_in, const int* in_sizes, int n_in,
                              void* d_out, int out_size, void* d_ws, size_t ws_size,
                              hipStream_t stream) {
  const float* x      = (const float*)d_in[0];
  const int*   edge   = (const int*)d_in[1];
  const int*   seedp  = (const int*)d_in[2];
  const float* proj_w = (const float*)d_in[3];
  const float* proj_b = (const float*)d_in[4];
  const float* mlp1_w = (const float*)d_in[5];
  const float* mlp1_b = (const float*)d_in[6];
  const float* mlp2_w = (const float*)d_in[7];
  const float* mlp2_b = (const float*)d_in[8];
  const float* eps    = (const float*)d_in[9];
  const float* bn_g   = (const float*)d_in[10];
  const float* bn_b   = (const float*)d_in[11];
  const float* W1     = (const float*)d_in[12];
  const float* W2     = (const float*)d_in[13];
  const float* w_attn = (const float*)d_in[14];
  const float* cls_w  = (const float*)d_in[15];
  const float* cls_b  = (const float*)d_in[16];
  float* out = (float*)d_out;

  char* ws = (char*)d_ws;
  size_t off = 0;
  auto alloc = [&](size_t bytes) -> void* {
    void* p = ws + off;
    off = (off + bytes + 255) & ~(size_t)255;
    return p;
  };
  unsigned short* buf0 = (unsigned short*)alloc((size_t)N_NODES * DIM_H * 2);
  unsigned short* buf1 = (unsigned short*)alloc((size_t)N_NODES * DIM_H * 2);
  float* pbuf   = (float*)alloc((size_t)N_NODES * 4);
  int* rowptr   = (int*)alloc((size_t)(N_NODES + 1) * 4);
  int* cursor   = (int*)alloc((size_t)(N_NODES + 1) * 4);
  int* csr      = (int*)alloc((size_t)N_EDGES * 4);
  int* part     = (int*)alloc((size_t)N_NODES * 4);
  int* bsum     = (int*)alloc(64 * 4);
  float* stats  = (float*)alloc((size_t)NSHADOW * SSTRIDE * 4);
  float* s2     = (float*)alloc(DIM_H * 4);
  float* scalrd = (float*)alloc(256 * 4);  // [0]=expsum, +64: rdout[192]
  float* scal   = scalrd;
  float* rdout  = scalrd + 64;
  uint4* WTall  = (uint4*)alloc((size_t)(7 * 24 * 192 + 16 * 192) * 16);

  const uint4* B1p[N_LAYERS] = {WTall, WTall + 4608, WTall + 2 * 4608};
  const uint4* B2p[N_LAYERS] = {WTall + 3 * 4608, WTall + 4 * 4608, WTall + 5 * 4608};
  const uint4* Bap = WTall + 6 * 4608;
  const uint4* Bpp = WTall + 7 * 4608;

  const int GRID64 = (N_NODES + 63) / 64;   // 782

  // weight pack
  k_wtp<<<(7 * 24 * 192 + 16 * 192 + 255) / 256, 256, 0, stream>>>(mlp1_w, mlp2_w, W1, proj_w, WTall);

  // CSR build
  hipMemsetAsync(cursor, 0, (size_t)(N_NODES + 1) * 4, stream);
  k_hist<<<(N_EDGES + 255) / 256, 256, 0, stream>>>(edge, cursor);
  k_scanA<<<SCAN_NBLK, 1024, 0, stream>>>(cursor, part, bsum);
  k_scanB<<<1, 64, 0, stream>>>(bsum);
  k_scanC<<<(N_NODES + 255) / 256, 256, 0, stream>>>(part, bsum, rowptr, cursor);
  k_fill<<<(N_EDGES + 255) / 256, 256, 0, stream>>>(edge, cursor, csr);

  // projection: x -> buf0 (relu'd h0, bf16)
  k_proj<<<GRID64, 256, 0, stream>>>(x, Bpp, proj_b, buf0);

  // GIN layers (ping-pong; BN+relu folded into next consumer, coef computed from shadow stats inline)
  unsigned short* cur = buf0;
  unsigned short* nxt = buf1;
  for (int l = 0; l < N_LAYERS; ++l) {
    const float* g_prev = bn_g + (size_t)(l - 1) * DIM_H;
    const float* b_prev = bn_b + (size_t)(l - 1) * DIM_H;
    if (l == 0)
      k_agg<false><<<(N_NODES + 3) / 4, 256, 0, stream>>>(cur, rowptr, csr, stats, g_prev, b_prev, eps, l, nxt);
    else
      k_agg<true><<<(N_NODES + 3) / 4, 256, 0, stream>>>(cur, rowptr, csr, stats, g_prev, b_prev, eps, l, nxt);
    hipMemsetAsync(stats, 0, (size_t)NSHADOW * SSTRIDE * 4, stream);
    k_mlp<<<GRID64, 256, 0, stream>>>(nxt, B1p[l], mlp1_b + (size_t)l * DIM_H,
                                      B2p[l], mlp2_b + (size_t)l * DIM_H, nxt, stats);
    unsigned short* t = cur; cur = nxt; nxt = t;
  }
  // cur = pre-BN z2; stats = layer-2 shadow stats; BN fused into all consumers below
  const float* g2 = bn_g + (size_t)2 * DIM_H;
  const float* b2c = bn_b + (size_t)2 * DIM_H;

  hipMemsetAsync(scalrd, 0, 256 * 4, stream);
  k_seed_s2<<<1, 768, 0, stream>>>(cur, stats, g2, b2c, seedp, W2, s2);
  k_attnm<<<GRID64, 256, 0, stream>>>(cur, stats, g2, b2c, Bap, s2, w_attn, pbuf, scal);
  k_alpha<<<(N_NODES + 255) / 256, 256, 0, stream>>>(pbuf, scal, out + 1);
  k_readout<<<RD_BLOCKS, 256, 0, stream>>>(pbuf, cur, stats, g2, b2c, rdout);
  k_logit<<<1, 256, 0, stream>>>(rdout, scal, cls_w, cls_b, out);
}